// Round 10
// baseline (448.643 us; speedup 1.0000x reference)
//
#include <hip/hip_runtime.h>
#include <math.h>

#define SCALE_F   0.17677669529663687f   // 32^-0.5
#define SCALE_L2E 0.25505837072959003f   // 32^-0.5 * log2(e)

using bf16x8 = __attribute__((ext_vector_type(8))) __bf16;
using f32x2  = __attribute__((ext_vector_type(2))) float;
using f32x4  = __attribute__((ext_vector_type(4))) float;
using f32x16 = __attribute__((ext_vector_type(16))) float;
using uint2e = __attribute__((ext_vector_type(2))) unsigned int;

__device__ inline unsigned short f2bf(float x) {
    __bf16 h = (__bf16)x;                       // HW v_cvt (RNE)
    return __builtin_bit_cast(unsigned short, h);
}
__device__ inline float bf2f(unsigned short u) {
    unsigned int x = ((unsigned int)u) << 16;
    return __builtin_bit_cast(float, x);
}
__device__ inline unsigned int packbf(float a, float b) {
    return (unsigned int)f2bf(a) | ((unsigned int)f2bf(b) << 16);
}
__device__ inline bf16x8 ldfrag(const unsigned short* p) {
    return __builtin_bit_cast(bf16x8, *reinterpret_cast<const uint4*>(p));
}

// ---------------------------------------------------------------------------
// fp32 k-projection GEMM. BM=128, BN=128, BK=32, 512 thr, 4x8 micro-tile.
// Inner math via __builtin_elementwise_fma on f32x2 -> llvm.fma.v2f32 ->
// v_pk_fma_f32 (2 FMA/instr; per-component rounding == v_fma_f32).
// Each output's accumulation remains ONE fma chain over k ascending ->
// k values bit-identical to all previous passing rounds (argsort-safe).
// ---------------------------------------------------------------------------
__global__ __launch_bounds__(512)
void gemm_k_kernel(const float* __restrict__ A, const float* __restrict__ Bmat,
                   const float* __restrict__ bias, float* __restrict__ CT)
{
    const int bm = blockIdx.x, bn = blockIdx.y, bz = blockIdx.z;
    const float* Bp = Bmat + (long)bz * 384 * 4096;
    float* Cp = CT + (long)bz * 4096 * 384;
    __shared__ float As[32][132];
    __shared__ float BsF[32 * 136];
    const int tid = threadIdx.x;
    const int tx = tid & 15, ty = tid >> 4;    // tx 0..15, ty 0..31
    const int m0 = bm * 128, n0 = bn * 128;

    f32x2 acc2[4][4];
    #pragma unroll
    for (int i = 0; i < 4; ++i)
        #pragma unroll
        for (int p = 0; p < 4; ++p) acc2[i][p] = (f32x2){0.f, 0.f};

    for (int k0 = 0; k0 < 384; k0 += 32) {
        if (k0) __syncthreads();
        #pragma unroll
        for (int it = 0; it < 2; ++it) {
            int slot = tid + it * 512;
            int rA = slot >> 3, cA = slot & 7;          // A: 128 rows x 8 quads
            float4 av = *reinterpret_cast<const float4*>(&A[(long)(384 + m0 + rA) * 384 + k0 + cA * 4]);
            As[cA * 4 + 0][rA] = av.x; As[cA * 4 + 1][rA] = av.y;
            As[cA * 4 + 2][rA] = av.z; As[cA * 4 + 3][rA] = av.w;
            int sr = slot >> 5, sq = slot & 31;         // B: 32 rows x 32 quads
            int wB = sr * 136 + ((sq & 1) << 6) + ((sq >> 1) << 2);
            *reinterpret_cast<float4*>(&BsF[wB]) =
                *reinterpret_cast<const float4*>(&Bp[(long)(k0 + sr) * 4096 + n0 + sq * 4]);
        }
        __syncthreads();
        #pragma unroll
        for (int kk = 0; kk < 32; ++kk) {
            float a[4];
            *reinterpret_cast<float4*>(&a[0]) = *reinterpret_cast<const float4*>(&As[kk][ty * 4]);
            float4 blo = *reinterpret_cast<const float4*>(&BsF[kk * 136 + tx * 4]);
            float4 bhi = *reinterpret_cast<const float4*>(&BsF[kk * 136 + 64 + tx * 4]);
            f32x2 b2[4];
            b2[0] = (f32x2){blo.x, blo.y}; b2[1] = (f32x2){blo.z, blo.w};
            b2[2] = (f32x2){bhi.x, bhi.y}; b2[3] = (f32x2){bhi.z, bhi.w};
            #pragma unroll
            for (int i = 0; i < 4; ++i) {
                f32x2 a2 = (f32x2){a[i], a[i]};
                #pragma unroll
                for (int p = 0; p < 4; ++p)
                    acc2[i][p] = __builtin_elementwise_fma(a2, b2[p], acc2[i][p]);  // v_pk_fma_f32
            }
        }
    }

    float bv[4];
    #pragma unroll
    for (int i = 0; i < 4; ++i) bv[i] = bias[384 + m0 + ty * 4 + i];
    #pragma unroll
    for (int p = 0; p < 4; ++p)
        #pragma unroll
        for (int c = 0; c < 2; ++c) {
            int j = 2 * p + c;
            long tok = n0 + tx * 8 + j;
            float4 v = make_float4(acc2[0][p][c] + bv[0], acc2[1][p][c] + bv[1],
                                   acc2[2][p][c] + bv[2], acc2[3][p][c] + bv[3]);
            *reinterpret_cast<float4*>(Cp + tok * 384 + m0 + ty * 4) = v;
        }
}

// ---------------------------------------------------------------------------
// bf16 MFMA NT-GEMM: D[rowA][rowB] = sum_k A[rowA][k]*B[rowB][k], both k-contig.
// SM=0: store bf16 at C[t=colB][m=rowA] (ldc 768), bias by rowA  (QV proj)
// SM=1: store f32  at C[m=colB][t=rowA] (ldc 4096), bias by colB (out proj)
// SPLIT: A,B given as hi/lo bf16 pairs; 3-term product.
// ---------------------------------------------------------------------------
template<bool SPLIT, int SM>
__global__ __launch_bounds__(256)
void mfma_nt_kernel(const unsigned short* __restrict__ Ah, const unsigned short* __restrict__ Al,
                    const unsigned short* __restrict__ Bh, const unsigned short* __restrict__ Bl,
                    const float* __restrict__ bias, void* __restrict__ Cout,
                    int K, int lda, int ldb,
                    long strideAb, long strideBb, long strideCb)
{
    extern __shared__ unsigned short smem[];
    unsigned short* As  = smem;            // [128][40]
    unsigned short* Bs  = smem + 5120;
    unsigned short* Asl = smem + 10240;
    unsigned short* Bsl = smem + 15360;
    const int bm = blockIdx.x, bn = blockIdx.y, bz = blockIdx.z;
    const unsigned short* Ap = Ah + (long)bz * strideAb;
    const unsigned short* Bp = Bh + (long)bz * strideBb;
    const unsigned short* Alp = nullptr;
    const unsigned short* Blp = nullptr;
    if constexpr (SPLIT) {
        Alp = Al + (long)bz * strideAb;
        Blp = Bl + (long)bz * strideBb;
    }
    const int tid = threadIdx.x;
    const int lane = tid & 63, wid = tid >> 6;
    const int wr = wid >> 1, wc = wid & 1;
    const int l15 = lane & 15, l4 = lane >> 4;
    const int m0 = bm * 128, n0 = bn * 128;

    const f32x4 Z4 = {0.f, 0.f, 0.f, 0.f};
    f32x4 acc[4][4];
    #pragma unroll
    for (int i = 0; i < 4; ++i)
        #pragma unroll
        for (int j = 0; j < 4; ++j) acc[i][j] = Z4;

    for (int k0 = 0; k0 < K; k0 += 32) {
        if (k0) __syncthreads();
        #pragma unroll
        for (int it = 0; it < 2; ++it) {
            int slot = tid + it * 256;
            int r = slot >> 2, cq = slot & 3;
            *reinterpret_cast<uint4*>(&As[r * 40 + cq * 8]) =
                *reinterpret_cast<const uint4*>(&Ap[(long)(m0 + r) * lda + k0 + cq * 8]);
            *reinterpret_cast<uint4*>(&Bs[r * 40 + cq * 8]) =
                *reinterpret_cast<const uint4*>(&Bp[(long)(n0 + r) * ldb + k0 + cq * 8]);
            if constexpr (SPLIT) {
                *reinterpret_cast<uint4*>(&Asl[r * 40 + cq * 8]) =
                    *reinterpret_cast<const uint4*>(&Alp[(long)(m0 + r) * lda + k0 + cq * 8]);
                *reinterpret_cast<uint4*>(&Bsl[r * 40 + cq * 8]) =
                    *reinterpret_cast<const uint4*>(&Blp[(long)(n0 + r) * ldb + k0 + cq * 8]);
            }
        }
        __syncthreads();

        bf16x8 af[4], bg[4], afl[4], bgl[4];
        #pragma unroll
        for (int f = 0; f < 4; ++f) {
            af[f] = ldfrag(&As[(wr * 64 + f * 16 + l15) * 40 + l4 * 8]);
            bg[f] = ldfrag(&Bs[(wc * 64 + f * 16 + l15) * 40 + l4 * 8]);
        }
        if constexpr (SPLIT) {
            #pragma unroll
            for (int f = 0; f < 4; ++f) {
                afl[f] = ldfrag(&Asl[(wr * 64 + f * 16 + l15) * 40 + l4 * 8]);
                bgl[f] = ldfrag(&Bsl[(wc * 64 + f * 16 + l15) * 40 + l4 * 8]);
            }
        }
        #pragma unroll
        for (int fi = 0; fi < 4; ++fi)
            #pragma unroll
            for (int fj = 0; fj < 4; ++fj) {
                acc[fi][fj] = __builtin_amdgcn_mfma_f32_16x16x32_bf16(af[fi], bg[fj], acc[fi][fj], 0, 0, 0);
                if constexpr (SPLIT) {
                    acc[fi][fj] = __builtin_amdgcn_mfma_f32_16x16x32_bf16(af[fi], bgl[fj], acc[fi][fj], 0, 0, 0);
                    acc[fi][fj] = __builtin_amdgcn_mfma_f32_16x16x32_bf16(afl[fi], bg[fj], acc[fi][fj], 0, 0, 0);
                }
            }
    }

    if constexpr (SM == 0) {
        unsigned short* Cq = (unsigned short*)Cout + (long)bz * strideCb;
        #pragma unroll
        for (int fi = 0; fi < 4; ++fi)
            #pragma unroll
            for (int fj = 0; fj < 4; ++fj) {
                const int m = m0 + wr * 64 + fi * 16 + l4 * 4;
                const int t = n0 + wc * 64 + fj * 16 + l15;
                ushort4 h;
                h.x = f2bf(acc[fi][fj][0] + bias[m + 0]);
                h.y = f2bf(acc[fi][fj][1] + bias[m + 1]);
                h.z = f2bf(acc[fi][fj][2] + bias[m + 2]);
                h.w = f2bf(acc[fi][fj][3] + bias[m + 3]);
                *reinterpret_cast<ushort4*>(&Cq[(long)t * 768 + m]) = h;
            }
    } else {
        float* Cf = (float*)Cout + (long)bz * strideCb;
        #pragma unroll
        for (int fi = 0; fi < 4; ++fi)
            #pragma unroll
            for (int fj = 0; fj < 4; ++fj) {
                const int t = m0 + wr * 64 + fi * 16 + l4 * 4;
                const int m = n0 + wc * 64 + fj * 16 + l15;
                const float bv = bias[m];
                float4 v = make_float4(acc[fi][fj][0] + bv, acc[fi][fj][1] + bv,
                                       acc[fi][fj][2] + bv, acc[fi][fj][3] + bv);
                *reinterpret_cast<float4*>(&Cf[(long)m * 4096 + t]) = v;
            }
    }
}

// ---------------------------------------------------------------------------
// Weight conversion: Wqv bf16 (q,v rows of qkv_w), qv bias gather,
// out_w split hi/lo bf16.
// ---------------------------------------------------------------------------
__global__ __launch_bounds__(256)
void convert_w_kernel(const float* __restrict__ qkv_w, const float* __restrict__ qkv_b,
                      const float* __restrict__ out_w,
                      unsigned short* __restrict__ Wqv, float* __restrict__ qvb,
                      unsigned short* __restrict__ owh, unsigned short* __restrict__ owl)
{
    const int total = 294912 + 147456 + 768;
    for (int i = blockIdx.x * 256 + threadIdx.x; i < total; i += gridDim.x * 256) {
        if (i < 294912) {
            int m = i / 384, k = i - m * 384;
            int src = (m < 384) ? m : m + 384;
            Wqv[i] = f2bf(qkv_w[(long)src * 384 + k]);
        } else if (i < 294912 + 147456) {
            int o = i - 294912;
            float w = out_w[o];
            unsigned short h = f2bf(w);
            owh[o] = h;
            owl[o] = f2bf(w - bf2f(h));
        } else {
            int m = i - 294912 - 147456;
            qvb[m] = qkv_b[(m < 384) ? m : m + 384];
        }
    }
}

// ---------------------------------------------------------------------------
// x [b][384][4096] fp32 -> xbT [b][4096][384] bf16 (LDS 64x64 transpose)
// ---------------------------------------------------------------------------
__global__ __launch_bounds__(256)
void transpose_x_kernel(const float* __restrict__ x, unsigned short* __restrict__ xbT)
{
    const int t0 = blockIdx.x * 64, c0 = blockIdx.y * 64, b = blockIdx.z;
    __shared__ float tl[64][65];
    const int tid = threadIdx.x;
    #pragma unroll
    for (int i = 0; i < 16; ++i) {
        int cr = (tid >> 6) + i * 4, tc = tid & 63;
        tl[cr][tc] = x[((long)b * 384 + c0 + cr) * 4096 + t0 + tc];
    }
    __syncthreads();
    #pragma unroll
    for (int i = 0; i < 8; ++i) {
        int tr = (tid >> 5) + i * 8, c2 = (tid & 31) * 2;
        unsigned int u = packbf(tl[c2][tr], tl[c2 + 1][tr]);
        *reinterpret_cast<unsigned int*>(&xbT[((long)b * 4096 + t0 + tr) * 384 + c0 + c2]) = u;
    }
}

// ---------------------------------------------------------------------------
// Depthwise 5x5 conv (pad 2), v from qvB (bf16), out lepeT (bf16).
// ---------------------------------------------------------------------------
__global__ __launch_bounds__(256)
void lepe_kernel(const unsigned short* __restrict__ qvB, const float* __restrict__ w5,
                 const float* __restrict__ wb, unsigned short* __restrict__ lepeT)
{
    const int ch0 = blockIdx.x * 16;
    const int y0 = blockIdx.y * 8;
    const int b = blockIdx.z;
    const unsigned short* vb = qvB + (long)b * 4096 * 768 + 384 + ch0;
    unsigned short* dst = lepeT + (long)b * 4096 * 384 + ch0;
    __shared__ float tile[12 * 68 * 16];
    const int tid = threadIdx.x;

    for (int i = tid; i < 12 * 68 * 16; i += 256) {
        int pix = i >> 4, c = i & 15;
        int yy = pix / 68, xx = pix % 68;
        int gy = y0 + yy - 2, gx = xx - 2;
        float v = 0.f;
        if (gy >= 0 && gy < 64 && gx >= 0 && gx < 64)
            v = bf2f(vb[(long)(gy * 64 + gx) * 768 + c]);
        tile[i] = v;
    }
    const int c = tid & 15, xo = tid >> 4;
    float f[25];
    #pragma unroll
    for (int j = 0; j < 25; ++j) f[j] = w5[(ch0 + c) * 25 + j];
    const float bv = wb[ch0 + c];
    __syncthreads();

    #pragma unroll
    for (int yy = 0; yy < 8; ++yy) {
        #pragma unroll
        for (int xq = 0; xq < 4; ++xq) {
            int x = xq * 16 + xo;
            float acc = bv;
            #pragma unroll
            for (int dy = 0; dy < 5; ++dy)
                #pragma unroll
                for (int dx = 0; dx < 5; ++dx)
                    acc += tile[((yy + dy) * 68 + (x + dx)) * 16 + c] * f[dy * 5 + dx];
            dst[(long)((y0 + yy) * 64 + x) * 384 + c] = f2bf(acc);
        }
    }
}

// ---------------------------------------------------------------------------
// cos kernel: reads Kf32 [b][t][384] (bit-identical k values).
// ---------------------------------------------------------------------------
__global__ __launch_bounds__(256)
void cos_kernel(const float* __restrict__ Kf32, float* __restrict__ cosv)
{
    const int bn = blockIdx.x;
    const int b = bn / 12, n = bn % 12;
    const float* kb = Kf32 + (long)b * 4096 * 384 + n * 32;
    __shared__ float part[256][33];
    __shared__ float clsn[32];
    const int tid = threadIdx.x;
    float acc[32];
    #pragma unroll
    for (int d = 0; d < 32; ++d) acc[d] = 0.f;
    for (int i = 0; i < 16; ++i) {
        long tok = tid + i * 256;
        const float* kr = kb + tok * 384;
        #pragma unroll
        for (int d = 0; d < 32; ++d) acc[d] += kr[d];
    }
    #pragma unroll
    for (int d = 0; d < 32; ++d) part[tid][d] = acc[d];
    __syncthreads();
    if (tid < 32) {
        double s = 0.0;
        for (int t = 0; t < 256; ++t) s += (double)part[t][tid];
        part[0][tid] = (float)s;
    }
    __syncthreads();
    if (tid == 0) {
        double nn = 0.0;
        for (int d = 0; d < 32; ++d) { double v = (double)part[0][d]; nn += v * v; }
        double inv = 1.0 / sqrt(nn > 1e-300 ? nn : 1e-300);
        for (int d = 0; d < 32; ++d) clsn[d] = (float)((double)part[0][d] * inv);
    }
    __syncthreads();
    for (int i = 0; i < 16; ++i) {
        long tok = tid + i * 256;
        const float* kr = kb + tok * 384;
        double dot = 0.0, nrm = 0.0;
        #pragma unroll
        for (int d = 0; d < 32; ++d) {
            float kv = kr[d];
            dot += (double)clsn[d] * (double)kv;
            nrm += (double)kv * (double)kv;
        }
        double cv = dot / sqrt(nrm > 1e-300 ? nrm : 1e-300);
        cosv[(long)bn * 4096 + tok] = (float)cv;
    }
}

// ---------------------------------------------------------------------------
// Bitonic argsort ascending by (cos, idx) — matches stable jnp.argsort.
// ---------------------------------------------------------------------------
__global__ __launch_bounds__(1024)
void sort_kernel(const float* __restrict__ cosv, int* __restrict__ idxo)
{
    const int bn = blockIdx.x;
    __shared__ float sv[4096];
    __shared__ int si[4096];
    const int tid = threadIdx.x;
    for (int i = tid; i < 4096; i += 1024) { sv[i] = cosv[(long)bn * 4096 + i]; si[i] = i; }
    __syncthreads();
    for (int size = 2; size <= 4096; size <<= 1) {
        for (int stride = size >> 1; stride >= 1; stride >>= 1) {
            #pragma unroll 2
            for (int i = tid; i < 2048; i += 1024) {
                int lo = (i << 1) - (i & (stride - 1));
                int hi = lo + stride;
                bool asc = ((lo & size) == 0);
                float av = sv[lo], bvv = sv[hi];
                int ai = si[lo], bi = si[hi];
                bool agtb = (av > bvv) || (av == bvv && ai > bi);
                if (agtb == asc) {
                    sv[lo] = bvv; sv[hi] = av;
                    si[lo] = bi; si[hi] = ai;
                }
            }
            __syncthreads();
        }
    }
    for (int i = tid; i < 4096; i += 1024) idxo[(long)bn * 4096 + i] = si[i];
}

// ---------------------------------------------------------------------------
// MFMA clustered attention. grid (16,12,8), 256 thr = 4 waves.
// K staged as bf16(k * SCALE * log2e) -> scores in log2 domain, p = exp2(s).
// ---------------------------------------------------------------------------
__global__ __launch_bounds__(256)
void attn_kernel(const float* __restrict__ Kf32, unsigned short* __restrict__ qvB,
                 const int* __restrict__ idxbuf, const unsigned short* __restrict__ lepeT)
{
    const int cc = blockIdx.x, n = blockIdx.y, b = blockIdx.z;
    const int* ip = idxbuf + ((long)(b * 12 + n)) * 4096 + cc * 256;

    __shared__ unsigned short KsL[256][36];
    __shared__ unsigned short VsT[32][260];
    __shared__ int tokLds[256];

    const int tid = threadIdx.x;
    const int w = tid >> 6;
    const int lane = tid & 63;
    const int lo5 = lane & 31;
    const int hi = lane >> 5;
    const int hi8 = hi * 8;

    // ---- gather ----
    const int tk0 = ip[tid];
    tokLds[tid] = tk0;
    const long tb = (long)b * 4096 + tk0;
    const unsigned short* qrow = qvB + tb * 768 + n * 32;
    const float* krow = Kf32 + tb * 384 + n * 32;

    unsigned int Pq[16];
    #pragma unroll
    for (int i = 0; i < 4; ++i) {
        uint4 qu = *reinterpret_cast<const uint4*>(qrow + i * 8);
        Pq[4 * i + 0] = qu.x; Pq[4 * i + 1] = qu.y;
        Pq[4 * i + 2] = qu.z; Pq[4 * i + 3] = qu.w;
    }
    #pragma unroll
    for (int dq = 0; dq < 8; ++dq) {
        float4 kv = *reinterpret_cast<const float4*>(krow + dq * 4);
        ushort4 kp;
        kp.x = f2bf(kv.x * SCALE_L2E); kp.y = f2bf(kv.y * SCALE_L2E);
        kp.z = f2bf(kv.z * SCALE_L2E); kp.w = f2bf(kv.w * SCALE_L2E);
        *reinterpret_cast<ushort4*>(&KsL[tid][dq * 4]) = kp;
    }
    {
        union { uint4 u[4]; unsigned short s[32]; } vv;
        const unsigned short* vrow = qrow + 384;
        #pragma unroll
        for (int i = 0; i < 4; ++i) vv.u[i] = *reinterpret_cast<const uint4*>(vrow + i * 8);
        #pragma unroll
        for (int j = 0; j < 32; ++j) VsT[j][tid] = vv.s[j];
    }

    // ---- Q B-frags from own registers via permlane32_swap ----
    bf16x8 qf00, qf01, qf10, qf11;
    {
        unsigned int w0[2][4], w1[2][4];
        #pragma unroll
        for (int ks = 0; ks < 2; ++ks)
            #pragma unroll
            for (int j = 0; j < 4; ++j) {
                uint2e r = __builtin_amdgcn_permlane32_swap(Pq[ks * 8 + j], Pq[ks * 8 + 4 + j], false, false);
                w0[ks][j] = r[0];
                w1[ks][j] = r[1];
            }
        qf00 = __builtin_bit_cast(bf16x8, make_uint4(w0[0][0], w0[0][1], w0[0][2], w0[0][3]));
        qf01 = __builtin_bit_cast(bf16x8, make_uint4(w0[1][0], w0[1][1], w0[1][2], w0[1][3]));
        qf10 = __builtin_bit_cast(bf16x8, make_uint4(w1[0][0], w1[0][1], w1[0][2], w1[0][3]));
        qf11 = __builtin_bit_cast(bf16x8, make_uint4(w1[1][0], w1[1][1], w1[1][2], w1[1][3]));
    }
    __syncthreads();

    const f32x16 Z16 = {0,0,0,0,0,0,0,0,0,0,0,0,0,0,0,0};
    f32x16 o0 = Z16, o1 = Z16;
    float lsum0 = 0.f, lsum1 = 0.f;

#define LDFRAG(ARR, ROW, OFF) ({ \
    const unsigned short* _p = &ARR[ROW][OFF]; \
    union { bf16x8 v; ushort4 h[2]; } _u; \
    _u.h[0] = *reinterpret_cast<const ushort4*>(_p); \
    _u.h[1] = *reinterpret_cast<const ushort4*>(_p + 4); \
    _u.v; })

#define EXP16(S, LS) { _Pragma("unroll") for (int r = 0; r < 16; ++r) { float _e = __builtin_exp2f(S[r]); S[r] = _e; LS += _e; } }

#define MKPB(S, H) ({ \
    unsigned int _x0 = packbf(S[(H) * 8 + 0], S[(H) * 8 + 1]); \
    unsigned int _x1 = packbf(S[(H) * 8 + 2], S[(H) * 8 + 3]); \
    unsigned int _x2 = packbf(S[(H) * 8 + 4], S[(H) * 8 + 5]); \
    unsigned int _x3 = packbf(S[(H) * 8 + 6], S[(H) * 8 + 7]); \
    uint2e _r02 = __builtin_amdgcn_permlane32_swap(_x0, _x2, false, false); \
    uint2e _r13 = __builtin_amdgcn_permlane32_swap(_x1, _x3, false, false); \
    __builtin_bit_cast(bf16x8, make_uint4(_r02[0], _r13[0], _r02[1], _r13[1])); })

    for (int ch = 0; ch < 4; ++ch) {
        const int rb = ch * 64;
        f32x16 s00 = Z16, s01 = Z16, s10 = Z16, s11 = Z16;
        bf16x8 ka;
        ka = LDFRAG(KsL, rb + lo5, hi8);
        s00 = __builtin_amdgcn_mfma_f32_32x32x16_bf16(ka, qf00, s00, 0, 0, 0);
        s01 = __builtin_amdgcn_mfma_f32_32x32x16_bf16(ka, qf10, s01, 0, 0, 0);
        ka = LDFRAG(KsL, rb + lo5, 16 + hi8);
        s00 = __builtin_amdgcn_mfma_f32_32x32x16_bf16(ka, qf01, s00, 0, 0, 0);
        s01 = __builtin_amdgcn_mfma_f32_32x32x16_bf16(ka, qf11, s01, 0, 0, 0);
        ka = LDFRAG(KsL, rb + 32 + lo5, hi8);
        s10 = __builtin_amdgcn_mfma_f32_32x32x16_bf16(ka, qf00, s10, 0, 0, 0);
        s11 = __builtin_amdgcn_mfma_f32_32x32x16_bf16(ka, qf10, s11, 0, 0, 0);
        ka = LDFRAG(KsL, rb + 32 + lo5, 16 + hi8);
        s10 = __builtin_amdgcn_mfma_f32_32x32x16_bf16(ka, qf01, s10, 0, 0, 0);
        s11 = __builtin_amdgcn_mfma_f32_32x32x16_bf16(ka, qf11, s11, 0, 0, 0);

        EXP16(s00, lsum0); EXP16(s01, lsum1);
        EXP16(s10, lsum0); EXP16(s11, lsum1);

        bf16x8 va, pb0, pb1;
        va = LDFRAG(VsT, lo5, rb + 0 + hi8);
        pb0 = MKPB(s00, 0); pb1 = MKPB(s01, 0);
        o0 = __builtin_amdgcn_mfma_f32_32x32x16_bf16(va, pb0, o0, 0, 0, 0);
        o1 = __builtin_amdgcn_mfma_f32_32x32x16_bf16(va, pb1, o1, 0, 0, 0);
        va = LDFRAG(VsT, lo5, rb + 16 + hi8);
        pb0 = MKPB(s00, 1); pb1 = MKPB(s01, 1);
        o0 = __builtin_amdgcn_mfma_f32_32x32x16_bf16(va, pb0, o0, 0, 0, 0);
        o1 = __builtin_amdgcn_mfma_f32_32x32x16_bf16(va, pb1, o1, 0, 0, 0);
        va = LDFRAG(VsT, lo5, rb + 32 + hi8);
        pb0 = MKPB(s10, 0); pb1 = MKPB(s11, 0);
        o0 = __builtin_amdgcn_mfma_f32_32x32x16_bf16(va, pb0, o0, 0, 0, 0);
        o1 = __builtin_amdgcn_mfma_f32_32x32x16_bf16(va, pb1, o1, 0, 0, 0);
        va = LDFRAG(VsT, lo5, rb + 48 + hi8);
        pb0 = MKPB(s10, 1); pb1 = MKPB(s11, 1);
        o0 = __builtin_amdgcn_mfma_f32_32x32x16_bf16(va, pb0, o0, 0, 0, 0);
        o1 = __builtin_amdgcn_mfma_f32_32x32x16_bf16(va, pb1, o1, 0, 0, 0);
    }

    // ---- epilogue: res = o/l + lepe -> bf16 hi/lo into qvB ----
    const float lf0 = lsum0 + __shfl_xor(lsum0, 32);
    const float lf1 = lsum1 + __shfl_xor(lsum1, 32);
    const float li0 = 1.f / lf0, li1 = 1.f / lf1;

    #pragma unroll
    for (int qt = 0; qt < 2; ++qt) {
        const int qrix = w * 64 + qt * 32 + lo5;
        const int tk = tokLds[qrix];
        const long tb2 = (long)b * 4096 + tk;
        unsigned short* resrow = qvB + tb2 * 768;
        const unsigned short* lp = lepeT + tb2 * 384 + n * 32;
        const float li = qt ? li1 : li0;
        const f32x16& oo = qt ? o1 : o0;
        #pragma unroll
        for (int qd = 0; qd < 4; ++qd) {
            const int d0 = qd * 8 + hi * 4;
            ushort4 lv = *reinterpret_cast<const ushort4*>(lp + d0);
            float r0 = oo[qd * 4 + 0] * li + bf2f(lv.x);
            float r1 = oo[qd * 4 + 1] * li + bf2f(lv.y);
            float r2 = oo[qd * 4 + 2] * li + bf2f(lv.z);
            float r3 = oo[qd * 4 + 3] * li + bf2f(lv.w);
            unsigned short h0 = f2bf(r0), h1 = f2bf(r1), h2 = f2bf(r2), h3 = f2bf(r3);
            ushort4 hh = {h0, h1, h2, h3};
            ushort4 ll = {f2bf(r0 - bf2f(h0)), f2bf(r1 - bf2f(h1)),
                          f2bf(r2 - bf2f(h2)), f2bf(r3 - bf2f(h3))};
            *reinterpret_cast<ushort4*>(resrow + n * 32 + d0) = hh;
            *reinterpret_cast<ushort4*>(resrow + 384 + n * 32 + d0) = ll;
        }
    }
#undef LDFRAG
#undef EXP16
#undef MKPB
}

// ---------------------------------------------------------------------------
extern "C" void kernel_launch(void* const* d_in, const int* in_sizes, int n_in,
                              void* d_out, int out_size, void* d_ws, size_t ws_size,
                              hipStream_t stream)
{
    const float* x      = (const float*)d_in[0];
    const float* qkv_w  = (const float*)d_in[1];
    const float* qkv_b  = (const float*)d_in[2];
    const float* lepe_w = (const float*)d_in[3];
    const float* lepe_b = (const float*)d_in[4];
    const float* out_w  = (const float*)d_in[5];
    const float* out_b  = (const float*)d_in[6];
    float* out = (float*)d_out;

    char* ws = (char*)d_ws;
    float*          Kf32 = (float*)ws;                                  // 50331648 B
    unsigned short* qvB  = (unsigned short*)(ws + 50331648);            // 50331648 B
    float*          cosv = (float*)(ws + 100663296);                    // 1572864 B
    int*            idx  = (int*)(ws + 102236160);                      // 1572864 B
    unsigned short* Wqv  = (unsigned short*)(ws + 103809024);           // 589824 B
    unsigned short* owh  = (unsigned short*)(ws + 104398848);           // 294912 B
    unsigned short* owl  = (unsigned short*)(ws + 104693760);           // 294912 B
    float*          qvb  = (float*)(ws + 104988672);                    // 3072 B

    unsigned short* xbT   = (unsigned short*)d_out;                     // dead before out-proj
    unsigned short* lepeT = (unsigned short*)d_out + 12582912;          // dead before out-proj

    // 1) weight conversions
    convert_w_kernel<<<1731, 256, 0, stream>>>(qkv_w, qkv_b, out_w, Wqv, qvb, owh, owl);
    // 2) x -> token-major bf16
    transpose_x_kernel<<<dim3(64, 6, 8), 256, 0, stream>>>(x, xbT);
    // 3) k projection, exact fp32 (per-output accumulation bit-identical)
    gemm_k_kernel<<<dim3(3, 32, 8), 512, 0, stream>>>(qkv_w, x, qkv_b, Kf32);
    // 4) q,v projection, bf16 MFMA -> qvB [b][t][768] bf16
    mfma_nt_kernel<false, 0><<<dim3(6, 32, 8), 256, 20480, stream>>>(
        Wqv, nullptr, xbT, nullptr, qvb, qvB,
        384, 384, 384, 0L, (long)4096 * 384, (long)4096 * 768);
    // 5) LePE depthwise conv (v bf16 -> lepeT bf16)
    lepe_kernel<<<dim3(24, 8, 8), 256, 0, stream>>>(qvB, lepe_w, lepe_b, lepeT);
    // 6) cosine-to-class-mean per (b, head)
    cos_kernel<<<96, 256, 0, stream>>>(Kf32, cosv);
    // 7) stable ascending argsort
    sort_kernel<<<96, 1024, 0, stream>>>(cosv, idx);
    // 8) clustered attention + lepe residual; res -> bf16 hi/lo over qvB
    attn_kernel<<<dim3(16, 12, 8), 256, 0, stream>>>(Kf32, qvB, idx, lepeT);
    // 9) output projection, split-bf16 (3-term) MFMA -> out
    mfma_nt_kernel<true, 1><<<dim3(32, 3, 8), 256, 40960, stream>>>(
        qvB, qvB + 384, owh, owl, out_b, out,
        384, 768, 384, (long)4096 * 768, 0L, (long)384 * 4096);
}

// Round 11
// 401.294 us; speedup vs baseline: 1.1180x; 1.1180x over previous
//
#include <hip/hip_runtime.h>
#include <math.h>

#define SCALE_F   0.17677669529663687f   // 32^-0.5
#define SCALE_L2E 0.25505837072959003f   // 32^-0.5 * log2(e)

using bf16x8 = __attribute__((ext_vector_type(8))) __bf16;
using f32x2  = __attribute__((ext_vector_type(2))) float;
using f32x4  = __attribute__((ext_vector_type(4))) float;
using f32x16 = __attribute__((ext_vector_type(16))) float;
using uint2e = __attribute__((ext_vector_type(2))) unsigned int;

__device__ inline unsigned short f2bf(float x) {
    __bf16 h = (__bf16)x;                       // HW v_cvt (RNE)
    return __builtin_bit_cast(unsigned short, h);
}
__device__ inline float bf2f(unsigned short u) {
    unsigned int x = ((unsigned int)u) << 16;
    return __builtin_bit_cast(float, x);
}
__device__ inline unsigned int packbf(float a, float b) {
    return (unsigned int)f2bf(a) | ((unsigned int)f2bf(b) << 16);
}
__device__ inline bf16x8 ldfrag(const unsigned short* p) {
    return __builtin_bit_cast(bf16x8, *reinterpret_cast<const uint4*>(p));
}

// ---------------------------------------------------------------------------
// fp32 k-projection GEMM. BM=128, BN=128, BK=32, 512 thr, 4x8 micro-tile.
// Each output's accumulation remains ONE fma chain over k ascending ->
// k values bit-identical to all previous passing rounds (argsort-safe).
// Parked at ~130us (2.1x scalar-FMA floor); fp32-exactness blocks MFMA.
// ---------------------------------------------------------------------------
__global__ __launch_bounds__(512)
void gemm_k_kernel(const float* __restrict__ A, const float* __restrict__ Bmat,
                   const float* __restrict__ bias, float* __restrict__ CT)
{
    const int bm = blockIdx.x, bn = blockIdx.y, bz = blockIdx.z;
    const float* Bp = Bmat + (long)bz * 384 * 4096;
    float* Cp = CT + (long)bz * 4096 * 384;
    __shared__ float As[32][132];
    __shared__ float BsF[32 * 136];
    const int tid = threadIdx.x;
    const int tx = tid & 15, ty = tid >> 4;    // tx 0..15, ty 0..31
    const int m0 = bm * 128, n0 = bn * 128;

    f32x2 acc2[4][4];
    #pragma unroll
    for (int i = 0; i < 4; ++i)
        #pragma unroll
        for (int p = 0; p < 4; ++p) acc2[i][p] = (f32x2){0.f, 0.f};

    for (int k0 = 0; k0 < 384; k0 += 32) {
        if (k0) __syncthreads();
        #pragma unroll
        for (int it = 0; it < 2; ++it) {
            int slot = tid + it * 512;
            int rA = slot >> 3, cA = slot & 7;          // A: 128 rows x 8 quads
            float4 av = *reinterpret_cast<const float4*>(&A[(long)(384 + m0 + rA) * 384 + k0 + cA * 4]);
            As[cA * 4 + 0][rA] = av.x; As[cA * 4 + 1][rA] = av.y;
            As[cA * 4 + 2][rA] = av.z; As[cA * 4 + 3][rA] = av.w;
            int sr = slot >> 5, sq = slot & 31;         // B: 32 rows x 32 quads
            int wB = sr * 136 + ((sq & 1) << 6) + ((sq >> 1) << 2);
            *reinterpret_cast<float4*>(&BsF[wB]) =
                *reinterpret_cast<const float4*>(&Bp[(long)(k0 + sr) * 4096 + n0 + sq * 4]);
        }
        __syncthreads();
        #pragma unroll
        for (int kk = 0; kk < 32; ++kk) {
            float a[4];
            *reinterpret_cast<float4*>(&a[0]) = *reinterpret_cast<const float4*>(&As[kk][ty * 4]);
            float4 blo = *reinterpret_cast<const float4*>(&BsF[kk * 136 + tx * 4]);
            float4 bhi = *reinterpret_cast<const float4*>(&BsF[kk * 136 + 64 + tx * 4]);
            f32x2 b2[4];
            b2[0] = (f32x2){blo.x, blo.y}; b2[1] = (f32x2){blo.z, blo.w};
            b2[2] = (f32x2){bhi.x, bhi.y}; b2[3] = (f32x2){bhi.z, bhi.w};
            #pragma unroll
            for (int i = 0; i < 4; ++i) {
                f32x2 a2 = (f32x2){a[i], a[i]};
                #pragma unroll
                for (int p = 0; p < 4; ++p)
                    acc2[i][p] = __builtin_elementwise_fma(a2, b2[p], acc2[i][p]);
            }
        }
    }

    float bv[4];
    #pragma unroll
    for (int i = 0; i < 4; ++i) bv[i] = bias[384 + m0 + ty * 4 + i];
    #pragma unroll
    for (int p = 0; p < 4; ++p)
        #pragma unroll
        for (int c = 0; c < 2; ++c) {
            int j = 2 * p + c;
            long tok = n0 + tx * 8 + j;
            float4 v = make_float4(acc2[0][p][c] + bv[0], acc2[1][p][c] + bv[1],
                                   acc2[2][p][c] + bv[2], acc2[3][p][c] + bv[3]);
            *reinterpret_cast<float4*>(Cp + tok * 384 + m0 + ty * 4) = v;
        }
}

// ---------------------------------------------------------------------------
// bf16 MFMA NT-GEMM: D[rowA][rowB] = sum_k A[rowA][k]*B[rowB][k], both k-contig.
// SM=0: store bf16 at C[t=colB][m=rowA] (ldc 768), bias by rowA  (QV proj)
// SM=1: store f32  at C[m=colB][t=rowA] (ldc 4096), bias by colB (out proj)
// SPLIT: A,B given as hi/lo bf16 pairs; 3-term product.
// ---------------------------------------------------------------------------
template<bool SPLIT, int SM>
__global__ __launch_bounds__(256)
void mfma_nt_kernel(const unsigned short* __restrict__ Ah, const unsigned short* __restrict__ Al,
                    const unsigned short* __restrict__ Bh, const unsigned short* __restrict__ Bl,
                    const float* __restrict__ bias, void* __restrict__ Cout,
                    int K, int lda, int ldb,
                    long strideAb, long strideBb, long strideCb)
{
    extern __shared__ unsigned short smem[];
    unsigned short* As  = smem;            // [128][40]
    unsigned short* Bs  = smem + 5120;
    unsigned short* Asl = smem + 10240;
    unsigned short* Bsl = smem + 15360;
    const int bm = blockIdx.x, bn = blockIdx.y, bz = blockIdx.z;
    const unsigned short* Ap = Ah + (long)bz * strideAb;
    const unsigned short* Bp = Bh + (long)bz * strideBb;
    const unsigned short* Alp = nullptr;
    const unsigned short* Blp = nullptr;
    if constexpr (SPLIT) {
        Alp = Al + (long)bz * strideAb;
        Blp = Bl + (long)bz * strideBb;
    }
    const int tid = threadIdx.x;
    const int lane = tid & 63, wid = tid >> 6;
    const int wr = wid >> 1, wc = wid & 1;
    const int l15 = lane & 15, l4 = lane >> 4;
    const int m0 = bm * 128, n0 = bn * 128;

    const f32x4 Z4 = {0.f, 0.f, 0.f, 0.f};
    f32x4 acc[4][4];
    #pragma unroll
    for (int i = 0; i < 4; ++i)
        #pragma unroll
        for (int j = 0; j < 4; ++j) acc[i][j] = Z4;

    for (int k0 = 0; k0 < K; k0 += 32) {
        if (k0) __syncthreads();
        #pragma unroll
        for (int it = 0; it < 2; ++it) {
            int slot = tid + it * 256;
            int r = slot >> 2, cq = slot & 3;
            *reinterpret_cast<uint4*>(&As[r * 40 + cq * 8]) =
                *reinterpret_cast<const uint4*>(&Ap[(long)(m0 + r) * lda + k0 + cq * 8]);
            *reinterpret_cast<uint4*>(&Bs[r * 40 + cq * 8]) =
                *reinterpret_cast<const uint4*>(&Bp[(long)(n0 + r) * ldb + k0 + cq * 8]);
            if constexpr (SPLIT) {
                *reinterpret_cast<uint4*>(&Asl[r * 40 + cq * 8]) =
                    *reinterpret_cast<const uint4*>(&Alp[(long)(m0 + r) * lda + k0 + cq * 8]);
                *reinterpret_cast<uint4*>(&Bsl[r * 40 + cq * 8]) =
                    *reinterpret_cast<const uint4*>(&Blp[(long)(n0 + r) * ldb + k0 + cq * 8]);
            }
        }
        __syncthreads();

        bf16x8 af[4], bg[4], afl[4], bgl[4];
        #pragma unroll
        for (int f = 0; f < 4; ++f) {
            af[f] = ldfrag(&As[(wr * 64 + f * 16 + l15) * 40 + l4 * 8]);
            bg[f] = ldfrag(&Bs[(wc * 64 + f * 16 + l15) * 40 + l4 * 8]);
        }
        if constexpr (SPLIT) {
            #pragma unroll
            for (int f = 0; f < 4; ++f) {
                afl[f] = ldfrag(&Asl[(wr * 64 + f * 16 + l15) * 40 + l4 * 8]);
                bgl[f] = ldfrag(&Bsl[(wc * 64 + f * 16 + l15) * 40 + l4 * 8]);
            }
        }
        #pragma unroll
        for (int fi = 0; fi < 4; ++fi)
            #pragma unroll
            for (int fj = 0; fj < 4; ++fj) {
                acc[fi][fj] = __builtin_amdgcn_mfma_f32_16x16x32_bf16(af[fi], bg[fj], acc[fi][fj], 0, 0, 0);
                if constexpr (SPLIT) {
                    acc[fi][fj] = __builtin_amdgcn_mfma_f32_16x16x32_bf16(af[fi], bgl[fj], acc[fi][fj], 0, 0, 0);
                    acc[fi][fj] = __builtin_amdgcn_mfma_f32_16x16x32_bf16(afl[fi], bg[fj], acc[fi][fj], 0, 0, 0);
                }
            }
    }

    if constexpr (SM == 0) {
        unsigned short* Cq = (unsigned short*)Cout + (long)bz * strideCb;
        #pragma unroll
        for (int fi = 0; fi < 4; ++fi)
            #pragma unroll
            for (int fj = 0; fj < 4; ++fj) {
                const int m = m0 + wr * 64 + fi * 16 + l4 * 4;
                const int t = n0 + wc * 64 + fj * 16 + l15;
                ushort4 h;
                h.x = f2bf(acc[fi][fj][0] + bias[m + 0]);
                h.y = f2bf(acc[fi][fj][1] + bias[m + 1]);
                h.z = f2bf(acc[fi][fj][2] + bias[m + 2]);
                h.w = f2bf(acc[fi][fj][3] + bias[m + 3]);
                *reinterpret_cast<ushort4*>(&Cq[(long)t * 768 + m]) = h;
            }
    } else {
        float* Cf = (float*)Cout + (long)bz * strideCb;
        #pragma unroll
        for (int fi = 0; fi < 4; ++fi)
            #pragma unroll
            for (int fj = 0; fj < 4; ++fj) {
                const int t = m0 + wr * 64 + fi * 16 + l4 * 4;
                const int m = n0 + wc * 64 + fj * 16 + l15;
                const float bv = bias[m];
                float4 v = make_float4(acc[fi][fj][0] + bv, acc[fi][fj][1] + bv,
                                       acc[fi][fj][2] + bv, acc[fi][fj][3] + bv);
                *reinterpret_cast<float4*>(&Cf[(long)m * 4096 + t]) = v;
            }
    }
}

// ---------------------------------------------------------------------------
// Weight conversion: Wqv bf16 (q,v rows of qkv_w), qv bias gather,
// out_w split hi/lo bf16.
// ---------------------------------------------------------------------------
__global__ __launch_bounds__(256)
void convert_w_kernel(const float* __restrict__ qkv_w, const float* __restrict__ qkv_b,
                      const float* __restrict__ out_w,
                      unsigned short* __restrict__ Wqv, float* __restrict__ qvb,
                      unsigned short* __restrict__ owh, unsigned short* __restrict__ owl)
{
    const int total = 294912 + 147456 + 768;
    for (int i = blockIdx.x * 256 + threadIdx.x; i < total; i += gridDim.x * 256) {
        if (i < 294912) {
            int m = i / 384, k = i - m * 384;
            int src = (m < 384) ? m : m + 384;
            Wqv[i] = f2bf(qkv_w[(long)src * 384 + k]);
        } else if (i < 294912 + 147456) {
            int o = i - 294912;
            float w = out_w[o];
            unsigned short h = f2bf(w);
            owh[o] = h;
            owl[o] = f2bf(w - bf2f(h));
        } else {
            int m = i - 294912 - 147456;
            qvb[m] = qkv_b[(m < 384) ? m : m + 384];
        }
    }
}

// ---------------------------------------------------------------------------
// x [b][384][4096] fp32 -> xbT [b][4096][384] bf16 (LDS 64x64 transpose)
// ---------------------------------------------------------------------------
__global__ __launch_bounds__(256)
void transpose_x_kernel(const float* __restrict__ x, unsigned short* __restrict__ xbT)
{
    const int t0 = blockIdx.x * 64, c0 = blockIdx.y * 64, b = blockIdx.z;
    __shared__ float tl[64][65];
    const int tid = threadIdx.x;
    #pragma unroll
    for (int i = 0; i < 16; ++i) {
        int cr = (tid >> 6) + i * 4, tc = tid & 63;
        tl[cr][tc] = x[((long)b * 384 + c0 + cr) * 4096 + t0 + tc];
    }
    __syncthreads();
    #pragma unroll
    for (int i = 0; i < 8; ++i) {
        int tr = (tid >> 5) + i * 8, c2 = (tid & 31) * 2;
        unsigned int u = packbf(tl[c2][tr], tl[c2 + 1][tr]);
        *reinterpret_cast<unsigned int*>(&xbT[((long)b * 4096 + t0 + tr) * 384 + c0 + c2]) = u;
    }
}

// ---------------------------------------------------------------------------
// Depthwise 5x5 conv (pad 2), v from qvB (bf16), out lepeT (bf16).
// Staging via uint4 (16B = 8 channels) loads instead of scalar 2B.
// ---------------------------------------------------------------------------
__global__ __launch_bounds__(256)
void lepe_kernel(const unsigned short* __restrict__ qvB, const float* __restrict__ w5,
                 const float* __restrict__ wb, unsigned short* __restrict__ lepeT)
{
    const int ch0 = blockIdx.x * 16;
    const int y0 = blockIdx.y * 8;
    const int b = blockIdx.z;
    const unsigned short* vb = qvB + (long)b * 4096 * 768 + 384 + ch0;
    unsigned short* dst = lepeT + (long)b * 4096 * 384 + ch0;
    __shared__ float tile[12 * 68 * 16];
    const int tid = threadIdx.x;

    for (int s = tid; s < 12 * 68 * 2; s += 256) {
        int pix = s >> 1, half = s & 1;
        int yy = pix / 68, xx = pix % 68;
        int gy = y0 + yy - 2, gx = xx - 2;
        float* tp = &tile[pix * 16 + half * 8];
        if (gy >= 0 && gy < 64 && gx >= 0 && gx < 64) {
            uint4 u = *reinterpret_cast<const uint4*>(vb + (long)(gy * 64 + gx) * 768 + half * 8);
            tp[0] = bf2f((unsigned short)(u.x & 0xFFFFu)); tp[1] = bf2f((unsigned short)(u.x >> 16));
            tp[2] = bf2f((unsigned short)(u.y & 0xFFFFu)); tp[3] = bf2f((unsigned short)(u.y >> 16));
            tp[4] = bf2f((unsigned short)(u.z & 0xFFFFu)); tp[5] = bf2f((unsigned short)(u.z >> 16));
            tp[6] = bf2f((unsigned short)(u.w & 0xFFFFu)); tp[7] = bf2f((unsigned short)(u.w >> 16));
        } else {
            #pragma unroll
            for (int j = 0; j < 8; ++j) tp[j] = 0.f;
        }
    }
    const int c = tid & 15, xo = tid >> 4;
    float f[25];
    #pragma unroll
    for (int j = 0; j < 25; ++j) f[j] = w5[(ch0 + c) * 25 + j];
    const float bv = wb[ch0 + c];
    __syncthreads();

    #pragma unroll
    for (int yy = 0; yy < 8; ++yy) {
        #pragma unroll
        for (int xq = 0; xq < 4; ++xq) {
            int x = xq * 16 + xo;
            float acc = bv;
            #pragma unroll
            for (int dy = 0; dy < 5; ++dy)
                #pragma unroll
                for (int dx = 0; dx < 5; ++dx)
                    acc += tile[((yy + dy) * 68 + (x + dx)) * 16 + c] * f[dy * 5 + dx];
            dst[(long)((y0 + yy) * 64 + x) * 384 + c] = f2bf(acc);
        }
    }
}

// ---------------------------------------------------------------------------
// cls kernel: per (b,n) normalized mean of k (bit-identical to prior cos
// kernel phase 1), written to clsg[bn*32+d].
// ---------------------------------------------------------------------------
__global__ __launch_bounds__(256)
void cls_kernel(const float* __restrict__ Kf32, float* __restrict__ clsg)
{
    const int bn = blockIdx.x;
    const int b = bn / 12, n = bn % 12;
    const float* kb = Kf32 + (long)b * 4096 * 384 + n * 32;
    __shared__ float part[256][33];
    const int tid = threadIdx.x;
    float acc[32];
    #pragma unroll
    for (int d = 0; d < 32; ++d) acc[d] = 0.f;
    for (int i = 0; i < 16; ++i) {
        long tok = tid + i * 256;
        const float* kr = kb + tok * 384;
        #pragma unroll
        for (int d = 0; d < 32; ++d) acc[d] += kr[d];
    }
    #pragma unroll
    for (int d = 0; d < 32; ++d) part[tid][d] = acc[d];
    __syncthreads();
    if (tid < 32) {
        double s = 0.0;
        for (int t = 0; t < 256; ++t) s += (double)part[t][tid];
        part[0][tid] = (float)s;
    }
    __syncthreads();
    if (tid == 0) {
        double nn = 0.0;
        for (int d = 0; d < 32; ++d) { double v = (double)part[0][d]; nn += v * v; }
        double inv = 1.0 / sqrt(nn > 1e-300 ? nn : 1e-300);
        for (int d = 0; d < 32; ++d) clsg[bn * 32 + d] = (float)((double)part[0][d] * inv);
    }
}

// ---------------------------------------------------------------------------
// cos2 kernel: per-token cosine (same fp64 math as before -> bit-identical
// cosv). grid (96, 8): 512 tokens per block for full occupancy.
// ---------------------------------------------------------------------------
__global__ __launch_bounds__(256)
void cos2_kernel(const float* __restrict__ Kf32, const float* __restrict__ clsg,
                 float* __restrict__ cosv)
{
    const int bn = blockIdx.x;
    const int b = bn / 12, n = bn % 12;
    const float* kb = Kf32 + (long)b * 4096 * 384 + n * 32;
    const int t0 = blockIdx.y * 512;
    const int tid = threadIdx.x;
    float clsn[32];
    #pragma unroll
    for (int d = 0; d < 32; ++d) clsn[d] = clsg[bn * 32 + d];
    #pragma unroll
    for (int i = 0; i < 2; ++i) {
        long tok = t0 + tid + i * 256;
        const float* kr = kb + tok * 384;
        double dot = 0.0, nrm = 0.0;
        #pragma unroll
        for (int d = 0; d < 32; ++d) {
            float kv = kr[d];
            dot += (double)clsn[d] * (double)kv;
            nrm += (double)kv * (double)kv;
        }
        double cv = dot / sqrt(nrm > 1e-300 ? nrm : 1e-300);
        cosv[(long)bn * 4096 + tok] = (float)cv;
    }
}

// ---------------------------------------------------------------------------
// Bitonic argsort ascending via packed u64 keys: (sortable32(cos)<<32)|idx.
// Ascending u64 == ascending (cos, idx) incl. stable tie-break -> output
// permutation bit-identical to the two-array version.
// ---------------------------------------------------------------------------
__global__ __launch_bounds__(1024)
void sort_kernel(const float* __restrict__ cosv, int* __restrict__ idxo)
{
    const int bn = blockIdx.x;
    __shared__ unsigned long long sk[4096];
    const int tid = threadIdx.x;
    for (int i = tid; i < 4096; i += 1024) {
        unsigned int u = __builtin_bit_cast(unsigned int, cosv[(long)bn * 4096 + i]);
        u = (u & 0x80000000u) ? ~u : (u | 0x80000000u);
        sk[i] = ((unsigned long long)u << 32) | (unsigned int)i;
    }
    __syncthreads();
    for (int size = 2; size <= 4096; size <<= 1) {
        for (int stride = size >> 1; stride >= 1; stride >>= 1) {
            #pragma unroll 2
            for (int i = tid; i < 2048; i += 1024) {
                int lo = (i << 1) - (i & (stride - 1));
                int hi = lo + stride;
                bool asc = ((lo & size) == 0);
                unsigned long long a = sk[lo], bq = sk[hi];
                if ((a > bq) == asc) { sk[lo] = bq; sk[hi] = a; }
            }
            __syncthreads();
        }
    }
    for (int i = tid; i < 4096; i += 1024)
        idxo[(long)bn * 4096 + i] = (int)(sk[i] & 0xFFFFFFFFu);
}

// ---------------------------------------------------------------------------
// MFMA clustered attention. grid (16,12,8), 256 thr = 4 waves.
// K staged as bf16(k * SCALE * log2e) -> scores in log2 domain, p = exp2(s).
// s_setprio(1) around MFMA clusters (T5).
// ---------------------------------------------------------------------------
__global__ __launch_bounds__(256)
void attn_kernel(const float* __restrict__ Kf32, unsigned short* __restrict__ qvB,
                 const int* __restrict__ idxbuf, const unsigned short* __restrict__ lepeT)
{
    const int cc = blockIdx.x, n = blockIdx.y, b = blockIdx.z;
    const int* ip = idxbuf + ((long)(b * 12 + n)) * 4096 + cc * 256;

    __shared__ unsigned short KsL[256][36];
    __shared__ unsigned short VsT[32][260];
    __shared__ int tokLds[256];

    const int tid = threadIdx.x;
    const int w = tid >> 6;
    const int lane = tid & 63;
    const int lo5 = lane & 31;
    const int hi = lane >> 5;
    const int hi8 = hi * 8;

    // ---- gather ----
    const int tk0 = ip[tid];
    tokLds[tid] = tk0;
    const long tb = (long)b * 4096 + tk0;
    const unsigned short* qrow = qvB + tb * 768 + n * 32;
    const float* krow = Kf32 + tb * 384 + n * 32;

    unsigned int Pq[16];
    #pragma unroll
    for (int i = 0; i < 4; ++i) {
        uint4 qu = *reinterpret_cast<const uint4*>(qrow + i * 8);
        Pq[4 * i + 0] = qu.x; Pq[4 * i + 1] = qu.y;
        Pq[4 * i + 2] = qu.z; Pq[4 * i + 3] = qu.w;
    }
    #pragma unroll
    for (int dq = 0; dq < 8; ++dq) {
        float4 kv = *reinterpret_cast<const float4*>(krow + dq * 4);
        ushort4 kp;
        kp.x = f2bf(kv.x * SCALE_L2E); kp.y = f2bf(kv.y * SCALE_L2E);
        kp.z = f2bf(kv.z * SCALE_L2E); kp.w = f2bf(kv.w * SCALE_L2E);
        *reinterpret_cast<ushort4*>(&KsL[tid][dq * 4]) = kp;
    }
    {
        union { uint4 u[4]; unsigned short s[32]; } vv;
        const unsigned short* vrow = qrow + 384;
        #pragma unroll
        for (int i = 0; i < 4; ++i) vv.u[i] = *reinterpret_cast<const uint4*>(vrow + i * 8);
        #pragma unroll
        for (int j = 0; j < 32; ++j) VsT[j][tid] = vv.s[j];
    }

    // ---- Q B-frags from own registers via permlane32_swap ----
    bf16x8 qf00, qf01, qf10, qf11;
    {
        unsigned int w0[2][4], w1[2][4];
        #pragma unroll
        for (int ks = 0; ks < 2; ++ks)
            #pragma unroll
            for (int j = 0; j < 4; ++j) {
                uint2e r = __builtin_amdgcn_permlane32_swap(Pq[ks * 8 + j], Pq[ks * 8 + 4 + j], false, false);
                w0[ks][j] = r[0];
                w1[ks][j] = r[1];
            }
        qf00 = __builtin_bit_cast(bf16x8, make_uint4(w0[0][0], w0[0][1], w0[0][2], w0[0][3]));
        qf01 = __builtin_bit_cast(bf16x8, make_uint4(w0[1][0], w0[1][1], w0[1][2], w0[1][3]));
        qf10 = __builtin_bit_cast(bf16x8, make_uint4(w1[0][0], w1[0][1], w1[0][2], w1[0][3]));
        qf11 = __builtin_bit_cast(bf16x8, make_uint4(w1[1][0], w1[1][1], w1[1][2], w1[1][3]));
    }
    __syncthreads();

    const f32x16 Z16 = {0,0,0,0,0,0,0,0,0,0,0,0,0,0,0,0};
    f32x16 o0 = Z16, o1 = Z16;
    float lsum0 = 0.f, lsum1 = 0.f;

#define LDFRAG(ARR, ROW, OFF) ({ \
    const unsigned short* _p = &ARR[ROW][OFF]; \
    union { bf16x8 v; ushort4 h[2]; } _u; \
    _u.h[0] = *reinterpret_cast<const ushort4*>(_p); \
    _u.h[1] = *reinterpret_cast<const ushort4*>(_p + 4); \
    _u.v; })

#define EXP16(S, LS) { _Pragma("unroll") for (int r = 0; r < 16; ++r) { float _e = __builtin_exp2f(S[r]); S[r] = _e; LS += _e; } }

#define MKPB(S, H) ({ \
    unsigned int _x0 = packbf(S[(H) * 8 + 0], S[(H) * 8 + 1]); \
    unsigned int _x1 = packbf(S[(H) * 8 + 2], S[(H) * 8 + 3]); \
    unsigned int _x2 = packbf(S[(H) * 8 + 4], S[(H) * 8 + 5]); \
    unsigned int _x3 = packbf(S[(H) * 8 + 6], S[(H) * 8 + 7]); \
    uint2e _r02 = __builtin_amdgcn_permlane32_swap(_x0, _x2, false, false); \
    uint2e _r13 = __builtin_amdgcn_permlane32_swap(_x1, _x3, false, false); \
    __builtin_bit_cast(bf16x8, make_uint4(_r02[0], _r13[0], _r02[1], _r13[1])); })

    for (int ch = 0; ch < 4; ++ch) {
        const int rb = ch * 64;
        f32x16 s00 = Z16, s01 = Z16, s10 = Z16, s11 = Z16;
        bf16x8 ka;
        __builtin_amdgcn_s_setprio(1);
        ka = LDFRAG(KsL, rb + lo5, hi8);
        s00 = __builtin_amdgcn_mfma_f32_32x32x16_bf16(ka, qf00, s00, 0, 0, 0);
        s01 = __builtin_amdgcn_mfma_f32_32x32x16_bf16(ka, qf10, s01, 0, 0, 0);
        ka = LDFRAG(KsL, rb + lo5, 16 + hi8);
        s00 = __builtin_amdgcn_mfma_f32_32x32x16_bf16(ka, qf01, s00, 0, 0, 0);
        s01 = __builtin_amdgcn_mfma_f32_32x32x16_bf16(ka, qf11, s01, 0, 0, 0);
        ka = LDFRAG(KsL, rb + 32 + lo5, hi8);
        s10 = __builtin_amdgcn_mfma_f32_32x32x16_bf16(ka, qf00, s10, 0, 0, 0);
        s11 = __builtin_amdgcn_mfma_f32_32x32x16_bf16(ka, qf10, s11, 0, 0, 0);
        ka = LDFRAG(KsL, rb + 32 + lo5, 16 + hi8);
        s10 = __builtin_amdgcn_mfma_f32_32x32x16_bf16(ka, qf01, s10, 0, 0, 0);
        s11 = __builtin_amdgcn_mfma_f32_32x32x16_bf16(ka, qf11, s11, 0, 0, 0);
        __builtin_amdgcn_s_setprio(0);

        EXP16(s00, lsum0); EXP16(s01, lsum1);
        EXP16(s10, lsum0); EXP16(s11, lsum1);

        bf16x8 va, pb0, pb1;
        __builtin_amdgcn_s_setprio(1);
        va = LDFRAG(VsT, lo5, rb + 0 + hi8);
        pb0 = MKPB(s00, 0); pb1 = MKPB(s01, 0);
        o0 = __builtin_amdgcn_mfma_f32_32x32x16_bf16(va, pb0, o0, 0, 0, 0);
        o1 = __builtin_amdgcn_mfma_f32_32x32x16_bf16(va, pb1, o1, 0, 0, 0);
        va = LDFRAG(VsT, lo5, rb + 16 + hi8);
        pb0 = MKPB(s00, 1); pb1 = MKPB(s01, 1);
        o0 = __builtin_amdgcn_mfma_f32_32x32x16_bf16(va, pb0, o0, 0, 0, 0);
        o1 = __builtin_amdgcn_mfma_f32_32x32x16_bf16(va, pb1, o1, 0, 0, 0);
        va = LDFRAG(VsT, lo5, rb + 32 + hi8);
        pb0 = MKPB(s10, 0); pb1 = MKPB(s11, 0);
        o0 = __builtin_amdgcn_mfma_f32_32x32x16_bf16(va, pb0, o0, 0, 0, 0);
        o1 = __builtin_amdgcn_mfma_f32_32x32x16_bf16(va, pb1, o1, 0, 0, 0);
        va = LDFRAG(VsT, lo5, rb + 48 + hi8);
        pb0 = MKPB(s10, 1); pb1 = MKPB(s11, 1);
        o0 = __builtin_amdgcn_mfma_f32_32x32x16_bf16(va, pb0, o0, 0, 0, 0);
        o1 = __builtin_amdgcn_mfma_f32_32x32x16_bf16(va, pb1, o1, 0, 0, 0);
        __builtin_amdgcn_s_setprio(0);
    }

    // ---- epilogue: res = o/l + lepe -> bf16 hi/lo into qvB ----
    const float lf0 = lsum0 + __shfl_xor(lsum0, 32);
    const float lf1 = lsum1 + __shfl_xor(lsum1, 32);
    const float li0 = 1.f / lf0, li1 = 1.f / lf1;

    #pragma unroll
    for (int qt = 0; qt < 2; ++qt) {
        const int qrix = w * 64 + qt * 32 + lo5;
        const int tk = tokLds[qrix];
        const long tb2 = (long)b * 4096 + tk;
        unsigned short* resrow = qvB + tb2 * 768;
        const unsigned short* lp = lepeT + tb2 * 384 + n * 32;
        const float li = qt ? li1 : li0;
        const f32x16& oo = qt ? o1 : o0;
        #pragma unroll
        for (int qd = 0; qd < 4; ++qd) {
            const int d0 = qd * 8 + hi * 4;
            ushort4 lv = *reinterpret_cast<const ushort4*>(lp + d0);
            float r0 = oo[qd * 4 + 0] * li + bf2f(lv.x);
            float r1 = oo[qd * 4 + 1] * li + bf2f(lv.y);
            float r2 = oo[qd * 4 + 2] * li + bf2f(lv.z);
            float r3 = oo[qd * 4 + 3] * li + bf2f(lv.w);
            unsigned short h0 = f2bf(r0), h1 = f2bf(r1), h2 = f2bf(r2), h3 = f2bf(r3);
            ushort4 hh = {h0, h1, h2, h3};
            ushort4 ll = {f2bf(r0 - bf2f(h0)), f2bf(r1 - bf2f(h1)),
                          f2bf(r2 - bf2f(h2)), f2bf(r3 - bf2f(h3))};
            *reinterpret_cast<ushort4*>(resrow + n * 32 + d0) = hh;
            *reinterpret_cast<ushort4*>(resrow + 384 + n * 32 + d0) = ll;
        }
    }
#undef LDFRAG
#undef EXP16
#undef MKPB
}

// ---------------------------------------------------------------------------
extern "C" void kernel_launch(void* const* d_in, const int* in_sizes, int n_in,
                              void* d_out, int out_size, void* d_ws, size_t ws_size,
                              hipStream_t stream)
{
    const float* x      = (const float*)d_in[0];
    const float* qkv_w  = (const float*)d_in[1];
    const float* qkv_b  = (const float*)d_in[2];
    const float* lepe_w = (const float*)d_in[3];
    const float* lepe_b = (const float*)d_in[4];
    const float* out_w  = (const float*)d_in[5];
    const float* out_b  = (const float*)d_in[6];
    float* out = (float*)d_out;

    char* ws = (char*)d_ws;
    float*          Kf32 = (float*)ws;                                  // 50331648 B
    unsigned short* qvB  = (unsigned short*)(ws + 50331648);            // 50331648 B
    float*          cosv = (float*)(ws + 100663296);                    // 1572864 B
    int*            idx  = (int*)(ws + 102236160);                      // 1572864 B
    unsigned short* Wqv  = (unsigned short*)(ws + 103809024);           // 589824 B
    unsigned short* owh  = (unsigned short*)(ws + 104398848);           // 294912 B
    unsigned short* owl  = (unsigned short*)(ws + 104693760);           // 294912 B
    float*          qvb  = (float*)(ws + 104988672);                    // 3072 B
    float*          clsg = (float*)(ws + 104991744);                    // 12288 B

    unsigned short* xbT   = (unsigned short*)d_out;                     // dead before out-proj
    unsigned short* lepeT = (unsigned short*)d_out + 12582912;          // dead before out-proj

    // 1) weight conversions
    convert_w_kernel<<<1731, 256, 0, stream>>>(qkv_w, qkv_b, out_w, Wqv, qvb, owh, owl);
    // 2) x -> token-major bf16
    transpose_x_kernel<<<dim3(64, 6, 8), 256, 0, stream>>>(x, xbT);
    // 3) k projection, exact fp32 (per-output accumulation bit-identical)
    gemm_k_kernel<<<dim3(3, 32, 8), 512, 0, stream>>>(qkv_w, x, qkv_b, Kf32);
    // 4) q,v projection, bf16 MFMA -> qvB [b][t][768] bf16
    mfma_nt_kernel<false, 0><<<dim3(6, 32, 8), 256, 20480, stream>>>(
        Wqv, nullptr, xbT, nullptr, qvb, qvB,
        384, 384, 384, 0L, (long)4096 * 384, (long)4096 * 768);
    // 5) LePE depthwise conv (v bf16 -> lepeT bf16)
    lepe_kernel<<<dim3(24, 8, 8), 256, 0, stream>>>(qvB, lepe_w, lepe_b, lepeT);
    // 6) class-mean (bit-identical) then per-token cosine at full occupancy
    cls_kernel<<<96, 256, 0, stream>>>(Kf32, clsg);
    cos2_kernel<<<dim3(96, 8), 256, 0, stream>>>(Kf32, clsg, cosv);
    // 7) stable ascending argsort (u64-packed bitonic, identical permutation)
    sort_kernel<<<96, 1024, 0, stream>>>(cosv, idx);
    // 8) clustered attention + lepe residual; res -> bf16 hi/lo over qvB
    attn_kernel<<<dim3(16, 12, 8), 256, 0, stream>>>(Kf32, qvB, idx, lepeT);
    // 9) output projection, split-bf16 (3-term) MFMA -> out
    mfma_nt_kernel<true, 1><<<dim3(32, 3, 8), 256, 40960, stream>>>(
        qvB, qvB + 384, owh, owl, out_b, out,
        384, 768, 384, (long)4096 * 768, 0L, (long)384 * 4096);
}

// Round 12
// 395.631 us; speedup vs baseline: 1.1340x; 1.0143x over previous
//
#include <hip/hip_runtime.h>
#include <math.h>

#define SCALE_F   0.17677669529663687f   // 32^-0.5
#define SCALE_L2E 0.25505837072959003f   // 32^-0.5 * log2(e)

using bf16x8 = __attribute__((ext_vector_type(8))) __bf16;
using f32x2  = __attribute__((ext_vector_type(2))) float;
using f32x4  = __attribute__((ext_vector_type(4))) float;
using f32x16 = __attribute__((ext_vector_type(16))) float;
using uint2e = __attribute__((ext_vector_type(2))) unsigned int;

__device__ inline unsigned short f2bf(float x) {
    __bf16 h = (__bf16)x;                       // HW v_cvt (RNE)
    return __builtin_bit_cast(unsigned short, h);
}
__device__ inline float bf2f(unsigned short u) {
    unsigned int x = ((unsigned int)u) << 16;
    return __builtin_bit_cast(float, x);
}
__device__ inline unsigned int packbf(float a, float b) {
    return (unsigned int)f2bf(a) | ((unsigned int)f2bf(b) << 16);
}
__device__ inline bf16x8 ldfrag(const unsigned short* p) {
    return __builtin_bit_cast(bf16x8, *reinterpret_cast<const uint4*>(p));
}

// ---------------------------------------------------------------------------
// fp32 k-projection GEMM. BM=128, BN=128, BK=32, 512 thr, 4x8 micro-tile.
// B-tile register prefetch: next tile's global loads issue right after the
// staging barrier and land during compute (hides HBM latency; +8 VGPR only —
// A stays direct-path, it's L2-hot weight data).
// Each output's accumulation remains ONE fma chain over k ascending ->
// k values bit-identical to all previous passing rounds (argsort-safe).
// ---------------------------------------------------------------------------
__global__ __launch_bounds__(512)
void gemm_k_kernel(const float* __restrict__ A, const float* __restrict__ Bmat,
                   const float* __restrict__ bias, float* __restrict__ CT)
{
    const int bm = blockIdx.x, bn = blockIdx.y, bz = blockIdx.z;
    const float* Bp = Bmat + (long)bz * 384 * 4096;
    float* Cp = CT + (long)bz * 4096 * 384;
    __shared__ float As[32][132];
    __shared__ float BsF[32 * 136];
    const int tid = threadIdx.x;
    const int tx = tid & 15, ty = tid >> 4;    // tx 0..15, ty 0..31
    const int m0 = bm * 128, n0 = bn * 128;

    const int sr0 = tid >> 5,          sq0 = tid & 31;
    const int sr1 = (tid + 512) >> 5,  sq1 = (tid + 512) & 31;
    const int wB0 = sr0 * 136 + ((sq0 & 1) << 6) + ((sq0 >> 1) << 2);
    const int wB1 = sr1 * 136 + ((sq1 & 1) << 6) + ((sq1 >> 1) << 2);

    f32x2 acc2[4][4];
    #pragma unroll
    for (int i = 0; i < 4; ++i)
        #pragma unroll
        for (int p = 0; p < 4; ++p) acc2[i][p] = (f32x2){0.f, 0.f};

    // prologue: prefetch B tile 0
    float4 bPf0 = *reinterpret_cast<const float4*>(&Bp[(long)sr0 * 4096 + n0 + sq0 * 4]);
    float4 bPf1 = *reinterpret_cast<const float4*>(&Bp[(long)sr1 * 4096 + n0 + sq1 * 4]);

    for (int k0 = 0; k0 < 384; k0 += 32) {
        if (k0) __syncthreads();                 // all readers done with prev tile
        // commit prefetched B
        *reinterpret_cast<float4*>(&BsF[wB0]) = bPf0;
        *reinterpret_cast<float4*>(&BsF[wB1]) = bPf1;
        // A staged directly (L2-hot weights)
        #pragma unroll
        for (int it = 0; it < 2; ++it) {
            int slot = tid + it * 512;
            int rA = slot >> 3, cA = slot & 7;
            float4 av = *reinterpret_cast<const float4*>(&A[(long)(384 + m0 + rA) * 384 + k0 + cA * 4]);
            As[cA * 4 + 0][rA] = av.x; As[cA * 4 + 1][rA] = av.y;
            As[cA * 4 + 2][rA] = av.z; As[cA * 4 + 3][rA] = av.w;
        }
        __syncthreads();
        // prefetch next B while computing this tile
        if (k0 + 32 < 384) {
            bPf0 = *reinterpret_cast<const float4*>(&Bp[(long)(k0 + 32 + sr0) * 4096 + n0 + sq0 * 4]);
            bPf1 = *reinterpret_cast<const float4*>(&Bp[(long)(k0 + 32 + sr1) * 4096 + n0 + sq1 * 4]);
        }
        #pragma unroll
        for (int kk = 0; kk < 32; ++kk) {
            float a[4];
            *reinterpret_cast<float4*>(&a[0]) = *reinterpret_cast<const float4*>(&As[kk][ty * 4]);
            float4 blo = *reinterpret_cast<const float4*>(&BsF[kk * 136 + tx * 4]);
            float4 bhi = *reinterpret_cast<const float4*>(&BsF[kk * 136 + 64 + tx * 4]);
            f32x2 b2[4];
            b2[0] = (f32x2){blo.x, blo.y}; b2[1] = (f32x2){blo.z, blo.w};
            b2[2] = (f32x2){bhi.x, bhi.y}; b2[3] = (f32x2){bhi.z, bhi.w};
            #pragma unroll
            for (int i = 0; i < 4; ++i) {
                f32x2 a2 = (f32x2){a[i], a[i]};
                #pragma unroll
                for (int p = 0; p < 4; ++p)
                    acc2[i][p] = __builtin_elementwise_fma(a2, b2[p], acc2[i][p]);
            }
        }
    }

    float bv[4];
    #pragma unroll
    for (int i = 0; i < 4; ++i) bv[i] = bias[384 + m0 + ty * 4 + i];
    #pragma unroll
    for (int p = 0; p < 4; ++p)
        #pragma unroll
        for (int c = 0; c < 2; ++c) {
            int j = 2 * p + c;
            long tok = n0 + tx * 8 + j;
            float4 v = make_float4(acc2[0][p][c] + bv[0], acc2[1][p][c] + bv[1],
                                   acc2[2][p][c] + bv[2], acc2[3][p][c] + bv[3]);
            *reinterpret_cast<float4*>(Cp + tok * 384 + m0 + ty * 4) = v;
        }
}

// ---------------------------------------------------------------------------
// bf16 MFMA NT-GEMM: D[rowA][rowB] = sum_k A[rowA][k]*B[rowB][k], both k-contig.
// SM=0: store bf16 at C[t=colB][m=rowA] (ldc 768), bias by rowA  (QV proj)
// SM=1: store f32  at C[m=colB][t=rowA] (ldc 4096), bias by colB (out proj)
// SPLIT: A,B given as hi/lo bf16 pairs; 3-term product.
// ---------------------------------------------------------------------------
template<bool SPLIT, int SM>
__global__ __launch_bounds__(256)
void mfma_nt_kernel(const unsigned short* __restrict__ Ah, const unsigned short* __restrict__ Al,
                    const unsigned short* __restrict__ Bh, const unsigned short* __restrict__ Bl,
                    const float* __restrict__ bias, void* __restrict__ Cout,
                    int K, int lda, int ldb,
                    long strideAb, long strideBb, long strideCb)
{
    extern __shared__ unsigned short smem[];
    unsigned short* As  = smem;            // [128][40]
    unsigned short* Bs  = smem + 5120;
    unsigned short* Asl = smem + 10240;
    unsigned short* Bsl = smem + 15360;
    const int bm = blockIdx.x, bn = blockIdx.y, bz = blockIdx.z;
    const unsigned short* Ap = Ah + (long)bz * strideAb;
    const unsigned short* Bp = Bh + (long)bz * strideBb;
    const unsigned short* Alp = nullptr;
    const unsigned short* Blp = nullptr;
    if constexpr (SPLIT) {
        Alp = Al + (long)bz * strideAb;
        Blp = Bl + (long)bz * strideBb;
    }
    const int tid = threadIdx.x;
    const int lane = tid & 63, wid = tid >> 6;
    const int wr = wid >> 1, wc = wid & 1;
    const int l15 = lane & 15, l4 = lane >> 4;
    const int m0 = bm * 128, n0 = bn * 128;

    const f32x4 Z4 = {0.f, 0.f, 0.f, 0.f};
    f32x4 acc[4][4];
    #pragma unroll
    for (int i = 0; i < 4; ++i)
        #pragma unroll
        for (int j = 0; j < 4; ++j) acc[i][j] = Z4;

    for (int k0 = 0; k0 < K; k0 += 32) {
        if (k0) __syncthreads();
        #pragma unroll
        for (int it = 0; it < 2; ++it) {
            int slot = tid + it * 256;
            int r = slot >> 2, cq = slot & 3;
            *reinterpret_cast<uint4*>(&As[r * 40 + cq * 8]) =
                *reinterpret_cast<const uint4*>(&Ap[(long)(m0 + r) * lda + k0 + cq * 8]);
            *reinterpret_cast<uint4*>(&Bs[r * 40 + cq * 8]) =
                *reinterpret_cast<const uint4*>(&Bp[(long)(n0 + r) * ldb + k0 + cq * 8]);
            if constexpr (SPLIT) {
                *reinterpret_cast<uint4*>(&Asl[r * 40 + cq * 8]) =
                    *reinterpret_cast<const uint4*>(&Alp[(long)(m0 + r) * lda + k0 + cq * 8]);
                *reinterpret_cast<uint4*>(&Bsl[r * 40 + cq * 8]) =
                    *reinterpret_cast<const uint4*>(&Blp[(long)(n0 + r) * ldb + k0 + cq * 8]);
            }
        }
        __syncthreads();

        bf16x8 af[4], bg[4], afl[4], bgl[4];
        #pragma unroll
        for (int f = 0; f < 4; ++f) {
            af[f] = ldfrag(&As[(wr * 64 + f * 16 + l15) * 40 + l4 * 8]);
            bg[f] = ldfrag(&Bs[(wc * 64 + f * 16 + l15) * 40 + l4 * 8]);
        }
        if constexpr (SPLIT) {
            #pragma unroll
            for (int f = 0; f < 4; ++f) {
                afl[f] = ldfrag(&Asl[(wr * 64 + f * 16 + l15) * 40 + l4 * 8]);
                bgl[f] = ldfrag(&Bsl[(wc * 64 + f * 16 + l15) * 40 + l4 * 8]);
            }
        }
        #pragma unroll
        for (int fi = 0; fi < 4; ++fi)
            #pragma unroll
            for (int fj = 0; fj < 4; ++fj) {
                acc[fi][fj] = __builtin_amdgcn_mfma_f32_16x16x32_bf16(af[fi], bg[fj], acc[fi][fj], 0, 0, 0);
                if constexpr (SPLIT) {
                    acc[fi][fj] = __builtin_amdgcn_mfma_f32_16x16x32_bf16(af[fi], bgl[fj], acc[fi][fj], 0, 0, 0);
                    acc[fi][fj] = __builtin_amdgcn_mfma_f32_16x16x32_bf16(afl[fi], bg[fj], acc[fi][fj], 0, 0, 0);
                }
            }
    }

    if constexpr (SM == 0) {
        unsigned short* Cq = (unsigned short*)Cout + (long)bz * strideCb;
        #pragma unroll
        for (int fi = 0; fi < 4; ++fi)
            #pragma unroll
            for (int fj = 0; fj < 4; ++fj) {
                const int m = m0 + wr * 64 + fi * 16 + l4 * 4;
                const int t = n0 + wc * 64 + fj * 16 + l15;
                ushort4 h;
                h.x = f2bf(acc[fi][fj][0] + bias[m + 0]);
                h.y = f2bf(acc[fi][fj][1] + bias[m + 1]);
                h.z = f2bf(acc[fi][fj][2] + bias[m + 2]);
                h.w = f2bf(acc[fi][fj][3] + bias[m + 3]);
                *reinterpret_cast<ushort4*>(&Cq[(long)t * 768 + m]) = h;
            }
    } else {
        float* Cf = (float*)Cout + (long)bz * strideCb;
        #pragma unroll
        for (int fi = 0; fi < 4; ++fi)
            #pragma unroll
            for (int fj = 0; fj < 4; ++fj) {
                const int t = m0 + wr * 64 + fi * 16 + l4 * 4;
                const int m = n0 + wc * 64 + fj * 16 + l15;
                const float bv = bias[m];
                float4 v = make_float4(acc[fi][fj][0] + bv, acc[fi][fj][1] + bv,
                                       acc[fi][fj][2] + bv, acc[fi][fj][3] + bv);
                *reinterpret_cast<float4*>(&Cf[(long)m * 4096 + t]) = v;
            }
    }
}

// ---------------------------------------------------------------------------
// Weight conversion: Wqv bf16 (q,v rows of qkv_w), qv bias gather,
// out_w split hi/lo bf16.
// ---------------------------------------------------------------------------
__global__ __launch_bounds__(256)
void convert_w_kernel(const float* __restrict__ qkv_w, const float* __restrict__ qkv_b,
                      const float* __restrict__ out_w,
                      unsigned short* __restrict__ Wqv, float* __restrict__ qvb,
                      unsigned short* __restrict__ owh, unsigned short* __restrict__ owl)
{
    const int total = 294912 + 147456 + 768;
    for (int i = blockIdx.x * 256 + threadIdx.x; i < total; i += gridDim.x * 256) {
        if (i < 294912) {
            int m = i / 384, k = i - m * 384;
            int src = (m < 384) ? m : m + 384;
            Wqv[i] = f2bf(qkv_w[(long)src * 384 + k]);
        } else if (i < 294912 + 147456) {
            int o = i - 294912;
            float w = out_w[o];
            unsigned short h = f2bf(w);
            owh[o] = h;
            owl[o] = f2bf(w - bf2f(h));
        } else {
            int m = i - 294912 - 147456;
            qvb[m] = qkv_b[(m < 384) ? m : m + 384];
        }
    }
}

// ---------------------------------------------------------------------------
// x [b][384][4096] fp32 -> xbT [b][4096][384] bf16 (LDS 64x64 transpose)
// ---------------------------------------------------------------------------
__global__ __launch_bounds__(256)
void transpose_x_kernel(const float* __restrict__ x, unsigned short* __restrict__ xbT)
{
    const int t0 = blockIdx.x * 64, c0 = blockIdx.y * 64, b = blockIdx.z;
    __shared__ float tl[64][65];
    const int tid = threadIdx.x;
    #pragma unroll
    for (int i = 0; i < 16; ++i) {
        int cr = (tid >> 6) + i * 4, tc = tid & 63;
        tl[cr][tc] = x[((long)b * 384 + c0 + cr) * 4096 + t0 + tc];
    }
    __syncthreads();
    #pragma unroll
    for (int i = 0; i < 8; ++i) {
        int tr = (tid >> 5) + i * 8, c2 = (tid & 31) * 2;
        unsigned int u = packbf(tl[c2][tr], tl[c2 + 1][tr]);
        *reinterpret_cast<unsigned int*>(&xbT[((long)b * 4096 + t0 + tr) * 384 + c0 + c2]) = u;
    }
}

// ---------------------------------------------------------------------------
// cls kernel: per (b,n) normalized mean of k (bit-identical math).
// ---------------------------------------------------------------------------
__global__ __launch_bounds__(256)
void cls_kernel(const float* __restrict__ Kf32, float* __restrict__ clsg)
{
    const int bn = blockIdx.x;
    const int b = bn / 12, n = bn % 12;
    const float* kb = Kf32 + (long)b * 4096 * 384 + n * 32;
    __shared__ float part[256][33];
    const int tid = threadIdx.x;
    float acc[32];
    #pragma unroll
    for (int d = 0; d < 32; ++d) acc[d] = 0.f;
    for (int i = 0; i < 16; ++i) {
        long tok = tid + i * 256;
        const float* kr = kb + tok * 384;
        #pragma unroll
        for (int d = 0; d < 32; ++d) acc[d] += kr[d];
    }
    #pragma unroll
    for (int d = 0; d < 32; ++d) part[tid][d] = acc[d];
    __syncthreads();
    if (tid < 32) {
        double s = 0.0;
        for (int t = 0; t < 256; ++t) s += (double)part[t][tid];
        part[0][tid] = (float)s;
    }
    __syncthreads();
    if (tid == 0) {
        double nn = 0.0;
        for (int d = 0; d < 32; ++d) { double v = (double)part[0][d]; nn += v * v; }
        double inv = 1.0 / sqrt(nn > 1e-300 ? nn : 1e-300);
        for (int d = 0; d < 32; ++d) clsg[bn * 32 + d] = (float)((double)part[0][d] * inv);
    }
}

// ---------------------------------------------------------------------------
// Merged lepe + cos2 kernel (independent ops, one dispatch -> co-scheduled).
// Blocks 0..1535: depthwise 5x5 conv. Blocks 1536..2303: per-token cosine.
// Both bodies identical math to round-11's standalone kernels.
// ---------------------------------------------------------------------------
__global__ __launch_bounds__(256)
void cos_lepe_kernel(const float* __restrict__ Kf32, const float* __restrict__ clsg,
                     float* __restrict__ cosv,
                     const unsigned short* __restrict__ qvB, const float* __restrict__ w5,
                     const float* __restrict__ wb, unsigned short* __restrict__ lepeT)
{
    __shared__ float tile[12 * 68 * 16];
    const int bid = blockIdx.x;
    const int tid = threadIdx.x;

    if (bid < 1536) {
        // ---- lepe role ----
        const int ch0 = (bid % 24) * 16;
        const int y0 = ((bid / 24) % 8) * 8;
        const int b = bid / 192;
        const unsigned short* vb = qvB + (long)b * 4096 * 768 + 384 + ch0;
        unsigned short* dst = lepeT + (long)b * 4096 * 384 + ch0;

        for (int s = tid; s < 12 * 68 * 2; s += 256) {
            int pix = s >> 1, half = s & 1;
            int yy = pix / 68, xx = pix % 68;
            int gy = y0 + yy - 2, gx = xx - 2;
            float* tp = &tile[pix * 16 + half * 8];
            if (gy >= 0 && gy < 64 && gx >= 0 && gx < 64) {
                uint4 u = *reinterpret_cast<const uint4*>(vb + (long)(gy * 64 + gx) * 768 + half * 8);
                tp[0] = bf2f((unsigned short)(u.x & 0xFFFFu)); tp[1] = bf2f((unsigned short)(u.x >> 16));
                tp[2] = bf2f((unsigned short)(u.y & 0xFFFFu)); tp[3] = bf2f((unsigned short)(u.y >> 16));
                tp[4] = bf2f((unsigned short)(u.z & 0xFFFFu)); tp[5] = bf2f((unsigned short)(u.z >> 16));
                tp[6] = bf2f((unsigned short)(u.w & 0xFFFFu)); tp[7] = bf2f((unsigned short)(u.w >> 16));
            } else {
                #pragma unroll
                for (int j = 0; j < 8; ++j) tp[j] = 0.f;
            }
        }
        const int c = tid & 15, xo = tid >> 4;
        float f[25];
        #pragma unroll
        for (int j = 0; j < 25; ++j) f[j] = w5[(ch0 + c) * 25 + j];
        const float bv = wb[ch0 + c];
        __syncthreads();

        #pragma unroll
        for (int yy = 0; yy < 8; ++yy) {
            #pragma unroll
            for (int xq = 0; xq < 4; ++xq) {
                int x = xq * 16 + xo;
                float acc = bv;
                #pragma unroll
                for (int dy = 0; dy < 5; ++dy)
                    #pragma unroll
                    for (int dx = 0; dx < 5; ++dx)
                        acc += tile[((yy + dy) * 68 + (x + dx)) * 16 + c] * f[dy * 5 + dx];
                dst[(long)((y0 + yy) * 64 + x) * 384 + c] = f2bf(acc);
            }
        }
    } else {
        // ---- cos2 role ----
        const int cb = bid - 1536;
        const int bn = cb % 96;
        const int b = bn / 12, n = bn % 12;
        const float* kb = Kf32 + (long)b * 4096 * 384 + n * 32;
        const int t0 = (cb / 96) * 512;
        float clsn[32];
        #pragma unroll
        for (int d = 0; d < 32; ++d) clsn[d] = clsg[bn * 32 + d];
        #pragma unroll
        for (int i = 0; i < 2; ++i) {
            long tok = t0 + tid + i * 256;
            const float* kr = kb + tok * 384;
            double dot = 0.0, nrm = 0.0;
            #pragma unroll
            for (int d = 0; d < 32; ++d) {
                float kv = kr[d];
                dot += (double)clsn[d] * (double)kv;
                nrm += (double)kv * (double)kv;
            }
            double cv = dot / sqrt(nrm > 1e-300 ? nrm : 1e-300);
            cosv[(long)bn * 4096 + tok] = (float)cv;
        }
    }
}

// ---------------------------------------------------------------------------
// Bitonic argsort ascending via packed u64 keys: (sortable32(cos)<<32)|idx.
// ---------------------------------------------------------------------------
__global__ __launch_bounds__(1024)
void sort_kernel(const float* __restrict__ cosv, int* __restrict__ idxo)
{
    const int bn = blockIdx.x;
    __shared__ unsigned long long sk[4096];
    const int tid = threadIdx.x;
    for (int i = tid; i < 4096; i += 1024) {
        unsigned int u = __builtin_bit_cast(unsigned int, cosv[(long)bn * 4096 + i]);
        u = (u & 0x80000000u) ? ~u : (u | 0x80000000u);
        sk[i] = ((unsigned long long)u << 32) | (unsigned int)i;
    }
    __syncthreads();
    for (int size = 2; size <= 4096; size <<= 1) {
        for (int stride = size >> 1; stride >= 1; stride >>= 1) {
            #pragma unroll 2
            for (int i = tid; i < 2048; i += 1024) {
                int lo = (i << 1) - (i & (stride - 1));
                int hi = lo + stride;
                bool asc = ((lo & size) == 0);
                unsigned long long a = sk[lo], bq = sk[hi];
                if ((a > bq) == asc) { sk[lo] = bq; sk[hi] = a; }
            }
            __syncthreads();
        }
    }
    for (int i = tid; i < 4096; i += 1024)
        idxo[(long)bn * 4096 + i] = (int)(sk[i] & 0xFFFFFFFFu);
}

// ---------------------------------------------------------------------------
// MFMA clustered attention. grid (16,12,8), 256 thr = 4 waves.
// K staged as bf16(k * SCALE * log2e) -> scores in log2 domain, p = exp2(s).
// ---------------------------------------------------------------------------
__global__ __launch_bounds__(256)
void attn_kernel(const float* __restrict__ Kf32, unsigned short* __restrict__ qvB,
                 const int* __restrict__ idxbuf, const unsigned short* __restrict__ lepeT)
{
    const int cc = blockIdx.x, n = blockIdx.y, b = blockIdx.z;
    const int* ip = idxbuf + ((long)(b * 12 + n)) * 4096 + cc * 256;

    __shared__ unsigned short KsL[256][36];
    __shared__ unsigned short VsT[32][260];
    __shared__ int tokLds[256];

    const int tid = threadIdx.x;
    const int w = tid >> 6;
    const int lane = tid & 63;
    const int lo5 = lane & 31;
    const int hi = lane >> 5;
    const int hi8 = hi * 8;

    // ---- gather ----
    const int tk0 = ip[tid];
    tokLds[tid] = tk0;
    const long tb = (long)b * 4096 + tk0;
    const unsigned short* qrow = qvB + tb * 768 + n * 32;
    const float* krow = Kf32 + tb * 384 + n * 32;

    unsigned int Pq[16];
    #pragma unroll
    for (int i = 0; i < 4; ++i) {
        uint4 qu = *reinterpret_cast<const uint4*>(qrow + i * 8);
        Pq[4 * i + 0] = qu.x; Pq[4 * i + 1] = qu.y;
        Pq[4 * i + 2] = qu.z; Pq[4 * i + 3] = qu.w;
    }
    #pragma unroll
    for (int dq = 0; dq < 8; ++dq) {
        float4 kv = *reinterpret_cast<const float4*>(krow + dq * 4);
        ushort4 kp;
        kp.x = f2bf(kv.x * SCALE_L2E); kp.y = f2bf(kv.y * SCALE_L2E);
        kp.z = f2bf(kv.z * SCALE_L2E); kp.w = f2bf(kv.w * SCALE_L2E);
        *reinterpret_cast<ushort4*>(&KsL[tid][dq * 4]) = kp;
    }
    {
        union { uint4 u[4]; unsigned short s[32]; } vv;
        const unsigned short* vrow = qrow + 384;
        #pragma unroll
        for (int i = 0; i < 4; ++i) vv.u[i] = *reinterpret_cast<const uint4*>(vrow + i * 8);
        #pragma unroll
        for (int j = 0; j < 32; ++j) VsT[j][tid] = vv.s[j];
    }

    // ---- Q B-frags from own registers via permlane32_swap ----
    bf16x8 qf00, qf01, qf10, qf11;
    {
        unsigned int w0[2][4], w1[2][4];
        #pragma unroll
        for (int ks = 0; ks < 2; ++ks)
            #pragma unroll
            for (int j = 0; j < 4; ++j) {
                uint2e r = __builtin_amdgcn_permlane32_swap(Pq[ks * 8 + j], Pq[ks * 8 + 4 + j], false, false);
                w0[ks][j] = r[0];
                w1[ks][j] = r[1];
            }
        qf00 = __builtin_bit_cast(bf16x8, make_uint4(w0[0][0], w0[0][1], w0[0][2], w0[0][3]));
        qf01 = __builtin_bit_cast(bf16x8, make_uint4(w0[1][0], w0[1][1], w0[1][2], w0[1][3]));
        qf10 = __builtin_bit_cast(bf16x8, make_uint4(w1[0][0], w1[0][1], w1[0][2], w1[0][3]));
        qf11 = __builtin_bit_cast(bf16x8, make_uint4(w1[1][0], w1[1][1], w1[1][2], w1[1][3]));
    }
    __syncthreads();

    const f32x16 Z16 = {0,0,0,0,0,0,0,0,0,0,0,0,0,0,0,0};
    f32x16 o0 = Z16, o1 = Z16;
    float lsum0 = 0.f, lsum1 = 0.f;

#define LDFRAG(ARR, ROW, OFF) ({ \
    const unsigned short* _p = &ARR[ROW][OFF]; \
    union { bf16x8 v; ushort4 h[2]; } _u; \
    _u.h[0] = *reinterpret_cast<const ushort4*>(_p); \
    _u.h[1] = *reinterpret_cast<const ushort4*>(_p + 4); \
    _u.v; })

#define EXP16(S, LS) { _Pragma("unroll") for (int r = 0; r < 16; ++r) { float _e = __builtin_exp2f(S[r]); S[r] = _e; LS += _e; } }

#define MKPB(S, H) ({ \
    unsigned int _x0 = packbf(S[(H) * 8 + 0], S[(H) * 8 + 1]); \
    unsigned int _x1 = packbf(S[(H) * 8 + 2], S[(H) * 8 + 3]); \
    unsigned int _x2 = packbf(S[(H) * 8 + 4], S[(H) * 8 + 5]); \
    unsigned int _x3 = packbf(S[(H) * 8 + 6], S[(H) * 8 + 7]); \
    uint2e _r02 = __builtin_amdgcn_permlane32_swap(_x0, _x2, false, false); \
    uint2e _r13 = __builtin_amdgcn_permlane32_swap(_x1, _x3, false, false); \
    __builtin_bit_cast(bf16x8, make_uint4(_r02[0], _r13[0], _r02[1], _r13[1])); })

    for (int ch = 0; ch < 4; ++ch) {
        const int rb = ch * 64;
        f32x16 s00 = Z16, s01 = Z16, s10 = Z16, s11 = Z16;
        bf16x8 ka;
        __builtin_amdgcn_s_setprio(1);
        ka = LDFRAG(KsL, rb + lo5, hi8);
        s00 = __builtin_amdgcn_mfma_f32_32x32x16_bf16(ka, qf00, s00, 0, 0, 0);
        s01 = __builtin_amdgcn_mfma_f32_32x32x16_bf16(ka, qf10, s01, 0, 0, 0);
        ka = LDFRAG(KsL, rb + lo5, 16 + hi8);
        s00 = __builtin_amdgcn_mfma_f32_32x32x16_bf16(ka, qf01, s00, 0, 0, 0);
        s01 = __builtin_amdgcn_mfma_f32_32x32x16_bf16(ka, qf11, s01, 0, 0, 0);
        ka = LDFRAG(KsL, rb + 32 + lo5, hi8);
        s10 = __builtin_amdgcn_mfma_f32_32x32x16_bf16(ka, qf00, s10, 0, 0, 0);
        s11 = __builtin_amdgcn_mfma_f32_32x32x16_bf16(ka, qf10, s11, 0, 0, 0);
        ka = LDFRAG(KsL, rb + 32 + lo5, 16 + hi8);
        s10 = __builtin_amdgcn_mfma_f32_32x32x16_bf16(ka, qf01, s10, 0, 0, 0);
        s11 = __builtin_amdgcn_mfma_f32_32x32x16_bf16(ka, qf11, s11, 0, 0, 0);
        __builtin_amdgcn_s_setprio(0);

        EXP16(s00, lsum0); EXP16(s01, lsum1);
        EXP16(s10, lsum0); EXP16(s11, lsum1);

        bf16x8 va, pb0, pb1;
        __builtin_amdgcn_s_setprio(1);
        va = LDFRAG(VsT, lo5, rb + 0 + hi8);
        pb0 = MKPB(s00, 0); pb1 = MKPB(s01, 0);
        o0 = __builtin_amdgcn_mfma_f32_32x32x16_bf16(va, pb0, o0, 0, 0, 0);
        o1 = __builtin_amdgcn_mfma_f32_32x32x16_bf16(va, pb1, o1, 0, 0, 0);
        va = LDFRAG(VsT, lo5, rb + 16 + hi8);
        pb0 = MKPB(s00, 1); pb1 = MKPB(s01, 1);
        o0 = __builtin_amdgcn_mfma_f32_32x32x16_bf16(va, pb0, o0, 0, 0, 0);
        o1 = __builtin_amdgcn_mfma_f32_32x32x16_bf16(va, pb1, o1, 0, 0, 0);
        va = LDFRAG(VsT, lo5, rb + 32 + hi8);
        pb0 = MKPB(s10, 0); pb1 = MKPB(s11, 0);
        o0 = __builtin_amdgcn_mfma_f32_32x32x16_bf16(va, pb0, o0, 0, 0, 0);
        o1 = __builtin_amdgcn_mfma_f32_32x32x16_bf16(va, pb1, o1, 0, 0, 0);
        va = LDFRAG(VsT, lo5, rb + 48 + hi8);
        pb0 = MKPB(s10, 1); pb1 = MKPB(s11, 1);
        o0 = __builtin_amdgcn_mfma_f32_32x32x16_bf16(va, pb0, o0, 0, 0, 0);
        o1 = __builtin_amdgcn_mfma_f32_32x32x16_bf16(va, pb1, o1, 0, 0, 0);
        __builtin_amdgcn_s_setprio(0);
    }

    // ---- epilogue: res = o/l + lepe -> bf16 hi/lo into qvB ----
    const float lf0 = lsum0 + __shfl_xor(lsum0, 32);
    const float lf1 = lsum1 + __shfl_xor(lsum1, 32);
    const float li0 = 1.f / lf0, li1 = 1.f / lf1;

    #pragma unroll
    for (int qt = 0; qt < 2; ++qt) {
        const int qrix = w * 64 + qt * 32 + lo5;
        const int tk = tokLds[qrix];
        const long tb2 = (long)b * 4096 + tk;
        unsigned short* resrow = qvB + tb2 * 768;
        const unsigned short* lp = lepeT + tb2 * 384 + n * 32;
        const float li = qt ? li1 : li0;
        const f32x16& oo = qt ? o1 : o0;
        #pragma unroll
        for (int qd = 0; qd < 4; ++qd) {
            const int d0 = qd * 8 + hi * 4;
            ushort4 lv = *reinterpret_cast<const ushort4*>(lp + d0);
            float r0 = oo[qd * 4 + 0] * li + bf2f(lv.x);
            float r1 = oo[qd * 4 + 1] * li + bf2f(lv.y);
            float r2 = oo[qd * 4 + 2] * li + bf2f(lv.z);
            float r3 = oo[qd * 4 + 3] * li + bf2f(lv.w);
            unsigned short h0 = f2bf(r0), h1 = f2bf(r1), h2 = f2bf(r2), h3 = f2bf(r3);
            ushort4 hh = {h0, h1, h2, h3};
            ushort4 ll = {f2bf(r0 - bf2f(h0)), f2bf(r1 - bf2f(h1)),
                          f2bf(r2 - bf2f(h2)), f2bf(r3 - bf2f(h3))};
            *reinterpret_cast<ushort4*>(resrow + n * 32 + d0) = hh;
            *reinterpret_cast<ushort4*>(resrow + 384 + n * 32 + d0) = ll;
        }
    }
#undef LDFRAG
#undef EXP16
#undef MKPB
}

// ---------------------------------------------------------------------------
extern "C" void kernel_launch(void* const* d_in, const int* in_sizes, int n_in,
                              void* d_out, int out_size, void* d_ws, size_t ws_size,
                              hipStream_t stream)
{
    const float* x      = (const float*)d_in[0];
    const float* qkv_w  = (const float*)d_in[1];
    const float* qkv_b  = (const float*)d_in[2];
    const float* lepe_w = (const float*)d_in[3];
    const float* lepe_b = (const float*)d_in[4];
    const float* out_w  = (const float*)d_in[5];
    const float* out_b  = (const float*)d_in[6];
    float* out = (float*)d_out;

    char* ws = (char*)d_ws;
    float*          Kf32 = (float*)ws;                                  // 50331648 B
    unsigned short* qvB  = (unsigned short*)(ws + 50331648);            // 50331648 B
    float*          cosv = (float*)(ws + 100663296);                    // 1572864 B
    int*            idx  = (int*)(ws + 102236160);                      // 1572864 B
    unsigned short* Wqv  = (unsigned short*)(ws + 103809024);           // 589824 B
    unsigned short* owh  = (unsigned short*)(ws + 104398848);           // 294912 B
    unsigned short* owl  = (unsigned short*)(ws + 104693760);           // 294912 B
    float*          qvb  = (float*)(ws + 104988672);                    // 3072 B
    float*          clsg = (float*)(ws + 104991744);                    // 12288 B

    unsigned short* xbT   = (unsigned short*)d_out;                     // dead before out-proj
    unsigned short* lepeT = (unsigned short*)d_out + 12582912;          // dead before out-proj

    // 1) weight conversions
    convert_w_kernel<<<1731, 256, 0, stream>>>(qkv_w, qkv_b, out_w, Wqv, qvb, owh, owl);
    // 2) x -> token-major bf16
    transpose_x_kernel<<<dim3(64, 6, 8), 256, 0, stream>>>(x, xbT);
    // 3) k projection, exact fp32 (per-output accumulation bit-identical)
    gemm_k_kernel<<<dim3(3, 32, 8), 512, 0, stream>>>(qkv_w, x, qkv_b, Kf32);
    // 4) q,v projection, bf16 MFMA -> qvB [b][t][768] bf16
    mfma_nt_kernel<false, 0><<<dim3(6, 32, 8), 256, 20480, stream>>>(
        Wqv, nullptr, xbT, nullptr, qvb, qvB,
        384, 384, 384, 0L, (long)4096 * 384, (long)4096 * 768);
    // 5) class-mean (bit-identical)
    cls_kernel<<<96, 256, 0, stream>>>(Kf32, clsg);
    // 6) merged lepe + per-token cosine (independent; one dispatch)
    cos_lepe_kernel<<<2304, 256, 0, stream>>>(Kf32, clsg, cosv, qvB, lepe_w, lepe_b, lepeT);
    // 7) stable ascending argsort (u64-packed bitonic, identical permutation)
    sort_kernel<<<96, 1024, 0, stream>>>(cosv, idx);
    // 8) clustered attention + lepe residual; res -> bf16 hi/lo over qvB
    attn_kernel<<<dim3(16, 12, 8), 256, 0, stream>>>(Kf32, qvB, idx, lepeT);
    // 9) output projection, split-bf16 (3-term) MFMA -> out
    mfma_nt_kernel<true, 1><<<dim3(32, 3, 8), 256, 40960, stream>>>(
        qvB, qvB + 384, owh, owl, out_b, out,
        384, 768, 384, (long)4096 * 768, 0L, (long)384 * 4096);
}

// Round 13
// 394.335 us; speedup vs baseline: 1.1377x; 1.0033x over previous
//
#include <hip/hip_runtime.h>
#include <math.h>

#define SCALE_F   0.17677669529663687f   // 32^-0.5
#define SCALE_L2E 0.25505837072959003f   // 32^-0.5 * log2(e)

using bf16x8 = __attribute__((ext_vector_type(8))) __bf16;
using f32x2  = __attribute__((ext_vector_type(2))) float;
using f32x4  = __attribute__((ext_vector_type(4))) float;
using f32x16 = __attribute__((ext_vector_type(16))) float;
using uint2e = __attribute__((ext_vector_type(2))) unsigned int;

__device__ inline unsigned short f2bf(float x) {
    __bf16 h = (__bf16)x;                       // HW v_cvt (RNE)
    return __builtin_bit_cast(unsigned short, h);
}
__device__ inline float bf2f(unsigned short u) {
    unsigned int x = ((unsigned int)u) << 16;
    return __builtin_bit_cast(float, x);
}
__device__ inline unsigned int packbf(float a, float b) {
    return (unsigned int)f2bf(a) | ((unsigned int)f2bf(b) << 16);
}
__device__ inline bf16x8 ldfrag(const unsigned short* p) {
    return __builtin_bit_cast(bf16x8, *reinterpret_cast<const uint4*>(p));
}

// ---------------------------------------------------------------------------
// fp32 k-projection GEMM. BM=128, BN=128, BK=32, 256 thr, 8x8 micro-tile:
// 4 ds_read_b128 per 128 FMA-cycles (73% FMA issue ceiling vs 64% at 4x8).
// A-frag reads are wave-broadcast on disjoint bank groups; B interleaved
// (2-way max). Each output = ONE fma chain over k ascending -> k values
// bit-identical to all previous passing rounds (argsort-safe).
// ---------------------------------------------------------------------------
__global__ __launch_bounds__(256)
void gemm_k_kernel(const float* __restrict__ A, const float* __restrict__ Bmat,
                   const float* __restrict__ bias, float* __restrict__ CT)
{
    const int bm = blockIdx.x, bn = blockIdx.y, bz = blockIdx.z;
    const float* Bp = Bmat + (long)bz * 384 * 4096;
    float* Cp = CT + (long)bz * 4096 * 384;
    __shared__ float As[32][132];
    __shared__ float BsF[32 * 136];
    const int tid = threadIdx.x;
    const int tx = tid & 15, ty = tid >> 4;    // tx 0..15 (col blk), ty 0..15 (row blk)
    const int m0 = bm * 128, n0 = bn * 128;

    float acc[8][8];
    #pragma unroll
    for (int i = 0; i < 8; ++i)
        #pragma unroll
        for (int j = 0; j < 8; ++j) acc[i][j] = 0.f;

    for (int k0 = 0; k0 < 384; k0 += 32) {
        if (k0) __syncthreads();
        #pragma unroll
        for (int it = 0; it < 4; ++it) {
            int slot = tid + it * 256;                  // 0..1023
            int rA = slot >> 3, cA = slot & 7;          // A: 128 rows x 8 quads
            float4 av = *reinterpret_cast<const float4*>(&A[(long)(384 + m0 + rA) * 384 + k0 + cA * 4]);
            As[cA * 4 + 0][rA] = av.x; As[cA * 4 + 1][rA] = av.y;
            As[cA * 4 + 2][rA] = av.z; As[cA * 4 + 3][rA] = av.w;
            int sr = slot >> 5, sq = slot & 31;         // B: 32 rows x 32 quads
            int wB = sr * 136 + ((sq & 1) << 6) + ((sq >> 1) << 2);
            *reinterpret_cast<float4*>(&BsF[wB]) =
                *reinterpret_cast<const float4*>(&Bp[(long)(k0 + sr) * 4096 + n0 + sq * 4]);
        }
        __syncthreads();
        #pragma unroll
        for (int kk = 0; kk < 32; ++kk) {
            float a[8], b[8];
            *reinterpret_cast<float4*>(&a[0]) = *reinterpret_cast<const float4*>(&As[kk][ty * 8]);
            *reinterpret_cast<float4*>(&a[4]) = *reinterpret_cast<const float4*>(&As[kk][ty * 8 + 4]);
            *reinterpret_cast<float4*>(&b[0]) = *reinterpret_cast<const float4*>(&BsF[kk * 136 + tx * 4]);
            *reinterpret_cast<float4*>(&b[4]) = *reinterpret_cast<const float4*>(&BsF[kk * 136 + 64 + tx * 4]);
            #pragma unroll
            for (int i = 0; i < 8; ++i)
                #pragma unroll
                for (int j = 0; j < 8; ++j)
                    acc[i][j] += a[i] * b[j];
        }
    }

    float bv[8];
    #pragma unroll
    for (int i = 0; i < 8; ++i) bv[i] = bias[384 + m0 + ty * 8 + i];
    #pragma unroll
    for (int j = 0; j < 8; ++j) {
        long tok = n0 + tx * 8 + j;
        float* ptr = Cp + tok * 384 + m0 + ty * 8;
        float4 lo = make_float4(acc[0][j] + bv[0], acc[1][j] + bv[1], acc[2][j] + bv[2], acc[3][j] + bv[3]);
        float4 hi = make_float4(acc[4][j] + bv[4], acc[5][j] + bv[5], acc[6][j] + bv[6], acc[7][j] + bv[7]);
        *reinterpret_cast<float4*>(ptr) = lo;
        *reinterpret_cast<float4*>(ptr + 4) = hi;
    }
}

// ---------------------------------------------------------------------------
// bf16 MFMA NT-GEMM: D[rowA][rowB] = sum_k A[rowA][k]*B[rowB][k], both k-contig.
// SM=0: store bf16 at C[t=colB][m=rowA] (ldc 768), bias by rowA  (QV proj)
// SM=1: store f32  at C[m=colB][t=rowA] (ldc 4096), bias by colB (out proj)
// SPLIT: A,B given as hi/lo bf16 pairs; 3-term product.
// ---------------------------------------------------------------------------
template<bool SPLIT, int SM>
__global__ __launch_bounds__(256)
void mfma_nt_kernel(const unsigned short* __restrict__ Ah, const unsigned short* __restrict__ Al,
                    const unsigned short* __restrict__ Bh, const unsigned short* __restrict__ Bl,
                    const float* __restrict__ bias, void* __restrict__ Cout,
                    int K, int lda, int ldb,
                    long strideAb, long strideBb, long strideCb)
{
    extern __shared__ unsigned short smem[];
    unsigned short* As  = smem;            // [128][40]
    unsigned short* Bs  = smem + 5120;
    unsigned short* Asl = smem + 10240;
    unsigned short* Bsl = smem + 15360;
    const int bm = blockIdx.x, bn = blockIdx.y, bz = blockIdx.z;
    const unsigned short* Ap = Ah + (long)bz * strideAb;
    const unsigned short* Bp = Bh + (long)bz * strideBb;
    const unsigned short* Alp = nullptr;
    const unsigned short* Blp = nullptr;
    if constexpr (SPLIT) {
        Alp = Al + (long)bz * strideAb;
        Blp = Bl + (long)bz * strideBb;
    }
    const int tid = threadIdx.x;
    const int lane = tid & 63, wid = tid >> 6;
    const int wr = wid >> 1, wc = wid & 1;
    const int l15 = lane & 15, l4 = lane >> 4;
    const int m0 = bm * 128, n0 = bn * 128;

    const f32x4 Z4 = {0.f, 0.f, 0.f, 0.f};
    f32x4 acc[4][4];
    #pragma unroll
    for (int i = 0; i < 4; ++i)
        #pragma unroll
        for (int j = 0; j < 4; ++j) acc[i][j] = Z4;

    for (int k0 = 0; k0 < K; k0 += 32) {
        if (k0) __syncthreads();
        #pragma unroll
        for (int it = 0; it < 2; ++it) {
            int slot = tid + it * 256;
            int r = slot >> 2, cq = slot & 3;
            *reinterpret_cast<uint4*>(&As[r * 40 + cq * 8]) =
                *reinterpret_cast<const uint4*>(&Ap[(long)(m0 + r) * lda + k0 + cq * 8]);
            *reinterpret_cast<uint4*>(&Bs[r * 40 + cq * 8]) =
                *reinterpret_cast<const uint4*>(&Bp[(long)(n0 + r) * ldb + k0 + cq * 8]);
            if constexpr (SPLIT) {
                *reinterpret_cast<uint4*>(&Asl[r * 40 + cq * 8]) =
                    *reinterpret_cast<const uint4*>(&Alp[(long)(m0 + r) * lda + k0 + cq * 8]);
                *reinterpret_cast<uint4*>(&Bsl[r * 40 + cq * 8]) =
                    *reinterpret_cast<const uint4*>(&Blp[(long)(n0 + r) * ldb + k0 + cq * 8]);
            }
        }
        __syncthreads();

        bf16x8 af[4], bg[4], afl[4], bgl[4];
        #pragma unroll
        for (int f = 0; f < 4; ++f) {
            af[f] = ldfrag(&As[(wr * 64 + f * 16 + l15) * 40 + l4 * 8]);
            bg[f] = ldfrag(&Bs[(wc * 64 + f * 16 + l15) * 40 + l4 * 8]);
        }
        if constexpr (SPLIT) {
            #pragma unroll
            for (int f = 0; f < 4; ++f) {
                afl[f] = ldfrag(&Asl[(wr * 64 + f * 16 + l15) * 40 + l4 * 8]);
                bgl[f] = ldfrag(&Bsl[(wc * 64 + f * 16 + l15) * 40 + l4 * 8]);
            }
        }
        #pragma unroll
        for (int fi = 0; fi < 4; ++fi)
            #pragma unroll
            for (int fj = 0; fj < 4; ++fj) {
                acc[fi][fj] = __builtin_amdgcn_mfma_f32_16x16x32_bf16(af[fi], bg[fj], acc[fi][fj], 0, 0, 0);
                if constexpr (SPLIT) {
                    acc[fi][fj] = __builtin_amdgcn_mfma_f32_16x16x32_bf16(af[fi], bgl[fj], acc[fi][fj], 0, 0, 0);
                    acc[fi][fj] = __builtin_amdgcn_mfma_f32_16x16x32_bf16(afl[fi], bg[fj], acc[fi][fj], 0, 0, 0);
                }
            }
    }

    if constexpr (SM == 0) {
        unsigned short* Cq = (unsigned short*)Cout + (long)bz * strideCb;
        #pragma unroll
        for (int fi = 0; fi < 4; ++fi)
            #pragma unroll
            for (int fj = 0; fj < 4; ++fj) {
                const int m = m0 + wr * 64 + fi * 16 + l4 * 4;
                const int t = n0 + wc * 64 + fj * 16 + l15;
                ushort4 h;
                h.x = f2bf(acc[fi][fj][0] + bias[m + 0]);
                h.y = f2bf(acc[fi][fj][1] + bias[m + 1]);
                h.z = f2bf(acc[fi][fj][2] + bias[m + 2]);
                h.w = f2bf(acc[fi][fj][3] + bias[m + 3]);
                *reinterpret_cast<ushort4*>(&Cq[(long)t * 768 + m]) = h;
            }
    } else {
        float* Cf = (float*)Cout + (long)bz * strideCb;
        #pragma unroll
        for (int fi = 0; fi < 4; ++fi)
            #pragma unroll
            for (int fj = 0; fj < 4; ++fj) {
                const int t = m0 + wr * 64 + fi * 16 + l4 * 4;
                const int m = n0 + wc * 64 + fj * 16 + l15;
                const float bv = bias[m];
                float4 v = make_float4(acc[fi][fj][0] + bv, acc[fi][fj][1] + bv,
                                       acc[fi][fj][2] + bv, acc[fi][fj][3] + bv);
                *reinterpret_cast<float4*>(&Cf[(long)m * 4096 + t]) = v;
            }
    }
}

// ---------------------------------------------------------------------------
// Merged prep kernel: blocks 0..3071 transpose x -> xbT bf16;
// blocks 3072..4802 weight conversion. Both only read inputs (independent).
// ---------------------------------------------------------------------------
__global__ __launch_bounds__(256)
void prep_kernel(const float* __restrict__ x, unsigned short* __restrict__ xbT,
                 const float* __restrict__ qkv_w, const float* __restrict__ qkv_b,
                 const float* __restrict__ out_w,
                 unsigned short* __restrict__ Wqv, float* __restrict__ qvb,
                 unsigned short* __restrict__ owh, unsigned short* __restrict__ owl)
{
    __shared__ float tl[64][65];
    const int bid = blockIdx.x;
    const int tid = threadIdx.x;
    if (bid < 3072) {
        const int t0 = (bid % 64) * 64, c0 = ((bid / 64) % 6) * 64, b = bid / 384;
        #pragma unroll
        for (int i = 0; i < 16; ++i) {
            int cr = (tid >> 6) + i * 4, tc = tid & 63;
            tl[cr][tc] = x[((long)b * 384 + c0 + cr) * 4096 + t0 + tc];
        }
        __syncthreads();
        #pragma unroll
        for (int i = 0; i < 8; ++i) {
            int tr = (tid >> 5) + i * 8, c2 = (tid & 31) * 2;
            unsigned int u = packbf(tl[c2][tr], tl[c2 + 1][tr]);
            *reinterpret_cast<unsigned int*>(&xbT[((long)b * 4096 + t0 + tr) * 384 + c0 + c2]) = u;
        }
    } else {
        const int total = 294912 + 147456 + 768;
        for (int i = (bid - 3072) * 256 + tid; i < total; i += 1731 * 256) {
            if (i < 294912) {
                int m = i / 384, k = i - m * 384;
                int src = (m < 384) ? m : m + 384;
                Wqv[i] = f2bf(qkv_w[(long)src * 384 + k]);
            } else if (i < 294912 + 147456) {
                int o = i - 294912;
                float w = out_w[o];
                unsigned short h = f2bf(w);
                owh[o] = h;
                owl[o] = f2bf(w - bf2f(h));
            } else {
                int m = i - 294912 - 147456;
                qvb[m] = qkv_b[(m < 384) ? m : m + 384];
            }
        }
    }
}

// ---------------------------------------------------------------------------
// cls kernel: per (b,n) normalized mean of k (bit-identical math).
// ---------------------------------------------------------------------------
__global__ __launch_bounds__(256)
void cls_kernel(const float* __restrict__ Kf32, float* __restrict__ clsg)
{
    const int bn = blockIdx.x;
    const int b = bn / 12, n = bn % 12;
    const float* kb = Kf32 + (long)b * 4096 * 384 + n * 32;
    __shared__ float part[256][33];
    const int tid = threadIdx.x;
    float acc[32];
    #pragma unroll
    for (int d = 0; d < 32; ++d) acc[d] = 0.f;
    for (int i = 0; i < 16; ++i) {
        long tok = tid + i * 256;
        const float* kr = kb + tok * 384;
        #pragma unroll
        for (int d = 0; d < 32; ++d) acc[d] += kr[d];
    }
    #pragma unroll
    for (int d = 0; d < 32; ++d) part[tid][d] = acc[d];
    __syncthreads();
    if (tid < 32) {
        double s = 0.0;
        for (int t = 0; t < 256; ++t) s += (double)part[t][tid];
        part[0][tid] = (float)s;
    }
    __syncthreads();
    if (tid == 0) {
        double nn = 0.0;
        for (int d = 0; d < 32; ++d) { double v = (double)part[0][d]; nn += v * v; }
        double inv = 1.0 / sqrt(nn > 1e-300 ? nn : 1e-300);
        for (int d = 0; d < 32; ++d) clsg[bn * 32 + d] = (float)((double)part[0][d] * inv);
    }
}

// ---------------------------------------------------------------------------
// Merged lepe + cos2 kernel (independent ops, one dispatch -> co-scheduled).
// ---------------------------------------------------------------------------
__global__ __launch_bounds__(256)
void cos_lepe_kernel(const float* __restrict__ Kf32, const float* __restrict__ clsg,
                     float* __restrict__ cosv,
                     const unsigned short* __restrict__ qvB, const float* __restrict__ w5,
                     const float* __restrict__ wb, unsigned short* __restrict__ lepeT)
{
    __shared__ float tile[12 * 68 * 16];
    const int bid = blockIdx.x;
    const int tid = threadIdx.x;

    if (bid < 1536) {
        const int ch0 = (bid % 24) * 16;
        const int y0 = ((bid / 24) % 8) * 8;
        const int b = bid / 192;
        const unsigned short* vb = qvB + (long)b * 4096 * 768 + 384 + ch0;
        unsigned short* dst = lepeT + (long)b * 4096 * 384 + ch0;

        for (int s = tid; s < 12 * 68 * 2; s += 256) {
            int pix = s >> 1, half = s & 1;
            int yy = pix / 68, xx = pix % 68;
            int gy = y0 + yy - 2, gx = xx - 2;
            float* tp = &tile[pix * 16 + half * 8];
            if (gy >= 0 && gy < 64 && gx >= 0 && gx < 64) {
                uint4 u = *reinterpret_cast<const uint4*>(vb + (long)(gy * 64 + gx) * 768 + half * 8);
                tp[0] = bf2f((unsigned short)(u.x & 0xFFFFu)); tp[1] = bf2f((unsigned short)(u.x >> 16));
                tp[2] = bf2f((unsigned short)(u.y & 0xFFFFu)); tp[3] = bf2f((unsigned short)(u.y >> 16));
                tp[4] = bf2f((unsigned short)(u.z & 0xFFFFu)); tp[5] = bf2f((unsigned short)(u.z >> 16));
                tp[6] = bf2f((unsigned short)(u.w & 0xFFFFu)); tp[7] = bf2f((unsigned short)(u.w >> 16));
            } else {
                #pragma unroll
                for (int j = 0; j < 8; ++j) tp[j] = 0.f;
            }
        }
        const int c = tid & 15, xo = tid >> 4;
        float f[25];
        #pragma unroll
        for (int j = 0; j < 25; ++j) f[j] = w5[(ch0 + c) * 25 + j];
        const float bv = wb[ch0 + c];
        __syncthreads();

        #pragma unroll
        for (int yy = 0; yy < 8; ++yy) {
            #pragma unroll
            for (int xq = 0; xq < 4; ++xq) {
                int x = xq * 16 + xo;
                float acc = bv;
                #pragma unroll
                for (int dy = 0; dy < 5; ++dy)
                    #pragma unroll
                    for (int dx = 0; dx < 5; ++dx)
                        acc += tile[((yy + dy) * 68 + (x + dx)) * 16 + c] * f[dy * 5 + dx];
                dst[(long)((y0 + yy) * 64 + x) * 384 + c] = f2bf(acc);
            }
        }
    } else {
        const int cb = bid - 1536;
        const int bn = cb % 96;
        const int b = bn / 12, n = bn % 12;
        const float* kb = Kf32 + (long)b * 4096 * 384 + n * 32;
        const int t0 = (cb / 96) * 512;
        float clsn[32];
        #pragma unroll
        for (int d = 0; d < 32; ++d) clsn[d] = clsg[bn * 32 + d];
        #pragma unroll
        for (int i = 0; i < 2; ++i) {
            long tok = t0 + tid + i * 256;
            const float* kr = kb + tok * 384;
            double dot = 0.0, nrm = 0.0;
            #pragma unroll
            for (int d = 0; d < 32; ++d) {
                float kv = kr[d];
                dot += (double)clsn[d] * (double)kv;
                nrm += (double)kv * (double)kv;
            }
            double cv = dot / sqrt(nrm > 1e-300 ? nrm : 1e-300);
            cosv[(long)bn * 4096 + tok] = (float)cv;
        }
    }
}

// ---------------------------------------------------------------------------
// Bitonic argsort ascending via packed u64 keys: (sortable32(cos)<<32)|idx.
// ---------------------------------------------------------------------------
__global__ __launch_bounds__(1024)
void sort_kernel(const float* __restrict__ cosv, int* __restrict__ idxo)
{
    const int bn = blockIdx.x;
    __shared__ unsigned long long sk[4096];
    const int tid = threadIdx.x;
    for (int i = tid; i < 4096; i += 1024) {
        unsigned int u = __builtin_bit_cast(unsigned int, cosv[(long)bn * 4096 + i]);
        u = (u & 0x80000000u) ? ~u : (u | 0x80000000u);
        sk[i] = ((unsigned long long)u << 32) | (unsigned int)i;
    }
    __syncthreads();
    for (int size = 2; size <= 4096; size <<= 1) {
        for (int stride = size >> 1; stride >= 1; stride >>= 1) {
            #pragma unroll 2
            for (int i = tid; i < 2048; i += 1024) {
                int lo = (i << 1) - (i & (stride - 1));
                int hi = lo + stride;
                bool asc = ((lo & size) == 0);
                unsigned long long a = sk[lo], bq = sk[hi];
                if ((a > bq) == asc) { sk[lo] = bq; sk[hi] = a; }
            }
            __syncthreads();
        }
    }
    for (int i = tid; i < 4096; i += 1024)
        idxo[(long)bn * 4096 + i] = (int)(sk[i] & 0xFFFFFFFFu);
}

// ---------------------------------------------------------------------------
// MFMA clustered attention. grid (16,12,8), 256 thr = 4 waves.
// ---------------------------------------------------------------------------
__global__ __launch_bounds__(256)
void attn_kernel(const float* __restrict__ Kf32, unsigned short* __restrict__ qvB,
                 const int* __restrict__ idxbuf, const unsigned short* __restrict__ lepeT)
{
    const int cc = blockIdx.x, n = blockIdx.y, b = blockIdx.z;
    const int* ip = idxbuf + ((long)(b * 12 + n)) * 4096 + cc * 256;

    __shared__ unsigned short KsL[256][36];
    __shared__ unsigned short VsT[32][260];
    __shared__ int tokLds[256];

    const int tid = threadIdx.x;
    const int w = tid >> 6;
    const int lane = tid & 63;
    const int lo5 = lane & 31;
    const int hi = lane >> 5;
    const int hi8 = hi * 8;

    // ---- gather ----
    const int tk0 = ip[tid];
    tokLds[tid] = tk0;
    const long tb = (long)b * 4096 + tk0;
    const unsigned short* qrow = qvB + tb * 768 + n * 32;
    const float* krow = Kf32 + tb * 384 + n * 32;

    unsigned int Pq[16];
    #pragma unroll
    for (int i = 0; i < 4; ++i) {
        uint4 qu = *reinterpret_cast<const uint4*>(qrow + i * 8);
        Pq[4 * i + 0] = qu.x; Pq[4 * i + 1] = qu.y;
        Pq[4 * i + 2] = qu.z; Pq[4 * i + 3] = qu.w;
    }
    #pragma unroll
    for (int dq = 0; dq < 8; ++dq) {
        float4 kv = *reinterpret_cast<const float4*>(krow + dq * 4);
        ushort4 kp;
        kp.x = f2bf(kv.x * SCALE_L2E); kp.y = f2bf(kv.y * SCALE_L2E);
        kp.z = f2bf(kv.z * SCALE_L2E); kp.w = f2bf(kv.w * SCALE_L2E);
        *reinterpret_cast<ushort4*>(&KsL[tid][dq * 4]) = kp;
    }
    {
        union { uint4 u[4]; unsigned short s[32]; } vv;
        const unsigned short* vrow = qrow + 384;
        #pragma unroll
        for (int i = 0; i < 4; ++i) vv.u[i] = *reinterpret_cast<const uint4*>(vrow + i * 8);
        #pragma unroll
        for (int j = 0; j < 32; ++j) VsT[j][tid] = vv.s[j];
    }

    // ---- Q B-frags from own registers via permlane32_swap ----
    bf16x8 qf00, qf01, qf10, qf11;
    {
        unsigned int w0[2][4], w1[2][4];
        #pragma unroll
        for (int ks = 0; ks < 2; ++ks)
            #pragma unroll
            for (int j = 0; j < 4; ++j) {
                uint2e r = __builtin_amdgcn_permlane32_swap(Pq[ks * 8 + j], Pq[ks * 8 + 4 + j], false, false);
                w0[ks][j] = r[0];
                w1[ks][j] = r[1];
            }
        qf00 = __builtin_bit_cast(bf16x8, make_uint4(w0[0][0], w0[0][1], w0[0][2], w0[0][3]));
        qf01 = __builtin_bit_cast(bf16x8, make_uint4(w0[1][0], w0[1][1], w0[1][2], w0[1][3]));
        qf10 = __builtin_bit_cast(bf16x8, make_uint4(w1[0][0], w1[0][1], w1[0][2], w1[0][3]));
        qf11 = __builtin_bit_cast(bf16x8, make_uint4(w1[1][0], w1[1][1], w1[1][2], w1[1][3]));
    }
    __syncthreads();

    const f32x16 Z16 = {0,0,0,0,0,0,0,0,0,0,0,0,0,0,0,0};
    f32x16 o0 = Z16, o1 = Z16;
    float lsum0 = 0.f, lsum1 = 0.f;

#define LDFRAG(ARR, ROW, OFF) ({ \
    const unsigned short* _p = &ARR[ROW][OFF]; \
    union { bf16x8 v; ushort4 h[2]; } _u; \
    _u.h[0] = *reinterpret_cast<const ushort4*>(_p); \
    _u.h[1] = *reinterpret_cast<const ushort4*>(_p + 4); \
    _u.v; })

#define EXP16(S, LS) { _Pragma("unroll") for (int r = 0; r < 16; ++r) { float _e = __builtin_exp2f(S[r]); S[r] = _e; LS += _e; } }

#define MKPB(S, H) ({ \
    unsigned int _x0 = packbf(S[(H) * 8 + 0], S[(H) * 8 + 1]); \
    unsigned int _x1 = packbf(S[(H) * 8 + 2], S[(H) * 8 + 3]); \
    unsigned int _x2 = packbf(S[(H) * 8 + 4], S[(H) * 8 + 5]); \
    unsigned int _x3 = packbf(S[(H) * 8 + 6], S[(H) * 8 + 7]); \
    uint2e _r02 = __builtin_amdgcn_permlane32_swap(_x0, _x2, false, false); \
    uint2e _r13 = __builtin_amdgcn_permlane32_swap(_x1, _x3, false, false); \
    __builtin_bit_cast(bf16x8, make_uint4(_r02[0], _r13[0], _r02[1], _r13[1])); })

    for (int ch = 0; ch < 4; ++ch) {
        const int rb = ch * 64;
        f32x16 s00 = Z16, s01 = Z16, s10 = Z16, s11 = Z16;
        bf16x8 ka;
        __builtin_amdgcn_s_setprio(1);
        ka = LDFRAG(KsL, rb + lo5, hi8);
        s00 = __builtin_amdgcn_mfma_f32_32x32x16_bf16(ka, qf00, s00, 0, 0, 0);
        s01 = __builtin_amdgcn_mfma_f32_32x32x16_bf16(ka, qf10, s01, 0, 0, 0);
        ka = LDFRAG(KsL, rb + lo5, 16 + hi8);
        s00 = __builtin_amdgcn_mfma_f32_32x32x16_bf16(ka, qf01, s00, 0, 0, 0);
        s01 = __builtin_amdgcn_mfma_f32_32x32x16_bf16(ka, qf11, s01, 0, 0, 0);
        ka = LDFRAG(KsL, rb + 32 + lo5, hi8);
        s10 = __builtin_amdgcn_mfma_f32_32x32x16_bf16(ka, qf00, s10, 0, 0, 0);
        s11 = __builtin_amdgcn_mfma_f32_32x32x16_bf16(ka, qf10, s11, 0, 0, 0);
        ka = LDFRAG(KsL, rb + 32 + lo5, 16 + hi8);
        s10 = __builtin_amdgcn_mfma_f32_32x32x16_bf16(ka, qf01, s10, 0, 0, 0);
        s11 = __builtin_amdgcn_mfma_f32_32x32x16_bf16(ka, qf11, s11, 0, 0, 0);
        __builtin_amdgcn_s_setprio(0);

        EXP16(s00, lsum0); EXP16(s01, lsum1);
        EXP16(s10, lsum0); EXP16(s11, lsum1);

        bf16x8 va, pb0, pb1;
        __builtin_amdgcn_s_setprio(1);
        va = LDFRAG(VsT, lo5, rb + 0 + hi8);
        pb0 = MKPB(s00, 0); pb1 = MKPB(s01, 0);
        o0 = __builtin_amdgcn_mfma_f32_32x32x16_bf16(va, pb0, o0, 0, 0, 0);
        o1 = __builtin_amdgcn_mfma_f32_32x32x16_bf16(va, pb1, o1, 0, 0, 0);
        va = LDFRAG(VsT, lo5, rb + 16 + hi8);
        pb0 = MKPB(s00, 1); pb1 = MKPB(s01, 1);
        o0 = __builtin_amdgcn_mfma_f32_32x32x16_bf16(va, pb0, o0, 0, 0, 0);
        o1 = __builtin_amdgcn_mfma_f32_32x32x16_bf16(va, pb1, o1, 0, 0, 0);
        va = LDFRAG(VsT, lo5, rb + 32 + hi8);
        pb0 = MKPB(s10, 0); pb1 = MKPB(s11, 0);
        o0 = __builtin_amdgcn_mfma_f32_32x32x16_bf16(va, pb0, o0, 0, 0, 0);
        o1 = __builtin_amdgcn_mfma_f32_32x32x16_bf16(va, pb1, o1, 0, 0, 0);
        va = LDFRAG(VsT, lo5, rb + 48 + hi8);
        pb0 = MKPB(s10, 1); pb1 = MKPB(s11, 1);
        o0 = __builtin_amdgcn_mfma_f32_32x32x16_bf16(va, pb0, o0, 0, 0, 0);
        o1 = __builtin_amdgcn_mfma_f32_32x32x16_bf16(va, pb1, o1, 0, 0, 0);
        __builtin_amdgcn_s_setprio(0);
    }

    // ---- epilogue: res = o/l + lepe -> bf16 hi/lo into qvB ----
    const float lf0 = lsum0 + __shfl_xor(lsum0, 32);
    const float lf1 = lsum1 + __shfl_xor(lsum1, 32);
    const float li0 = 1.f / lf0, li1 = 1.f / lf1;

    #pragma unroll
    for (int qt = 0; qt < 2; ++qt) {
        const int qrix = w * 64 + qt * 32 + lo5;
        const int tk = tokLds[qrix];
        const long tb2 = (long)b * 4096 + tk;
        unsigned short* resrow = qvB + tb2 * 768;
        const unsigned short* lp = lepeT + tb2 * 384 + n * 32;
        const float li = qt ? li1 : li0;
        const f32x16& oo = qt ? o1 : o0;
        #pragma unroll
        for (int qd = 0; qd < 4; ++qd) {
            const int d0 = qd * 8 + hi * 4;
            ushort4 lv = *reinterpret_cast<const ushort4*>(lp + d0);
            float r0 = oo[qd * 4 + 0] * li + bf2f(lv.x);
            float r1 = oo[qd * 4 + 1] * li + bf2f(lv.y);
            float r2 = oo[qd * 4 + 2] * li + bf2f(lv.z);
            float r3 = oo[qd * 4 + 3] * li + bf2f(lv.w);
            unsigned short h0 = f2bf(r0), h1 = f2bf(r1), h2 = f2bf(r2), h3 = f2bf(r3);
            ushort4 hh = {h0, h1, h2, h3};
            ushort4 ll = {f2bf(r0 - bf2f(h0)), f2bf(r1 - bf2f(h1)),
                          f2bf(r2 - bf2f(h2)), f2bf(r3 - bf2f(h3))};
            *reinterpret_cast<ushort4*>(resrow + n * 32 + d0) = hh;
            *reinterpret_cast<ushort4*>(resrow + 384 + n * 32 + d0) = ll;
        }
    }
#undef LDFRAG
#undef EXP16
#undef MKPB
}

// ---------------------------------------------------------------------------
extern "C" void kernel_launch(void* const* d_in, const int* in_sizes, int n_in,
                              void* d_out, int out_size, void* d_ws, size_t ws_size,
                              hipStream_t stream)
{
    const float* x      = (const float*)d_in[0];
    const float* qkv_w  = (const float*)d_in[1];
    const float* qkv_b  = (const float*)d_in[2];
    const float* lepe_w = (const float*)d_in[3];
    const float* lepe_b = (const float*)d_in[4];
    const float* out_w  = (const float*)d_in[5];
    const float* out_b  = (const float*)d_in[6];
    float* out = (float*)d_out;

    char* ws = (char*)d_ws;
    float*          Kf32 = (float*)ws;                                  // 50331648 B
    unsigned short* qvB  = (unsigned short*)(ws + 50331648);            // 50331648 B
    float*          cosv = (float*)(ws + 100663296);                    // 1572864 B
    int*            idx  = (int*)(ws + 102236160);                      // 1572864 B
    unsigned short* Wqv  = (unsigned short*)(ws + 103809024);           // 589824 B
    unsigned short* owh  = (unsigned short*)(ws + 104398848);           // 294912 B
    unsigned short* owl  = (unsigned short*)(ws + 104693760);           // 294912 B
    float*          qvb  = (float*)(ws + 104988672);                    // 3072 B
    float*          clsg = (float*)(ws + 104991744);                    // 12288 B

    unsigned short* xbT   = (unsigned short*)d_out;                     // dead before out-proj
    unsigned short* lepeT = (unsigned short*)d_out + 12582912;          // dead before out-proj

    // 1) merged prep: x transpose + weight conversions
    prep_kernel<<<4803, 256, 0, stream>>>(x, xbT, qkv_w, qkv_b, out_w, Wqv, qvb, owh, owl);
    // 2) k projection, exact fp32 (per-output accumulation bit-identical)
    gemm_k_kernel<<<dim3(3, 32, 8), 256, 0, stream>>>(qkv_w, x, qkv_b, Kf32);
    // 3) q,v projection, bf16 MFMA -> qvB [b][t][768] bf16
    mfma_nt_kernel<false, 0><<<dim3(6, 32, 8), 256, 20480, stream>>>(
        Wqv, nullptr, xbT, nullptr, qvb, qvB,
        384, 384, 384, 0L, (long)4096 * 384, (long)4096 * 768);
    // 4) class-mean (bit-identical)
    cls_kernel<<<96, 256, 0, stream>>>(Kf32, clsg);
    // 5) merged lepe + per-token cosine (independent; one dispatch)
    cos_lepe_kernel<<<2304, 256, 0, stream>>>(Kf32, clsg, cosv, qvB, lepe_w, lepe_b, lepeT);
    // 6) stable ascending argsort (u64-packed bitonic, identical permutation)
    sort_kernel<<<96, 1024, 0, stream>>>(cosv, idx);
    // 7) clustered attention + lepe residual; res -> bf16 hi/lo over qvB
    attn_kernel<<<dim3(16, 12, 8), 256, 0, stream>>>(Kf32, qvB, idx, lepeT);
    // 8) output projection, split-bf16 (3-term) MFMA -> out
    mfma_nt_kernel<true, 1><<<dim3(32, 3, 8), 256, 40960, stream>>>(
        qvB, qvB + 384, owh, owl, out_b, out,
        384, 768, 384, (long)4096 * 768, 0L, (long)384 * 4096);
}

// Round 14
// 391.101 us; speedup vs baseline: 1.1471x; 1.0083x over previous
//
#include <hip/hip_runtime.h>
#include <math.h>

#define SCALE_F   0.17677669529663687f   // 32^-0.5
#define SCALE_L2E 0.25505837072959003f   // 32^-0.5 * log2(e)

using bf16x8 = __attribute__((ext_vector_type(8))) __bf16;
using f32x2  = __attribute__((ext_vector_type(2))) float;
using f32x4  = __attribute__((ext_vector_type(4))) float;
using f32x16 = __attribute__((ext_vector_type(16))) float;
using uint2e = __attribute__((ext_vector_type(2))) unsigned int;

__device__ inline unsigned short f2bf(float x) {
    __bf16 h = (__bf16)x;                       // HW v_cvt (RNE)
    return __builtin_bit_cast(unsigned short, h);
}
__device__ inline float bf2f(unsigned short u) {
    unsigned int x = ((unsigned int)u) << 16;
    return __builtin_bit_cast(float, x);
}
__device__ inline unsigned int packbf(float a, float b) {
    return (unsigned int)f2bf(a) | ((unsigned int)f2bf(b) << 16);
}
__device__ inline bf16x8 ldfrag(const unsigned short* p) {
    return __builtin_bit_cast(bf16x8, *reinterpret_cast<const uint4*>(p));
}

// ---------------------------------------------------------------------------
// fp32 k-projection GEMM — round-12 measured-best config (129.5us):
// BM=128, BN=128, BK=32, 512 thr, 4x8 micro-tile, B register prefetch.
// Each output's accumulation remains ONE fma chain over k ascending ->
// k values bit-identical to all previous passing rounds (argsort-safe).
// ---------------------------------------------------------------------------
__global__ __launch_bounds__(512)
void gemm_k_kernel(const float* __restrict__ A, const float* __restrict__ Bmat,
                   const float* __restrict__ bias, float* __restrict__ CT)
{
    const int bm = blockIdx.x, bn = blockIdx.y, bz = blockIdx.z;
    const float* Bp = Bmat + (long)bz * 384 * 4096;
    float* Cp = CT + (long)bz * 4096 * 384;
    __shared__ float As[32][132];
    __shared__ float BsF[32 * 136];
    const int tid = threadIdx.x;
    const int tx = tid & 15, ty = tid >> 4;    // tx 0..15, ty 0..31
    const int m0 = bm * 128, n0 = bn * 128;

    const int sr0 = tid >> 5,          sq0 = tid & 31;
    const int sr1 = (tid + 512) >> 5,  sq1 = (tid + 512) & 31;
    const int wB0 = sr0 * 136 + ((sq0 & 1) << 6) + ((sq0 >> 1) << 2);
    const int wB1 = sr1 * 136 + ((sq1 & 1) << 6) + ((sq1 >> 1) << 2);

    f32x2 acc2[4][4];
    #pragma unroll
    for (int i = 0; i < 4; ++i)
        #pragma unroll
        for (int p = 0; p < 4; ++p) acc2[i][p] = (f32x2){0.f, 0.f};

    // prologue: prefetch B tile 0
    float4 bPf0 = *reinterpret_cast<const float4*>(&Bp[(long)sr0 * 4096 + n0 + sq0 * 4]);
    float4 bPf1 = *reinterpret_cast<const float4*>(&Bp[(long)sr1 * 4096 + n0 + sq1 * 4]);

    for (int k0 = 0; k0 < 384; k0 += 32) {
        if (k0) __syncthreads();
        *reinterpret_cast<float4*>(&BsF[wB0]) = bPf0;
        *reinterpret_cast<float4*>(&BsF[wB1]) = bPf1;
        #pragma unroll
        for (int it = 0; it < 2; ++it) {
            int slot = tid + it * 512;
            int rA = slot >> 3, cA = slot & 7;
            float4 av = *reinterpret_cast<const float4*>(&A[(long)(384 + m0 + rA) * 384 + k0 + cA * 4]);
            As[cA * 4 + 0][rA] = av.x; As[cA * 4 + 1][rA] = av.y;
            As[cA * 4 + 2][rA] = av.z; As[cA * 4 + 3][rA] = av.w;
        }
        __syncthreads();
        if (k0 + 32 < 384) {
            bPf0 = *reinterpret_cast<const float4*>(&Bp[(long)(k0 + 32 + sr0) * 4096 + n0 + sq0 * 4]);
            bPf1 = *reinterpret_cast<const float4*>(&Bp[(long)(k0 + 32 + sr1) * 4096 + n0 + sq1 * 4]);
        }
        #pragma unroll
        for (int kk = 0; kk < 32; ++kk) {
            float a[4];
            *reinterpret_cast<float4*>(&a[0]) = *reinterpret_cast<const float4*>(&As[kk][ty * 4]);
            float4 blo = *reinterpret_cast<const float4*>(&BsF[kk * 136 + tx * 4]);
            float4 bhi = *reinterpret_cast<const float4*>(&BsF[kk * 136 + 64 + tx * 4]);
            f32x2 b2[4];
            b2[0] = (f32x2){blo.x, blo.y}; b2[1] = (f32x2){blo.z, blo.w};
            b2[2] = (f32x2){bhi.x, bhi.y}; b2[3] = (f32x2){bhi.z, bhi.w};
            #pragma unroll
            for (int i = 0; i < 4; ++i) {
                f32x2 a2 = (f32x2){a[i], a[i]};
                #pragma unroll
                for (int p = 0; p < 4; ++p)
                    acc2[i][p] = __builtin_elementwise_fma(a2, b2[p], acc2[i][p]);
            }
        }
    }

    float bv[4];
    #pragma unroll
    for (int i = 0; i < 4; ++i) bv[i] = bias[384 + m0 + ty * 4 + i];
    #pragma unroll
    for (int p = 0; p < 4; ++p)
        #pragma unroll
        for (int c = 0; c < 2; ++c) {
            int j = 2 * p + c;
            long tok = n0 + tx * 8 + j;
            float4 v = make_float4(acc2[0][p][c] + bv[0], acc2[1][p][c] + bv[1],
                                   acc2[2][p][c] + bv[2], acc2[3][p][c] + bv[3]);
            *reinterpret_cast<float4*>(Cp + tok * 384 + m0 + ty * 4) = v;
        }
}

// ---------------------------------------------------------------------------
// bf16 MFMA NT-GEMM: D[rowA][rowB] = sum_k A[rowA][k]*B[rowB][k], both k-contig.
// SM=0: store bf16 at C[t=colB][m=rowA] (ldc 768), bias by rowA  (QV proj)
// SM=1: store f32  at C[m=colB][t=rowA] (ldc 4096), bias by colB (out proj)
// SPLIT: A,B given as hi/lo bf16 pairs; 3-term product.
// ---------------------------------------------------------------------------
template<bool SPLIT, int SM>
__global__ __launch_bounds__(256)
void mfma_nt_kernel(const unsigned short* __restrict__ Ah, const unsigned short* __restrict__ Al,
                    const unsigned short* __restrict__ Bh, const unsigned short* __restrict__ Bl,
                    const float* __restrict__ bias, void* __restrict__ Cout,
                    int K, int lda, int ldb,
                    long strideAb, long strideBb, long strideCb)
{
    extern __shared__ unsigned short smem[];
    unsigned short* As  = smem;            // [128][40]
    unsigned short* Bs  = smem + 5120;
    unsigned short* Asl = smem + 10240;
    unsigned short* Bsl = smem + 15360;
    const int bm = blockIdx.x, bn = blockIdx.y, bz = blockIdx.z;
    const unsigned short* Ap = Ah + (long)bz * strideAb;
    const unsigned short* Bp = Bh + (long)bz * strideBb;
    const unsigned short* Alp = nullptr;
    const unsigned short* Blp = nullptr;
    if constexpr (SPLIT) {
        Alp = Al + (long)bz * strideAb;
        Blp = Bl + (long)bz * strideBb;
    }
    const int tid = threadIdx.x;
    const int lane = tid & 63, wid = tid >> 6;
    const int wr = wid >> 1, wc = wid & 1;
    const int l15 = lane & 15, l4 = lane >> 4;
    const int m0 = bm * 128, n0 = bn * 128;

    const f32x4 Z4 = {0.f, 0.f, 0.f, 0.f};
    f32x4 acc[4][4];
    #pragma unroll
    for (int i = 0; i < 4; ++i)
        #pragma unroll
        for (int j = 0; j < 4; ++j) acc[i][j] = Z4;

    for (int k0 = 0; k0 < K; k0 += 32) {
        if (k0) __syncthreads();
        #pragma unroll
        for (int it = 0; it < 2; ++it) {
            int slot = tid + it * 256;
            int r = slot >> 2, cq = slot & 3;
            *reinterpret_cast<uint4*>(&As[r * 40 + cq * 8]) =
                *reinterpret_cast<const uint4*>(&Ap[(long)(m0 + r) * lda + k0 + cq * 8]);
            *reinterpret_cast<uint4*>(&Bs[r * 40 + cq * 8]) =
                *reinterpret_cast<const uint4*>(&Bp[(long)(n0 + r) * ldb + k0 + cq * 8]);
            if constexpr (SPLIT) {
                *reinterpret_cast<uint4*>(&Asl[r * 40 + cq * 8]) =
                    *reinterpret_cast<const uint4*>(&Alp[(long)(m0 + r) * lda + k0 + cq * 8]);
                *reinterpret_cast<uint4*>(&Bsl[r * 40 + cq * 8]) =
                    *reinterpret_cast<const uint4*>(&Blp[(long)(n0 + r) * ldb + k0 + cq * 8]);
            }
        }
        __syncthreads();

        bf16x8 af[4], bg[4], afl[4], bgl[4];
        #pragma unroll
        for (int f = 0; f < 4; ++f) {
            af[f] = ldfrag(&As[(wr * 64 + f * 16 + l15) * 40 + l4 * 8]);
            bg[f] = ldfrag(&Bs[(wc * 64 + f * 16 + l15) * 40 + l4 * 8]);
        }
        if constexpr (SPLIT) {
            #pragma unroll
            for (int f = 0; f < 4; ++f) {
                afl[f] = ldfrag(&Asl[(wr * 64 + f * 16 + l15) * 40 + l4 * 8]);
                bgl[f] = ldfrag(&Bsl[(wc * 64 + f * 16 + l15) * 40 + l4 * 8]);
            }
        }
        #pragma unroll
        for (int fi = 0; fi < 4; ++fi)
            #pragma unroll
            for (int fj = 0; fj < 4; ++fj) {
                acc[fi][fj] = __builtin_amdgcn_mfma_f32_16x16x32_bf16(af[fi], bg[fj], acc[fi][fj], 0, 0, 0);
                if constexpr (SPLIT) {
                    acc[fi][fj] = __builtin_amdgcn_mfma_f32_16x16x32_bf16(af[fi], bgl[fj], acc[fi][fj], 0, 0, 0);
                    acc[fi][fj] = __builtin_amdgcn_mfma_f32_16x16x32_bf16(afl[fi], bg[fj], acc[fi][fj], 0, 0, 0);
                }
            }
    }

    if constexpr (SM == 0) {
        unsigned short* Cq = (unsigned short*)Cout + (long)bz * strideCb;
        #pragma unroll
        for (int fi = 0; fi < 4; ++fi)
            #pragma unroll
            for (int fj = 0; fj < 4; ++fj) {
                const int m = m0 + wr * 64 + fi * 16 + l4 * 4;
                const int t = n0 + wc * 64 + fj * 16 + l15;
                ushort4 h;
                h.x = f2bf(acc[fi][fj][0] + bias[m + 0]);
                h.y = f2bf(acc[fi][fj][1] + bias[m + 1]);
                h.z = f2bf(acc[fi][fj][2] + bias[m + 2]);
                h.w = f2bf(acc[fi][fj][3] + bias[m + 3]);
                *reinterpret_cast<ushort4*>(&Cq[(long)t * 768 + m]) = h;
            }
    } else {
        float* Cf = (float*)Cout + (long)bz * strideCb;
        #pragma unroll
        for (int fi = 0; fi < 4; ++fi)
            #pragma unroll
            for (int fj = 0; fj < 4; ++fj) {
                const int t = m0 + wr * 64 + fi * 16 + l4 * 4;
                const int m = n0 + wc * 64 + fj * 16 + l15;
                const float bv = bias[m];
                float4 v = make_float4(acc[fi][fj][0] + bv, acc[fi][fj][1] + bv,
                                       acc[fi][fj][2] + bv, acc[fi][fj][3] + bv);
                *reinterpret_cast<float4*>(&Cf[(long)m * 4096 + t]) = v;
            }
    }
}

// ---------------------------------------------------------------------------
// Merged prep kernel: blocks 0..3071 transpose x -> xbT bf16;
// blocks 3072..4802 weight conversion.
// ---------------------------------------------------------------------------
__global__ __launch_bounds__(256)
void prep_kernel(const float* __restrict__ x, unsigned short* __restrict__ xbT,
                 const float* __restrict__ qkv_w, const float* __restrict__ qkv_b,
                 const float* __restrict__ out_w,
                 unsigned short* __restrict__ Wqv, float* __restrict__ qvb,
                 unsigned short* __restrict__ owh, unsigned short* __restrict__ owl)
{
    __shared__ float tl[64][65];
    const int bid = blockIdx.x;
    const int tid = threadIdx.x;
    if (bid < 3072) {
        const int t0 = (bid % 64) * 64, c0 = ((bid / 64) % 6) * 64, b = bid / 384;
        #pragma unroll
        for (int i = 0; i < 16; ++i) {
            int cr = (tid >> 6) + i * 4, tc = tid & 63;
            tl[cr][tc] = x[((long)b * 384 + c0 + cr) * 4096 + t0 + tc];
        }
        __syncthreads();
        #pragma unroll
        for (int i = 0; i < 8; ++i) {
            int tr = (tid >> 5) + i * 8, c2 = (tid & 31) * 2;
            unsigned int u = packbf(tl[c2][tr], tl[c2 + 1][tr]);
            *reinterpret_cast<unsigned int*>(&xbT[((long)b * 4096 + t0 + tr) * 384 + c0 + c2]) = u;
        }
    } else {
        const int total = 294912 + 147456 + 768;
        for (int i = (bid - 3072) * 256 + tid; i < total; i += 1731 * 256) {
            if (i < 294912) {
                int m = i / 384, k = i - m * 384;
                int src = (m < 384) ? m : m + 384;
                Wqv[i] = f2bf(qkv_w[(long)src * 384 + k]);
            } else if (i < 294912 + 147456) {
                int o = i - 294912;
                float w = out_w[o];
                unsigned short h = f2bf(w);
                owh[o] = h;
                owl[o] = f2bf(w - bf2f(h));
            } else {
                int m = i - 294912 - 147456;
                qvb[m] = qkv_b[(m < 384) ? m : m + 384];
            }
        }
    }
}

// ---------------------------------------------------------------------------
// cls kernel: per (b,n) normalized mean of k (bit-identical math).
// ---------------------------------------------------------------------------
__global__ __launch_bounds__(256)
void cls_kernel(const float* __restrict__ Kf32, float* __restrict__ clsg)
{
    const int bn = blockIdx.x;
    const int b = bn / 12, n = bn % 12;
    const float* kb = Kf32 + (long)b * 4096 * 384 + n * 32;
    __shared__ float part[256][33];
    const int tid = threadIdx.x;
    float acc[32];
    #pragma unroll
    for (int d = 0; d < 32; ++d) acc[d] = 0.f;
    for (int i = 0; i < 16; ++i) {
        long tok = tid + i * 256;
        const float* kr = kb + tok * 384;
        #pragma unroll
        for (int d = 0; d < 32; ++d) acc[d] += kr[d];
    }
    #pragma unroll
    for (int d = 0; d < 32; ++d) part[tid][d] = acc[d];
    __syncthreads();
    if (tid < 32) {
        double s = 0.0;
        for (int t = 0; t < 256; ++t) s += (double)part[t][tid];
        part[0][tid] = (float)s;
    }
    __syncthreads();
    if (tid == 0) {
        double nn = 0.0;
        for (int d = 0; d < 32; ++d) { double v = (double)part[0][d]; nn += v * v; }
        double inv = 1.0 / sqrt(nn > 1e-300 ? nn : 1e-300);
        for (int d = 0; d < 32; ++d) clsg[bn * 32 + d] = (float)((double)part[0][d] * inv);
    }
}

// ---------------------------------------------------------------------------
// Merged lepe + cos2 kernel (independent ops, one dispatch -> co-scheduled).
// ---------------------------------------------------------------------------
__global__ __launch_bounds__(256)
void cos_lepe_kernel(const float* __restrict__ Kf32, const float* __restrict__ clsg,
                     float* __restrict__ cosv,
                     const unsigned short* __restrict__ qvB, const float* __restrict__ w5,
                     const float* __restrict__ wb, unsigned short* __restrict__ lepeT)
{
    __shared__ float tile[12 * 68 * 16];
    const int bid = blockIdx.x;
    const int tid = threadIdx.x;

    if (bid < 1536) {
        const int ch0 = (bid % 24) * 16;
        const int y0 = ((bid / 24) % 8) * 8;
        const int b = bid / 192;
        const unsigned short* vb = qvB + (long)b * 4096 * 768 + 384 + ch0;
        unsigned short* dst = lepeT + (long)b * 4096 * 384 + ch0;

        for (int s = tid; s < 12 * 68 * 2; s += 256) {
            int pix = s >> 1, half = s & 1;
            int yy = pix / 68, xx = pix % 68;
            int gy = y0 + yy - 2, gx = xx - 2;
            float* tp = &tile[pix * 16 + half * 8];
            if (gy >= 0 && gy < 64 && gx >= 0 && gx < 64) {
                uint4 u = *reinterpret_cast<const uint4*>(vb + (long)(gy * 64 + gx) * 768 + half * 8);
                tp[0] = bf2f((unsigned short)(u.x & 0xFFFFu)); tp[1] = bf2f((unsigned short)(u.x >> 16));
                tp[2] = bf2f((unsigned short)(u.y & 0xFFFFu)); tp[3] = bf2f((unsigned short)(u.y >> 16));
                tp[4] = bf2f((unsigned short)(u.z & 0xFFFFu)); tp[5] = bf2f((unsigned short)(u.z >> 16));
                tp[6] = bf2f((unsigned short)(u.w & 0xFFFFu)); tp[7] = bf2f((unsigned short)(u.w >> 16));
            } else {
                #pragma unroll
                for (int j = 0; j < 8; ++j) tp[j] = 0.f;
            }
        }
        const int c = tid & 15, xo = tid >> 4;
        float f[25];
        #pragma unroll
        for (int j = 0; j < 25; ++j) f[j] = w5[(ch0 + c) * 25 + j];
        const float bv = wb[ch0 + c];
        __syncthreads();

        #pragma unroll
        for (int yy = 0; yy < 8; ++yy) {
            #pragma unroll
            for (int xq = 0; xq < 4; ++xq) {
                int x = xq * 16 + xo;
                float acc = bv;
                #pragma unroll
                for (int dy = 0; dy < 5; ++dy)
                    #pragma unroll
                    for (int dx = 0; dx < 5; ++dx)
                        acc += tile[((yy + dy) * 68 + (x + dx)) * 16 + c] * f[dy * 5 + dx];
                dst[(long)((y0 + yy) * 64 + x) * 384 + c] = f2bf(acc);
            }
        }
    } else {
        const int cb = bid - 1536;
        const int bn = cb % 96;
        const int b = bn / 12, n = bn % 12;
        const float* kb = Kf32 + (long)b * 4096 * 384 + n * 32;
        const int t0 = (cb / 96) * 512;
        float clsn[32];
        #pragma unroll
        for (int d = 0; d < 32; ++d) clsn[d] = clsg[bn * 32 + d];
        #pragma unroll
        for (int i = 0; i < 2; ++i) {
            long tok = t0 + tid + i * 256;
            const float* kr = kb + tok * 384;
            double dot = 0.0, nrm = 0.0;
            #pragma unroll
            for (int d = 0; d < 32; ++d) {
                float kv = kr[d];
                dot += (double)clsn[d] * (double)kv;
                nrm += (double)kv * (double)kv;
            }
            double cv = dot / sqrt(nrm > 1e-300 ? nrm : 1e-300);
            cosv[(long)bn * 4096 + tok] = (float)cv;
        }
    }
}

// ---------------------------------------------------------------------------
// Bitonic argsort ascending via packed u64 keys: (sortable32(cos)<<32)|idx.
// ---------------------------------------------------------------------------
__global__ __launch_bounds__(1024)
void sort_kernel(const float* __restrict__ cosv, int* __restrict__ idxo)
{
    const int bn = blockIdx.x;
    __shared__ unsigned long long sk[4096];
    const int tid = threadIdx.x;
    for (int i = tid; i < 4096; i += 1024) {
        unsigned int u = __builtin_bit_cast(unsigned int, cosv[(long)bn * 4096 + i]);
        u = (u & 0x80000000u) ? ~u : (u | 0x80000000u);
        sk[i] = ((unsigned long long)u << 32) | (unsigned int)i;
    }
    __syncthreads();
    for (int size = 2; size <= 4096; size <<= 1) {
        for (int stride = size >> 1; stride >= 1; stride >>= 1) {
            #pragma unroll 2
            for (int i = tid; i < 2048; i += 1024) {
                int lo = (i << 1) - (i & (stride - 1));
                int hi = lo + stride;
                bool asc = ((lo & size) == 0);
                unsigned long long a = sk[lo], bq = sk[hi];
                if ((a > bq) == asc) { sk[lo] = bq; sk[hi] = a; }
            }
            __syncthreads();
        }
    }
    for (int i = tid; i < 4096; i += 1024)
        idxo[(long)bn * 4096 + i] = (int)(sk[i] & 0xFFFFFFFFu);
}

// ---------------------------------------------------------------------------
// MFMA clustered attention. grid (16,12,8), 256 thr = 4 waves.
// ---------------------------------------------------------------------------
__global__ __launch_bounds__(256)
void attn_kernel(const float* __restrict__ Kf32, unsigned short* __restrict__ qvB,
                 const int* __restrict__ idxbuf, const unsigned short* __restrict__ lepeT)
{
    const int cc = blockIdx.x, n = blockIdx.y, b = blockIdx.z;
    const int* ip = idxbuf + ((long)(b * 12 + n)) * 4096 + cc * 256;

    __shared__ unsigned short KsL[256][36];
    __shared__ unsigned short VsT[32][260];
    __shared__ int tokLds[256];

    const int tid = threadIdx.x;
    const int w = tid >> 6;
    const int lane = tid & 63;
    const int lo5 = lane & 31;
    const int hi = lane >> 5;
    const int hi8 = hi * 8;

    // ---- gather ----
    const int tk0 = ip[tid];
    tokLds[tid] = tk0;
    const long tb = (long)b * 4096 + tk0;
    const unsigned short* qrow = qvB + tb * 768 + n * 32;
    const float* krow = Kf32 + tb * 384 + n * 32;

    unsigned int Pq[16];
    #pragma unroll
    for (int i = 0; i < 4; ++i) {
        uint4 qu = *reinterpret_cast<const uint4*>(qrow + i * 8);
        Pq[4 * i + 0] = qu.x; Pq[4 * i + 1] = qu.y;
        Pq[4 * i + 2] = qu.z; Pq[4 * i + 3] = qu.w;
    }
    #pragma unroll
    for (int dq = 0; dq < 8; ++dq) {
        float4 kv = *reinterpret_cast<const float4*>(krow + dq * 4);
        ushort4 kp;
        kp.x = f2bf(kv.x * SCALE_L2E); kp.y = f2bf(kv.y * SCALE_L2E);
        kp.z = f2bf(kv.z * SCALE_L2E); kp.w = f2bf(kv.w * SCALE_L2E);
        *reinterpret_cast<ushort4*>(&KsL[tid][dq * 4]) = kp;
    }
    {
        union { uint4 u[4]; unsigned short s[32]; } vv;
        const unsigned short* vrow = qrow + 384;
        #pragma unroll
        for (int i = 0; i < 4; ++i) vv.u[i] = *reinterpret_cast<const uint4*>(vrow + i * 8);
        #pragma unroll
        for (int j = 0; j < 32; ++j) VsT[j][tid] = vv.s[j];
    }

    // ---- Q B-frags from own registers via permlane32_swap ----
    bf16x8 qf00, qf01, qf10, qf11;
    {
        unsigned int w0[2][4], w1[2][4];
        #pragma unroll
        for (int ks = 0; ks < 2; ++ks)
            #pragma unroll
            for (int j = 0; j < 4; ++j) {
                uint2e r = __builtin_amdgcn_permlane32_swap(Pq[ks * 8 + j], Pq[ks * 8 + 4 + j], false, false);
                w0[ks][j] = r[0];
                w1[ks][j] = r[1];
            }
        qf00 = __builtin_bit_cast(bf16x8, make_uint4(w0[0][0], w0[0][1], w0[0][2], w0[0][3]));
        qf01 = __builtin_bit_cast(bf16x8, make_uint4(w0[1][0], w0[1][1], w0[1][2], w0[1][3]));
        qf10 = __builtin_bit_cast(bf16x8, make_uint4(w1[0][0], w1[0][1], w1[0][2], w1[0][3]));
        qf11 = __builtin_bit_cast(bf16x8, make_uint4(w1[1][0], w1[1][1], w1[1][2], w1[1][3]));
    }
    __syncthreads();

    const f32x16 Z16 = {0,0,0,0,0,0,0,0,0,0,0,0,0,0,0,0};
    f32x16 o0 = Z16, o1 = Z16;
    float lsum0 = 0.f, lsum1 = 0.f;

#define LDFRAG(ARR, ROW, OFF) ({ \
    const unsigned short* _p = &ARR[ROW][OFF]; \
    union { bf16x8 v; ushort4 h[2]; } _u; \
    _u.h[0] = *reinterpret_cast<const ushort4*>(_p); \
    _u.h[1] = *reinterpret_cast<const ushort4*>(_p + 4); \
    _u.v; })

#define EXP16(S, LS) { _Pragma("unroll") for (int r = 0; r < 16; ++r) { float _e = __builtin_exp2f(S[r]); S[r] = _e; LS += _e; } }

#define MKPB(S, H) ({ \
    unsigned int _x0 = packbf(S[(H) * 8 + 0], S[(H) * 8 + 1]); \
    unsigned int _x1 = packbf(S[(H) * 8 + 2], S[(H) * 8 + 3]); \
    unsigned int _x2 = packbf(S[(H) * 8 + 4], S[(H) * 8 + 5]); \
    unsigned int _x3 = packbf(S[(H) * 8 + 6], S[(H) * 8 + 7]); \
    uint2e _r02 = __builtin_amdgcn_permlane32_swap(_x0, _x2, false, false); \
    uint2e _r13 = __builtin_amdgcn_permlane32_swap(_x1, _x3, false, false); \
    __builtin_bit_cast(bf16x8, make_uint4(_r02[0], _r13[0], _r02[1], _r13[1])); })

    for (int ch = 0; ch < 4; ++ch) {
        const int rb = ch * 64;
        f32x16 s00 = Z16, s01 = Z16, s10 = Z16, s11 = Z16;
        bf16x8 ka;
        __builtin_amdgcn_s_setprio(1);
        ka = LDFRAG(KsL, rb + lo5, hi8);
        s00 = __builtin_amdgcn_mfma_f32_32x32x16_bf16(ka, qf00, s00, 0, 0, 0);
        s01 = __builtin_amdgcn_mfma_f32_32x32x16_bf16(ka, qf10, s01, 0, 0, 0);
        ka = LDFRAG(KsL, rb + lo5, 16 + hi8);
        s00 = __builtin_amdgcn_mfma_f32_32x32x16_bf16(ka, qf01, s00, 0, 0, 0);
        s01 = __builtin_amdgcn_mfma_f32_32x32x16_bf16(ka, qf11, s01, 0, 0, 0);
        ka = LDFRAG(KsL, rb + 32 + lo5, hi8);
        s10 = __builtin_amdgcn_mfma_f32_32x32x16_bf16(ka, qf00, s10, 0, 0, 0);
        s11 = __builtin_amdgcn_mfma_f32_32x32x16_bf16(ka, qf10, s11, 0, 0, 0);
        ka = LDFRAG(KsL, rb + 32 + lo5, 16 + hi8);
        s10 = __builtin_amdgcn_mfma_f32_32x32x16_bf16(ka, qf01, s10, 0, 0, 0);
        s11 = __builtin_amdgcn_mfma_f32_32x32x16_bf16(ka, qf11, s11, 0, 0, 0);
        __builtin_amdgcn_s_setprio(0);

        EXP16(s00, lsum0); EXP16(s01, lsum1);
        EXP16(s10, lsum0); EXP16(s11, lsum1);

        bf16x8 va, pb0, pb1;
        __builtin_amdgcn_s_setprio(1);
        va = LDFRAG(VsT, lo5, rb + 0 + hi8);
        pb0 = MKPB(s00, 0); pb1 = MKPB(s01, 0);
        o0 = __builtin_amdgcn_mfma_f32_32x32x16_bf16(va, pb0, o0, 0, 0, 0);
        o1 = __builtin_amdgcn_mfma_f32_32x32x16_bf16(va, pb1, o1, 0, 0, 0);
        va = LDFRAG(VsT, lo5, rb + 16 + hi8);
        pb0 = MKPB(s00, 1); pb1 = MKPB(s01, 1);
        o0 = __builtin_amdgcn_mfma_f32_32x32x16_bf16(va, pb0, o0, 0, 0, 0);
        o1 = __builtin_amdgcn_mfma_f32_32x32x16_bf16(va, pb1, o1, 0, 0, 0);
        va = LDFRAG(VsT, lo5, rb + 32 + hi8);
        pb0 = MKPB(s10, 0); pb1 = MKPB(s11, 0);
        o0 = __builtin_amdgcn_mfma_f32_32x32x16_bf16(va, pb0, o0, 0, 0, 0);
        o1 = __builtin_amdgcn_mfma_f32_32x32x16_bf16(va, pb1, o1, 0, 0, 0);
        va = LDFRAG(VsT, lo5, rb + 48 + hi8);
        pb0 = MKPB(s10, 1); pb1 = MKPB(s11, 1);
        o0 = __builtin_amdgcn_mfma_f32_32x32x16_bf16(va, pb0, o0, 0, 0, 0);
        o1 = __builtin_amdgcn_mfma_f32_32x32x16_bf16(va, pb1, o1, 0, 0, 0);
        __builtin_amdgcn_s_setprio(0);
    }

    // ---- epilogue: res = o/l + lepe -> bf16 hi/lo into qvB ----
    const float lf0 = lsum0 + __shfl_xor(lsum0, 32);
    const float lf1 = lsum1 + __shfl_xor(lsum1, 32);
    const float li0 = 1.f / lf0, li1 = 1.f / lf1;

    #pragma unroll
    for (int qt = 0; qt < 2; ++qt) {
        const int qrix = w * 64 + qt * 32 + lo5;
        const int tk = tokLds[qrix];
        const long tb2 = (long)b * 4096 + tk;
        unsigned short* resrow = qvB + tb2 * 768;
        const unsigned short* lp = lepeT + tb2 * 384 + n * 32;
        const float li = qt ? li1 : li0;
        const f32x16& oo = qt ? o1 : o0;
        #pragma unroll
        for (int qd = 0; qd < 4; ++qd) {
            const int d0 = qd * 8 + hi * 4;
            ushort4 lv = *reinterpret_cast<const ushort4*>(lp + d0);
            float r0 = oo[qd * 4 + 0] * li + bf2f(lv.x);
            float r1 = oo[qd * 4 + 1] * li + bf2f(lv.y);
            float r2 = oo[qd * 4 + 2] * li + bf2f(lv.z);
            float r3 = oo[qd * 4 + 3] * li + bf2f(lv.w);
            unsigned short h0 = f2bf(r0), h1 = f2bf(r1), h2 = f2bf(r2), h3 = f2bf(r3);
            ushort4 hh = {h0, h1, h2, h3};
            ushort4 ll = {f2bf(r0 - bf2f(h0)), f2bf(r1 - bf2f(h1)),
                          f2bf(r2 - bf2f(h2)), f2bf(r3 - bf2f(h3))};
            *reinterpret_cast<ushort4*>(resrow + n * 32 + d0) = hh;
            *reinterpret_cast<ushort4*>(resrow + 384 + n * 32 + d0) = ll;
        }
    }
#undef LDFRAG
#undef EXP16
#undef MKPB
}

// ---------------------------------------------------------------------------
extern "C" void kernel_launch(void* const* d_in, const int* in_sizes, int n_in,
                              void* d_out, int out_size, void* d_ws, size_t ws_size,
                              hipStream_t stream)
{
    const float* x      = (const float*)d_in[0];
    const float* qkv_w  = (const float*)d_in[1];
    const float* qkv_b  = (const float*)d_in[2];
    const float* lepe_w = (const float*)d_in[3];
    const float* lepe_b = (const float*)d_in[4];
    const float* out_w  = (const float*)d_in[5];
    const float* out_b  = (const float*)d_in[6];
    float* out = (float*)d_out;

    char* ws = (char*)d_ws;
    float*          Kf32 = (float*)ws;                                  // 50331648 B
    unsigned short* qvB  = (unsigned short*)(ws + 50331648);            // 50331648 B
    float*          cosv = (float*)(ws + 100663296);                    // 1572864 B
    int*            idx  = (int*)(ws + 102236160);                      // 1572864 B
    unsigned short* Wqv  = (unsigned short*)(ws + 103809024);           // 589824 B
    unsigned short* owh  = (unsigned short*)(ws + 104398848);           // 294912 B
    unsigned short* owl  = (unsigned short*)(ws + 104693760);           // 294912 B
    float*          qvb  = (float*)(ws + 104988672);                    // 3072 B
    float*          clsg = (float*)(ws + 104991744);                    // 12288 B

    unsigned short* xbT   = (unsigned short*)d_out;                     // dead before out-proj
    unsigned short* lepeT = (unsigned short*)d_out + 12582912;          // dead before out-proj

    // 1) merged prep: x transpose + weight conversions
    prep_kernel<<<4803, 256, 0, stream>>>(x, xbT, qkv_w, qkv_b, out_w, Wqv, qvb, owh, owl);
    // 2) k projection, exact fp32 (per-output accumulation bit-identical)
    gemm_k_kernel<<<dim3(3, 32, 8), 512, 0, stream>>>(qkv_w, x, qkv_b, Kf32);
    // 3) q,v projection, bf16 MFMA -> qvB [b][t][768] bf16
    mfma_nt_kernel<false, 0><<<dim3(6, 32, 8), 256, 20480, stream>>>(
        Wqv, nullptr, xbT, nullptr, qvb, qvB,
        384, 384, 384, 0L, (long)4096 * 384, (long)4096 * 768);
    // 4) class-mean (bit-identical)
    cls_kernel<<<96, 256, 0, stream>>>(Kf32, clsg);
    // 5) merged lepe + per-token cosine (independent; one dispatch)
    cos_lepe_kernel<<<2304, 256, 0, stream>>>(Kf32, clsg, cosv, qvB, lepe_w, lepe_b, lepeT);
    // 6) stable ascending argsort (u64-packed bitonic, identical permutation)
    sort_kernel<<<96, 1024, 0, stream>>>(cosv, idx);
    // 7) clustered attention + lepe residual; res -> bf16 hi/lo over qvB
    attn_kernel<<<dim3(16, 12, 8), 256, 0, stream>>>(Kf32, qvB, idx, lepeT);
    // 8) output projection, split-bf16 (3-term) MFMA -> out
    mfma_nt_kernel<true, 1><<<dim3(32, 3, 8), 256, 40960, stream>>>(
        qvB, qvB + 384, owh, owl, out_b, out,
        384, 768, 384, (long)4096 * 768, 0L, (long)384 * 4096);
}

// Round 15
// 375.319 us; speedup vs baseline: 1.1954x; 1.0420x over previous
//
#include <hip/hip_runtime.h>
#include <math.h>

#define SCALE_F   0.17677669529663687f   // 32^-0.5
#define SCALE_L2E 0.25505837072959003f   // 32^-0.5 * log2(e)

using bf16x8 = __attribute__((ext_vector_type(8))) __bf16;
using f32x2  = __attribute__((ext_vector_type(2))) float;
using f32x4  = __attribute__((ext_vector_type(4))) float;
using f32x16 = __attribute__((ext_vector_type(16))) float;
using uint2e = __attribute__((ext_vector_type(2))) unsigned int;

__device__ inline unsigned short f2bf(float x) {
    __bf16 h = (__bf16)x;                       // HW v_cvt (RNE)
    return __builtin_bit_cast(unsigned short, h);
}
__device__ inline float bf2f(unsigned short u) {
    unsigned int x = ((unsigned int)u) << 16;
    return __builtin_bit_cast(float, x);
}
__device__ inline unsigned int packbf(float a, float b) {
    return (unsigned int)f2bf(a) | ((unsigned int)f2bf(b) << 16);
}
__device__ inline bf16x8 ldfrag(const unsigned short* p) {
    return __builtin_bit_cast(bf16x8, *reinterpret_cast<const uint4*>(p));
}

// ---------------------------------------------------------------------------
// Fused k-projection (fp32, exact) + qv-projection (bf16 MFMA) mega-kernel.
// Blocks 0..767: gemm_k role (VALU-bound) — body identical to round-14
//   (k accumulation bit-identical, argsort-safe).
// Blocks 768..1535: qv role (MFMA-bound) — two 256-thr sub-blocks per block,
//   body identical to round-14 mfma_nt<false,0>.
// Disjoint pipes -> CU-level co-scheduling (MFMA+VALU overlap, time~max).
// Dynamic LDS 40960B.
// ---------------------------------------------------------------------------
__global__ __launch_bounds__(512)
void gemm_qv_kernel(const float* __restrict__ A, const float* __restrict__ Bmat,
                    const float* __restrict__ bias, float* __restrict__ CT,
                    const unsigned short* __restrict__ Wqv,
                    const unsigned short* __restrict__ xbT,
                    const float* __restrict__ qvb, unsigned short* __restrict__ qvB)
{
    extern __shared__ char smemRaw[];
    const int bid = blockIdx.x;

    if (bid < 768) {
        // ================= gemm_k role =================
        const int bm = bid % 3, bn = (bid / 3) % 32, bz = bid / 96;
        float* As  = (float*)smemRaw;                  // [32][132]
        float* BsF = (float*)(smemRaw + 16896);        // 32*136
        const float* Bp = Bmat + (long)bz * 384 * 4096;
        float* Cp = CT + (long)bz * 4096 * 384;
        const int tid = threadIdx.x;
        const int tx = tid & 15, ty = tid >> 4;
        const int m0 = bm * 128, n0 = bn * 128;

        const int sr0 = tid >> 5,          sq0 = tid & 31;
        const int sr1 = (tid + 512) >> 5,  sq1 = (tid + 512) & 31;
        const int wB0 = sr0 * 136 + ((sq0 & 1) << 6) + ((sq0 >> 1) << 2);
        const int wB1 = sr1 * 136 + ((sq1 & 1) << 6) + ((sq1 >> 1) << 2);

        f32x2 acc2[4][4];
        #pragma unroll
        for (int i = 0; i < 4; ++i)
            #pragma unroll
            for (int p = 0; p < 4; ++p) acc2[i][p] = (f32x2){0.f, 0.f};

        float4 bPf0 = *reinterpret_cast<const float4*>(&Bp[(long)sr0 * 4096 + n0 + sq0 * 4]);
        float4 bPf1 = *reinterpret_cast<const float4*>(&Bp[(long)sr1 * 4096 + n0 + sq1 * 4]);

        for (int k0 = 0; k0 < 384; k0 += 32) {
            if (k0) __syncthreads();
            *reinterpret_cast<float4*>(&BsF[wB0]) = bPf0;
            *reinterpret_cast<float4*>(&BsF[wB1]) = bPf1;
            #pragma unroll
            for (int it = 0; it < 2; ++it) {
                int slot = tid + it * 512;
                int rA = slot >> 3, cA = slot & 7;
                float4 av = *reinterpret_cast<const float4*>(&A[(long)(384 + m0 + rA) * 384 + k0 + cA * 4]);
                As[(cA * 4 + 0) * 132 + rA] = av.x; As[(cA * 4 + 1) * 132 + rA] = av.y;
                As[(cA * 4 + 2) * 132 + rA] = av.z; As[(cA * 4 + 3) * 132 + rA] = av.w;
            }
            __syncthreads();
            if (k0 + 32 < 384) {
                bPf0 = *reinterpret_cast<const float4*>(&Bp[(long)(k0 + 32 + sr0) * 4096 + n0 + sq0 * 4]);
                bPf1 = *reinterpret_cast<const float4*>(&Bp[(long)(k0 + 32 + sr1) * 4096 + n0 + sq1 * 4]);
            }
            #pragma unroll
            for (int kk = 0; kk < 32; ++kk) {
                float a[4];
                *reinterpret_cast<float4*>(&a[0]) = *reinterpret_cast<const float4*>(&As[kk * 132 + ty * 4]);
                float4 blo = *reinterpret_cast<const float4*>(&BsF[kk * 136 + tx * 4]);
                float4 bhi = *reinterpret_cast<const float4*>(&BsF[kk * 136 + 64 + tx * 4]);
                f32x2 b2[4];
                b2[0] = (f32x2){blo.x, blo.y}; b2[1] = (f32x2){blo.z, blo.w};
                b2[2] = (f32x2){bhi.x, bhi.y}; b2[3] = (f32x2){bhi.z, bhi.w};
                #pragma unroll
                for (int i = 0; i < 4; ++i) {
                    f32x2 a2 = (f32x2){a[i], a[i]};
                    #pragma unroll
                    for (int p = 0; p < 4; ++p)
                        acc2[i][p] = __builtin_elementwise_fma(a2, b2[p], acc2[i][p]);
                }
            }
        }

        float bv[4];
        #pragma unroll
        for (int i = 0; i < 4; ++i) bv[i] = bias[384 + m0 + ty * 4 + i];
        #pragma unroll
        for (int p = 0; p < 4; ++p)
            #pragma unroll
            for (int c = 0; c < 2; ++c) {
                int j = 2 * p + c;
                long tok = n0 + tx * 8 + j;
                float4 v = make_float4(acc2[0][p][c] + bv[0], acc2[1][p][c] + bv[1],
                                       acc2[2][p][c] + bv[2], acc2[3][p][c] + bv[3]);
                *reinterpret_cast<float4*>(Cp + tok * 384 + m0 + ty * 4) = v;
            }
    } else {
        // ================= qv role (2 sub-blocks of 256 thr) =================
        const int sub = threadIdx.x >> 8;
        const int tid = threadIdx.x & 255;
        unsigned short* As = (unsigned short*)(smemRaw + sub * 20480);          // [128][40]
        unsigned short* Bs = As + 5120;
        const int qb = (bid - 768) * 2 + sub;
        const int bm = qb % 6, bn = (qb / 6) % 32, bz = qb / 192;
        const unsigned short* Ap = Wqv;
        const unsigned short* Bp = xbT + (long)bz * 4096 * 384;
        const int lane = tid & 63, wid = tid >> 6;
        const int wr = wid >> 1, wc = wid & 1;
        const int l15 = lane & 15, l4 = lane >> 4;
        const int m0 = bm * 128, n0 = bn * 128;

        const f32x4 Z4 = {0.f, 0.f, 0.f, 0.f};
        f32x4 acc[4][4];
        #pragma unroll
        for (int i = 0; i < 4; ++i)
            #pragma unroll
            for (int j = 0; j < 4; ++j) acc[i][j] = Z4;

        for (int k0 = 0; k0 < 384; k0 += 32) {
            if (k0) __syncthreads();
            #pragma unroll
            for (int it = 0; it < 2; ++it) {
                int slot = tid + it * 256;
                int r = slot >> 2, cq = slot & 3;
                *reinterpret_cast<uint4*>(&As[r * 40 + cq * 8]) =
                    *reinterpret_cast<const uint4*>(&Ap[(long)(m0 + r) * 384 + k0 + cq * 8]);
                *reinterpret_cast<uint4*>(&Bs[r * 40 + cq * 8]) =
                    *reinterpret_cast<const uint4*>(&Bp[(long)(n0 + r) * 384 + k0 + cq * 8]);
            }
            __syncthreads();

            bf16x8 af[4], bg[4];
            #pragma unroll
            for (int f = 0; f < 4; ++f) {
                af[f] = ldfrag(&As[(wr * 64 + f * 16 + l15) * 40 + l4 * 8]);
                bg[f] = ldfrag(&Bs[(wc * 64 + f * 16 + l15) * 40 + l4 * 8]);
            }
            #pragma unroll
            for (int fi = 0; fi < 4; ++fi)
                #pragma unroll
                for (int fj = 0; fj < 4; ++fj)
                    acc[fi][fj] = __builtin_amdgcn_mfma_f32_16x16x32_bf16(af[fi], bg[fj], acc[fi][fj], 0, 0, 0);
        }

        unsigned short* Cq = qvB + (long)bz * 4096 * 768;
        #pragma unroll
        for (int fi = 0; fi < 4; ++fi)
            #pragma unroll
            for (int fj = 0; fj < 4; ++fj) {
                const int m = m0 + wr * 64 + fi * 16 + l4 * 4;
                const int t = n0 + wc * 64 + fj * 16 + l15;
                ushort4 h;
                h.x = f2bf(acc[fi][fj][0] + qvb[m + 0]);
                h.y = f2bf(acc[fi][fj][1] + qvb[m + 1]);
                h.z = f2bf(acc[fi][fj][2] + qvb[m + 2]);
                h.w = f2bf(acc[fi][fj][3] + qvb[m + 3]);
                *reinterpret_cast<ushort4*>(&Cq[(long)t * 768 + m]) = h;
            }
    }
}

// ---------------------------------------------------------------------------
// Out-projection: split-bf16 (3-term) MFMA NT-GEMM. Body identical to
// round-14 mfma_nt<true,1>.
// ---------------------------------------------------------------------------
__global__ __launch_bounds__(256)
void outproj_kernel(const unsigned short* __restrict__ Ah, const unsigned short* __restrict__ Al,
                    const unsigned short* __restrict__ Bh, const unsigned short* __restrict__ Bl,
                    const float* __restrict__ bias, float* __restrict__ Cout)
{
    extern __shared__ unsigned short smem[];
    unsigned short* As  = smem;            // [128][40]
    unsigned short* Bs  = smem + 5120;
    unsigned short* Asl = smem + 10240;
    unsigned short* Bsl = smem + 15360;
    const int bm = blockIdx.x, bn = blockIdx.y, bz = blockIdx.z;
    const unsigned short* Ap = Ah + (long)bz * 4096 * 768;
    const unsigned short* Alp = Al + (long)bz * 4096 * 768;
    const unsigned short* Bp = Bh;
    const unsigned short* Blp = Bl;
    const int tid = threadIdx.x;
    const int lane = tid & 63, wid = tid >> 6;
    const int wr = wid >> 1, wc = wid & 1;
    const int l15 = lane & 15, l4 = lane >> 4;
    const int m0 = bm * 128, n0 = bn * 128;

    const f32x4 Z4 = {0.f, 0.f, 0.f, 0.f};
    f32x4 acc[4][4];
    #pragma unroll
    for (int i = 0; i < 4; ++i)
        #pragma unroll
        for (int j = 0; j < 4; ++j) acc[i][j] = Z4;

    for (int k0 = 0; k0 < 384; k0 += 32) {
        if (k0) __syncthreads();
        #pragma unroll
        for (int it = 0; it < 2; ++it) {
            int slot = tid + it * 256;
            int r = slot >> 2, cq = slot & 3;
            *reinterpret_cast<uint4*>(&As[r * 40 + cq * 8]) =
                *reinterpret_cast<const uint4*>(&Ap[(long)(m0 + r) * 768 + k0 + cq * 8]);
            *reinterpret_cast<uint4*>(&Bs[r * 40 + cq * 8]) =
                *reinterpret_cast<const uint4*>(&Bp[(long)(n0 + r) * 384 + k0 + cq * 8]);
            *reinterpret_cast<uint4*>(&Asl[r * 40 + cq * 8]) =
                *reinterpret_cast<const uint4*>(&Alp[(long)(m0 + r) * 768 + k0 + cq * 8]);
            *reinterpret_cast<uint4*>(&Bsl[r * 40 + cq * 8]) =
                *reinterpret_cast<const uint4*>(&Blp[(long)(n0 + r) * 384 + k0 + cq * 8]);
        }
        __syncthreads();

        bf16x8 af[4], bg[4], afl[4], bgl[4];
        #pragma unroll
        for (int f = 0; f < 4; ++f) {
            af[f]  = ldfrag(&As[(wr * 64 + f * 16 + l15) * 40 + l4 * 8]);
            bg[f]  = ldfrag(&Bs[(wc * 64 + f * 16 + l15) * 40 + l4 * 8]);
            afl[f] = ldfrag(&Asl[(wr * 64 + f * 16 + l15) * 40 + l4 * 8]);
            bgl[f] = ldfrag(&Bsl[(wc * 64 + f * 16 + l15) * 40 + l4 * 8]);
        }
        #pragma unroll
        for (int fi = 0; fi < 4; ++fi)
            #pragma unroll
            for (int fj = 0; fj < 4; ++fj) {
                acc[fi][fj] = __builtin_amdgcn_mfma_f32_16x16x32_bf16(af[fi], bg[fj], acc[fi][fj], 0, 0, 0);
                acc[fi][fj] = __builtin_amdgcn_mfma_f32_16x16x32_bf16(af[fi], bgl[fj], acc[fi][fj], 0, 0, 0);
                acc[fi][fj] = __builtin_amdgcn_mfma_f32_16x16x32_bf16(afl[fi], bg[fj], acc[fi][fj], 0, 0, 0);
            }
    }

    float* Cf = Cout + (long)bz * 384 * 4096;
    #pragma unroll
    for (int fi = 0; fi < 4; ++fi)
        #pragma unroll
        for (int fj = 0; fj < 4; ++fj) {
            const int t = m0 + wr * 64 + fi * 16 + l4 * 4;
            const int m = n0 + wc * 64 + fj * 16 + l15;
            const float bv = bias[m];
            float4 v = make_float4(acc[fi][fj][0] + bv, acc[fi][fj][1] + bv,
                                   acc[fi][fj][2] + bv, acc[fi][fj][3] + bv);
            *reinterpret_cast<float4*>(&Cf[(long)m * 4096 + t]) = v;
        }
}

// ---------------------------------------------------------------------------
// Merged prep kernel: blocks 0..3071 transpose x -> xbT bf16;
// blocks 3072..4802 weight conversion.
// ---------------------------------------------------------------------------
__global__ __launch_bounds__(256)
void prep_kernel(const float* __restrict__ x, unsigned short* __restrict__ xbT,
                 const float* __restrict__ qkv_w, const float* __restrict__ qkv_b,
                 const float* __restrict__ out_w,
                 unsigned short* __restrict__ Wqv, float* __restrict__ qvb,
                 unsigned short* __restrict__ owh, unsigned short* __restrict__ owl)
{
    __shared__ float tl[64][65];
    const int bid = blockIdx.x;
    const int tid = threadIdx.x;
    if (bid < 3072) {
        const int t0 = (bid % 64) * 64, c0 = ((bid / 64) % 6) * 64, b = bid / 384;
        #pragma unroll
        for (int i = 0; i < 16; ++i) {
            int cr = (tid >> 6) + i * 4, tc = tid & 63;
            tl[cr][tc] = x[((long)b * 384 + c0 + cr) * 4096 + t0 + tc];
        }
        __syncthreads();
        #pragma unroll
        for (int i = 0; i < 8; ++i) {
            int tr = (tid >> 5) + i * 8, c2 = (tid & 31) * 2;
            unsigned int u = packbf(tl[c2][tr], tl[c2 + 1][tr]);
            *reinterpret_cast<unsigned int*>(&xbT[((long)b * 4096 + t0 + tr) * 384 + c0 + c2]) = u;
        }
    } else {
        const int total = 294912 + 147456 + 768;
        for (int i = (bid - 3072) * 256 + tid; i < total; i += 1731 * 256) {
            if (i < 294912) {
                int m = i / 384, k = i - m * 384;
                int src = (m < 384) ? m : m + 384;
                Wqv[i] = f2bf(qkv_w[(long)src * 384 + k]);
            } else if (i < 294912 + 147456) {
                int o = i - 294912;
                float w = out_w[o];
                unsigned short h = f2bf(w);
                owh[o] = h;
                owl[o] = f2bf(w - bf2f(h));
            } else {
                int m = i - 294912 - 147456;
                qvb[m] = qkv_b[(m < 384) ? m : m + 384];
            }
        }
    }
}

// ---------------------------------------------------------------------------
// cls kernel: per (b,n) normalized mean of k (bit-identical math).
// ---------------------------------------------------------------------------
__global__ __launch_bounds__(256)
void cls_kernel(const float* __restrict__ Kf32, float* __restrict__ clsg)
{
    const int bn = blockIdx.x;
    const int b = bn / 12, n = bn % 12;
    const float* kb = Kf32 + (long)b * 4096 * 384 + n * 32;
    __shared__ float part[256][33];
    const int tid = threadIdx.x;
    float acc[32];
    #pragma unroll
    for (int d = 0; d < 32; ++d) acc[d] = 0.f;
    for (int i = 0; i < 16; ++i) {
        long tok = tid + i * 256;
        const float* kr = kb + tok * 384;
        #pragma unroll
        for (int d = 0; d < 32; ++d) acc[d] += kr[d];
    }
    #pragma unroll
    for (int d = 0; d < 32; ++d) part[tid][d] = acc[d];
    __syncthreads();
    if (tid < 32) {
        double s = 0.0;
        for (int t = 0; t < 256; ++t) s += (double)part[t][tid];
        part[0][tid] = (float)s;
    }
    __syncthreads();
    if (tid == 0) {
        double nn = 0.0;
        for (int d = 0; d < 32; ++d) { double v = (double)part[0][d]; nn += v * v; }
        double inv = 1.0 / sqrt(nn > 1e-300 ? nn : 1e-300);
        for (int d = 0; d < 32; ++d) clsg[bn * 32 + d] = (float)((double)part[0][d] * inv);
    }
}

// ---------------------------------------------------------------------------
// Merged lepe + cos2 kernel (independent ops, one dispatch -> co-scheduled).
// ---------------------------------------------------------------------------
__global__ __launch_bounds__(256)
void cos_lepe_kernel(const float* __restrict__ Kf32, const float* __restrict__ clsg,
                     float* __restrict__ cosv,
                     const unsigned short* __restrict__ qvB, const float* __restrict__ w5,
                     const float* __restrict__ wb, unsigned short* __restrict__ lepeT)
{
    __shared__ float tile[12 * 68 * 16];
    const int bid = blockIdx.x;
    const int tid = threadIdx.x;

    if (bid < 1536) {
        const int ch0 = (bid % 24) * 16;
        const int y0 = ((bid / 24) % 8) * 8;
        const int b = bid / 192;
        const unsigned short* vb = qvB + (long)b * 4096 * 768 + 384 + ch0;
        unsigned short* dst = lepeT + (long)b * 4096 * 384 + ch0;

        for (int s = tid; s < 12 * 68 * 2; s += 256) {
            int pix = s >> 1, half = s & 1;
            int yy = pix / 68, xx = pix % 68;
            int gy = y0 + yy - 2, gx = xx - 2;
            float* tp = &tile[pix * 16 + half * 8];
            if (gy >= 0 && gy < 64 && gx >= 0 && gx < 64) {
                uint4 u = *reinterpret_cast<const uint4*>(vb + (long)(gy * 64 + gx) * 768 + half * 8);
                tp[0] = bf2f((unsigned short)(u.x & 0xFFFFu)); tp[1] = bf2f((unsigned short)(u.x >> 16));
                tp[2] = bf2f((unsigned short)(u.y & 0xFFFFu)); tp[3] = bf2f((unsigned short)(u.y >> 16));
                tp[4] = bf2f((unsigned short)(u.z & 0xFFFFu)); tp[5] = bf2f((unsigned short)(u.z >> 16));
                tp[6] = bf2f((unsigned short)(u.w & 0xFFFFu)); tp[7] = bf2f((unsigned short)(u.w >> 16));
            } else {
                #pragma unroll
                for (int j = 0; j < 8; ++j) tp[j] = 0.f;
            }
        }
        const int c = tid & 15, xo = tid >> 4;
        float f[25];
        #pragma unroll
        for (int j = 0; j < 25; ++j) f[j] = w5[(ch0 + c) * 25 + j];
        const float bv = wb[ch0 + c];
        __syncthreads();

        #pragma unroll
        for (int yy = 0; yy < 8; ++yy) {
            #pragma unroll
            for (int xq = 0; xq < 4; ++xq) {
                int x = xq * 16 + xo;
                float acc = bv;
                #pragma unroll
                for (int dy = 0; dy < 5; ++dy)
                    #pragma unroll
                    for (int dx = 0; dx < 5; ++dx)
                        acc += tile[((yy + dy) * 68 + (x + dx)) * 16 + c] * f[dy * 5 + dx];
                dst[(long)((y0 + yy) * 64 + x) * 384 + c] = f2bf(acc);
            }
        }
    } else {
        const int cb = bid - 1536;
        const int bn = cb % 96;
        const int b = bn / 12, n = bn % 12;
        const float* kb = Kf32 + (long)b * 4096 * 384 + n * 32;
        const int t0 = (cb / 96) * 512;
        float clsn[32];
        #pragma unroll
        for (int d = 0; d < 32; ++d) clsn[d] = clsg[bn * 32 + d];
        #pragma unroll
        for (int i = 0; i < 2; ++i) {
            long tok = t0 + tid + i * 256;
            const float* kr = kb + tok * 384;
            double dot = 0.0, nrm = 0.0;
            #pragma unroll
            for (int d = 0; d < 32; ++d) {
                float kv = kr[d];
                dot += (double)clsn[d] * (double)kv;
                nrm += (double)kv * (double)kv;
            }
            double cv = dot / sqrt(nrm > 1e-300 ? nrm : 1e-300);
            cosv[(long)bn * 4096 + tok] = (float)cv;
        }
    }
}

// ---------------------------------------------------------------------------
// Bitonic argsort ascending via packed u64 keys: (sortable32(cos)<<32)|idx.
// ---------------------------------------------------------------------------
__global__ __launch_bounds__(1024)
void sort_kernel(const float* __restrict__ cosv, int* __restrict__ idxo)
{
    const int bn = blockIdx.x;
    __shared__ unsigned long long sk[4096];
    const int tid = threadIdx.x;
    for (int i = tid; i < 4096; i += 1024) {
        unsigned int u = __builtin_bit_cast(unsigned int, cosv[(long)bn * 4096 + i]);
        u = (u & 0x80000000u) ? ~u : (u | 0x80000000u);
        sk[i] = ((unsigned long long)u << 32) | (unsigned int)i;
    }
    __syncthreads();
    for (int size = 2; size <= 4096; size <<= 1) {
        for (int stride = size >> 1; stride >= 1; stride >>= 1) {
            #pragma unroll 2
            for (int i = tid; i < 2048; i += 1024) {
                int lo = (i << 1) - (i & (stride - 1));
                int hi = lo + stride;
                bool asc = ((lo & size) == 0);
                unsigned long long a = sk[lo], bq = sk[hi];
                if ((a > bq) == asc) { sk[lo] = bq; sk[hi] = a; }
            }
            __syncthreads();
        }
    }
    for (int i = tid; i < 4096; i += 1024)
        idxo[(long)bn * 4096 + i] = (int)(sk[i] & 0xFFFFFFFFu);
}

// ---------------------------------------------------------------------------
// MFMA clustered attention. grid (16,12,8), 256 thr = 4 waves.
// ---------------------------------------------------------------------------
__global__ __launch_bounds__(256)
void attn_kernel(const float* __restrict__ Kf32, unsigned short* __restrict__ qvB,
                 const int* __restrict__ idxbuf, const unsigned short* __restrict__ lepeT)
{
    const int cc = blockIdx.x, n = blockIdx.y, b = blockIdx.z;
    const int* ip = idxbuf + ((long)(b * 12 + n)) * 4096 + cc * 256;

    __shared__ unsigned short KsL[256][36];
    __shared__ unsigned short VsT[32][260];
    __shared__ int tokLds[256];

    const int tid = threadIdx.x;
    const int w = tid >> 6;
    const int lane = tid & 63;
    const int lo5 = lane & 31;
    const int hi = lane >> 5;
    const int hi8 = hi * 8;

    // ---- gather ----
    const int tk0 = ip[tid];
    tokLds[tid] = tk0;
    const long tb = (long)b * 4096 + tk0;
    const unsigned short* qrow = qvB + tb * 768 + n * 32;
    const float* krow = Kf32 + tb * 384 + n * 32;

    unsigned int Pq[16];
    #pragma unroll
    for (int i = 0; i < 4; ++i) {
        uint4 qu = *reinterpret_cast<const uint4*>(qrow + i * 8);
        Pq[4 * i + 0] = qu.x; Pq[4 * i + 1] = qu.y;
        Pq[4 * i + 2] = qu.z; Pq[4 * i + 3] = qu.w;
    }
    #pragma unroll
    for (int dq = 0; dq < 8; ++dq) {
        float4 kv = *reinterpret_cast<const float4*>(krow + dq * 4);
        ushort4 kp;
        kp.x = f2bf(kv.x * SCALE_L2E); kp.y = f2bf(kv.y * SCALE_L2E);
        kp.z = f2bf(kv.z * SCALE_L2E); kp.w = f2bf(kv.w * SCALE_L2E);
        *reinterpret_cast<ushort4*>(&KsL[tid][dq * 4]) = kp;
    }
    {
        union { uint4 u[4]; unsigned short s[32]; } vv;
        const unsigned short* vrow = qrow + 384;
        #pragma unroll
        for (int i = 0; i < 4; ++i) vv.u[i] = *reinterpret_cast<const uint4*>(vrow + i * 8);
        #pragma unroll
        for (int j = 0; j < 32; ++j) VsT[j][tid] = vv.s[j];
    }

    // ---- Q B-frags from own registers via permlane32_swap ----
    bf16x8 qf00, qf01, qf10, qf11;
    {
        unsigned int w0[2][4], w1[2][4];
        #pragma unroll
        for (int ks = 0; ks < 2; ++ks)
            #pragma unroll
            for (int j = 0; j < 4; ++j) {
                uint2e r = __builtin_amdgcn_permlane32_swap(Pq[ks * 8 + j], Pq[ks * 8 + 4 + j], false, false);
                w0[ks][j] = r[0];
                w1[ks][j] = r[1];
            }
        qf00 = __builtin_bit_cast(bf16x8, make_uint4(w0[0][0], w0[0][1], w0[0][2], w0[0][3]));
        qf01 = __builtin_bit_cast(bf16x8, make_uint4(w0[1][0], w0[1][1], w0[1][2], w0[1][3]));
        qf10 = __builtin_bit_cast(bf16x8, make_uint4(w1[0][0], w1[0][1], w1[0][2], w1[0][3]));
        qf11 = __builtin_bit_cast(bf16x8, make_uint4(w1[1][0], w1[1][1], w1[1][2], w1[1][3]));
    }
    __syncthreads();

    const f32x16 Z16 = {0,0,0,0,0,0,0,0,0,0,0,0,0,0,0,0};
    f32x16 o0 = Z16, o1 = Z16;
    float lsum0 = 0.f, lsum1 = 0.f;

#define LDFRAG(ARR, ROW, OFF) ({ \
    const unsigned short* _p = &ARR[ROW][OFF]; \
    union { bf16x8 v; ushort4 h[2]; } _u; \
    _u.h[0] = *reinterpret_cast<const ushort4*>(_p); \
    _u.h[1] = *reinterpret_cast<const ushort4*>(_p + 4); \
    _u.v; })

#define EXP16(S, LS) { _Pragma("unroll") for (int r = 0; r < 16; ++r) { float _e = __builtin_exp2f(S[r]); S[r] = _e; LS += _e; } }

#define MKPB(S, H) ({ \
    unsigned int _x0 = packbf(S[(H) * 8 + 0], S[(H) * 8 + 1]); \
    unsigned int _x1 = packbf(S[(H) * 8 + 2], S[(H) * 8 + 3]); \
    unsigned int _x2 = packbf(S[(H) * 8 + 4], S[(H) * 8 + 5]); \
    unsigned int _x3 = packbf(S[(H) * 8 + 6], S[(H) * 8 + 7]); \
    uint2e _r02 = __builtin_amdgcn_permlane32_swap(_x0, _x2, false, false); \
    uint2e _r13 = __builtin_amdgcn_permlane32_swap(_x1, _x3, false, false); \
    __builtin_bit_cast(bf16x8, make_uint4(_r02[0], _r13[0], _r02[1], _r13[1])); })

    for (int ch = 0; ch < 4; ++ch) {
        const int rb = ch * 64;
        f32x16 s00 = Z16, s01 = Z16, s10 = Z16, s11 = Z16;
        bf16x8 ka;
        __builtin_amdgcn_s_setprio(1);
        ka = LDFRAG(KsL, rb + lo5, hi8);
        s00 = __builtin_amdgcn_mfma_f32_32x32x16_bf16(ka, qf00, s00, 0, 0, 0);
        s01 = __builtin_amdgcn_mfma_f32_32x32x16_bf16(ka, qf10, s01, 0, 0, 0);
        ka = LDFRAG(KsL, rb + lo5, 16 + hi8);
        s00 = __builtin_amdgcn_mfma_f32_32x32x16_bf16(ka, qf01, s00, 0, 0, 0);
        s01 = __builtin_amdgcn_mfma_f32_32x32x16_bf16(ka, qf11, s01, 0, 0, 0);
        ka = LDFRAG(KsL, rb + 32 + lo5, hi8);
        s10 = __builtin_amdgcn_mfma_f32_32x32x16_bf16(ka, qf00, s10, 0, 0, 0);
        s11 = __builtin_amdgcn_mfma_f32_32x32x16_bf16(ka, qf10, s11, 0, 0, 0);
        ka = LDFRAG(KsL, rb + 32 + lo5, 16 + hi8);
        s10 = __builtin_amdgcn_mfma_f32_32x32x16_bf16(ka, qf01, s10, 0, 0, 0);
        s11 = __builtin_amdgcn_mfma_f32_32x32x16_bf16(ka, qf11, s11, 0, 0, 0);
        __builtin_amdgcn_s_setprio(0);

        EXP16(s00, lsum0); EXP16(s01, lsum1);
        EXP16(s10, lsum0); EXP16(s11, lsum1);

        bf16x8 va, pb0, pb1;
        __builtin_amdgcn_s_setprio(1);
        va = LDFRAG(VsT, lo5, rb + 0 + hi8);
        pb0 = MKPB(s00, 0); pb1 = MKPB(s01, 0);
        o0 = __builtin_amdgcn_mfma_f32_32x32x16_bf16(va, pb0, o0, 0, 0, 0);
        o1 = __builtin_amdgcn_mfma_f32_32x32x16_bf16(va, pb1, o1, 0, 0, 0);
        va = LDFRAG(VsT, lo5, rb + 16 + hi8);
        pb0 = MKPB(s00, 1); pb1 = MKPB(s01, 1);
        o0 = __builtin_amdgcn_mfma_f32_32x32x16_bf16(va, pb0, o0, 0, 0, 0);
        o1 = __builtin_amdgcn_mfma_f32_32x32x16_bf16(va, pb1, o1, 0, 0, 0);
        va = LDFRAG(VsT, lo5, rb + 32 + hi8);
        pb0 = MKPB(s10, 0); pb1 = MKPB(s11, 0);
        o0 = __builtin_amdgcn_mfma_f32_32x32x16_bf16(va, pb0, o0, 0, 0, 0);
        o1 = __builtin_amdgcn_mfma_f32_32x32x16_bf16(va, pb1, o1, 0, 0, 0);
        va = LDFRAG(VsT, lo5, rb + 48 + hi8);
        pb0 = MKPB(s10, 1); pb1 = MKPB(s11, 1);
        o0 = __builtin_amdgcn_mfma_f32_32x32x16_bf16(va, pb0, o0, 0, 0, 0);
        o1 = __builtin_amdgcn_mfma_f32_32x32x16_bf16(va, pb1, o1, 0, 0, 0);
        __builtin_amdgcn_s_setprio(0);
    }

    // ---- epilogue: res = o/l + lepe -> bf16 hi/lo into qvB ----
    const float lf0 = lsum0 + __shfl_xor(lsum0, 32);
    const float lf1 = lsum1 + __shfl_xor(lsum1, 32);
    const float li0 = 1.f / lf0, li1 = 1.f / lf1;

    #pragma unroll
    for (int qt = 0; qt < 2; ++qt) {
        const int qrix = w * 64 + qt * 32 + lo5;
        const int tk = tokLds[qrix];
        const long tb2 = (long)b * 4096 + tk;
        unsigned short* resrow = qvB + tb2 * 768;
        const unsigned short* lp = lepeT + tb2 * 384 + n * 32;
        const float li = qt ? li1 : li0;
        const f32x16& oo = qt ? o1 : o0;
        #pragma unroll
        for (int qd = 0; qd < 4; ++qd) {
            const int d0 = qd * 8 + hi * 4;
            ushort4 lv = *reinterpret_cast<const ushort4*>(lp + d0);
            float r0 = oo[qd * 4 + 0] * li + bf2f(lv.x);
            float r1 = oo[qd * 4 + 1] * li + bf2f(lv.y);
            float r2 = oo[qd * 4 + 2] * li + bf2f(lv.z);
            float r3 = oo[qd * 4 + 3] * li + bf2f(lv.w);
            unsigned short h0 = f2bf(r0), h1 = f2bf(r1), h2 = f2bf(r2), h3 = f2bf(r3);
            ushort4 hh = {h0, h1, h2, h3};
            ushort4 ll = {f2bf(r0 - bf2f(h0)), f2bf(r1 - bf2f(h1)),
                          f2bf(r2 - bf2f(h2)), f2bf(r3 - bf2f(h3))};
            *reinterpret_cast<ushort4*>(resrow + n * 32 + d0) = hh;
            *reinterpret_cast<ushort4*>(resrow + 384 + n * 32 + d0) = ll;
        }
    }
#undef LDFRAG
#undef EXP16
#undef MKPB
}

// ---------------------------------------------------------------------------
extern "C" void kernel_launch(void* const* d_in, const int* in_sizes, int n_in,
                              void* d_out, int out_size, void* d_ws, size_t ws_size,
                              hipStream_t stream)
{
    const float* x      = (const float*)d_in[0];
    const float* qkv_w  = (const float*)d_in[1];
    const float* qkv_b  = (const float*)d_in[2];
    const float* lepe_w = (const float*)d_in[3];
    const float* lepe_b = (const float*)d_in[4];
    const float* out_w  = (const float*)d_in[5];
    const float* out_b  = (const float*)d_in[6];
    float* out = (float*)d_out;

    char* ws = (char*)d_ws;
    float*          Kf32 = (float*)ws;                                  // 50331648 B
    unsigned short* qvB  = (unsigned short*)(ws + 50331648);            // 50331648 B
    float*          cosv = (float*)(ws + 100663296);                    // 1572864 B
    int*            idx  = (int*)(ws + 102236160);                      // 1572864 B
    unsigned short* Wqv  = (unsigned short*)(ws + 103809024);           // 589824 B
    unsigned short* owh  = (unsigned short*)(ws + 104398848);           // 294912 B
    unsigned short* owl  = (unsigned short*)(ws + 104693760);           // 294912 B
    float*          qvb  = (float*)(ws + 104988672);                    // 3072 B
    float*          clsg = (float*)(ws + 104991744);                    // 12288 B

    unsigned short* xbT   = (unsigned short*)d_out;                     // dead before out-proj
    unsigned short* lepeT = (unsigned short*)d_out + 12582912;          // dead before out-proj

    // 1) merged prep: x transpose + weight conversions
    prep_kernel<<<4803, 256, 0, stream>>>(x, xbT, qkv_w, qkv_b, out_w, Wqv, qvb, owh, owl);
    // 2) fused k-projection (fp32, bit-identical) + qv-projection (bf16 MFMA):
    //    disjoint pipes co-scheduled on each CU
    gemm_qv_kernel<<<1536, 512, 40960, stream>>>(qkv_w, x, qkv_b, Kf32,
                                                 Wqv, xbT, qvb, qvB);
    // 3) class-mean (bit-identical)
    cls_kernel<<<96, 256, 0, stream>>>(Kf32, clsg);
    // 4) merged lepe + per-token cosine (independent; one dispatch)
    cos_lepe_kernel<<<2304, 256, 0, stream>>>(Kf32, clsg, cosv, qvB, lepe_w, lepe_b, lepeT);
    // 5) stable ascending argsort (u64-packed bitonic, identical permutation)
    sort_kernel<<<96, 1024, 0, stream>>>(cosv, idx);
    // 6) clustered attention + lepe residual; res -> bf16 hi/lo over qvB
    attn_kernel<<<dim3(16, 12, 8), 256, 0, stream>>>(Kf32, qvB, idx, lepeT);
    // 7) output projection, split-bf16 (3-term) MFMA -> out
    outproj_kernel<<<dim3(32, 3, 8), 256, 40960, stream>>>(
        qvB, qvB + 384, owh, owl, out_b, out);
}